// Round 2
// baseline (30909.219 us; speedup 1.0000x reference)
//
#include <hip/hip_runtime.h>
#include <hip/hip_cooperative_groups.h>
#include <cstddef>

namespace cg = cooperative_groups;

// ---------------------------------------------------------------------------
// B=64, S=256, W=256 input dim, E=512, HID=1024, L=2, NCLS=10
// Chunked pipeline (Tc timesteps/chunk, adaptive to ws_size):
//   per chunk: enc GEMM -> Gx0 GEMM -> coop LSTM0 -> Gx1 GEMM -> coop LSTM1
// Workspace (floats):
//   G    [Tc][4096][64]   gates-x chunk, reused by both layers
//   Y0c  [Tc][1024][64]   layer-0 h chunk ([t][k][b])
//   Ec   [Tc*64][512]     encoder chunk (row-major)
//   WhT0/WhT1 [4096][1024] transposed recurrent weights
//   hA/hB [1024][64]      h ping-pong; hst0/hst1, cst0/cst1 [1024][64] state
// ---------------------------------------------------------------------------

__device__ __forceinline__ float sigmoidf_(float x) {
    return 1.f / (1.f + __expf(-x));
}

// A addressing modes: 0 = row-major [r][k] (stride K)
//                     1 = "SKB": [r>>6][k][r&63]  (Y0 layout)
//                     2 = x input: [b=r&63][s=r>>6][k] with strides sB, sS
template <int AMODE>
__device__ __forceinline__ size_t addrA(int r, int k, int K, int sB, int sS) {
    if (AMODE == 0) return (size_t)r * K + k;
    if (AMODE == 1) return (size_t)(r >> 6) * K * 64 + (size_t)k * 64 + (r & 63);
    return (size_t)(r & 63) * sB + (size_t)(r >> 6) * sS + k;
}

// C = act(A[M,K] @ B[K,N] + bias1 + bias2).  BM=128, BN=64, BK=16, 256 thr,
// 8x4 microtile. CMODE 0: row-major. CMODE 1: [r>>6][col][r&63] (G layout).
template <int AMODE, int CMODE, bool PRELU>
__global__ __launch_bounds__(256) void gemm_k(
    const float* __restrict__ A, const float* __restrict__ B,
    float* __restrict__ C, const float* __restrict__ bias1,
    const float* __restrict__ bias2, const float* __restrict__ alphap,
    int M, int N, int K, int sB, int sS)
{
    __shared__ float As[128][17];
    __shared__ float Bs[16][64];
    const int tid = threadIdx.x;
    const int tx = tid & 15, ty = tid >> 4;
    const int rb = blockIdx.y * 128;
    const int cb = blockIdx.x * 64;

    float acc[8][4];
#pragma unroll
    for (int i = 0; i < 8; ++i)
#pragma unroll
        for (int j = 0; j < 4; ++j) acc[i][j] = 0.f;

    const int nk = K >> 4;
    for (int kt = 0; kt < nk; ++kt) {
        const int k0 = kt << 4;
        __syncthreads();
        if (AMODE == 1) {                 // vectorize along rows (b-contig)
            const int u = tid & 31, kk = tid >> 5;   // u: row-quad, kk: 0..7
#pragma unroll
            for (int h = 0; h < 2; ++h) {
                const int k = kk + h * 8;
                const int r0 = rb + u * 4;
                const float4 v = *reinterpret_cast<const float4*>(
                    &A[addrA<1>(r0, k0 + k, K, sB, sS)]);
                As[u * 4 + 0][k] = v.x; As[u * 4 + 1][k] = v.y;
                As[u * 4 + 2][k] = v.z; As[u * 4 + 3][k] = v.w;
            }
        } else {                          // vectorize along k
            const int row = tid >> 2, k4 = tid & 3;
#pragma unroll
            for (int h = 0; h < 2; ++h) {
                const int r = row + h * 64;
                const float4 v = *reinterpret_cast<const float4*>(
                    &A[addrA<AMODE>(rb + r, k0 + k4 * 4, K, sB, sS)]);
                As[r][k4 * 4 + 0] = v.x; As[r][k4 * 4 + 1] = v.y;
                As[r][k4 * 4 + 2] = v.z; As[r][k4 * 4 + 3] = v.w;
            }
        }
        {
            const int bk = tid >> 4, c4 = tid & 15;
            *reinterpret_cast<float4*>(&Bs[bk][c4 * 4]) =
                *reinterpret_cast<const float4*>(
                    &B[(size_t)(k0 + bk) * N + cb + c4 * 4]);
        }
        __syncthreads();
#pragma unroll
        for (int k = 0; k < 16; ++k) {
            float a[8];
#pragma unroll
            for (int i = 0; i < 8; ++i) a[i] = As[ty * 8 + i][k];
            const float4 bv =
                *reinterpret_cast<const float4*>(&Bs[k][tx * 4]);
#pragma unroll
            for (int i = 0; i < 8; ++i) {
                acc[i][0] = fmaf(a[i], bv.x, acc[i][0]);
                acc[i][1] = fmaf(a[i], bv.y, acc[i][1]);
                acc[i][2] = fmaf(a[i], bv.z, acc[i][2]);
                acc[i][3] = fmaf(a[i], bv.w, acc[i][3]);
            }
        }
    }

    float bsum[4];
#pragma unroll
    for (int j = 0; j < 4; ++j) {
        const int c = cb + tx * 4 + j;
        float b = bias1 ? bias1[c] : 0.f;
        if (bias2) b += bias2[c];
        bsum[j] = b;
    }
    const float alpha = PRELU ? alphap[0] : 0.f;
#pragma unroll
    for (int i = 0; i < 8; ++i) {
        const int r = rb + ty * 8 + i;
#pragma unroll
        for (int j = 0; j < 4; ++j) {
            float v = acc[i][j] + bsum[j];
            if (PRELU) v = (v >= 0.f) ? v : alpha * v;
            if (CMODE == 0)
                C[(size_t)r * N + cb + tx * 4 + j] = v;
            else
                C[(size_t)(r >> 6) * N * 64 + (size_t)(cb + tx * 4 + j) * 64 +
                  (r & 63)] = v;
        }
    }
}

// out[c][r] = in[r][c]; in is [R][Cc]. grid (Cc/32, R/32), 256 threads.
__global__ __launch_bounds__(256) void transpose_k(
    const float* __restrict__ in, float* __restrict__ out, int R, int Cc)
{
    __shared__ float tile[32][33];
    const int tx = threadIdx.x & 31, ty = threadIdx.x >> 5;   // ty 0..7
    const int rb = blockIdx.y * 32, cb = blockIdx.x * 32;
#pragma unroll
    for (int yy = 0; yy < 32; yy += 8)
        tile[ty + yy][tx] = in[(size_t)(rb + ty + yy) * Cc + cb + tx];
    __syncthreads();
#pragma unroll
    for (int yy = 0; yy < 32; yy += 8)
        out[(size_t)(cb + ty + yy) * R + rb + tx] = tile[tx][ty + yy];
}

// Persistent cooperative LSTM chunk. 256 blocks x 512 threads (1 block/CU).
// Wave w (0..7): wq=w&3 -> h-column blockIdx.x*4+wq; half=w>>2 -> k-half.
// lane = batch row. c lives in a VGPR across the chunk (half-0 waves).
// h ping-pongs hA/hB in [k][b] layout. G is [t][j][b] chunk-local.
// h0row/c0row (row-major [b][k]) given on first chunk, else hstate/cstate
// ([k][b]) carry state. At t==Tc-1 state is written back.
__global__ __launch_bounds__(512) void lstm_k(
    const float* __restrict__ G, const float* __restrict__ WhT,
    const float* __restrict__ h0row, const float* __restrict__ c0row,
    float* __restrict__ hstate, float* __restrict__ cstate,
    float* __restrict__ hA, float* __restrict__ hB, float* __restrict__ Y,
    int Tc)
{
    __shared__ float hS[2 * 8192];       // 64 KB: two 128-k chunks of h[k][b]
    float* partS = hS;                   // aliased reuse, barrier-guarded

    cg::grid_group grid = cg::this_grid();
    const int tid = threadIdx.x;
    const int lane = tid & 63;
    const int w = tid >> 6;
    const int wq = w & 3;
    const int half = w >> 2;
    const int colh = blockIdx.x * 4 + wq;
    const int ucolh = __builtin_amdgcn_readfirstlane(colh);
    const int uhalf = __builtin_amdgcn_readfirstlane(half);

    const float* __restrict__ wfp = WhT + (size_t)ucolh * 1024 + uhalf * 512;
    const float* __restrict__ wip = WhT + (size_t)(ucolh + 1024) * 1024 + uhalf * 512;
    const float* __restrict__ wgp = WhT + (size_t)(ucolh + 2048) * 1024 + uhalf * 512;
    const float* __restrict__ wop = WhT + (size_t)(ucolh + 3072) * 1024 + uhalf * 512;

    {   // init hA[k][b]
        const int idx = blockIdx.x * 512 + tid;
        if (idx < 65536)
            hA[idx] = h0row ? h0row[(idx & 63) * 1024 + (idx >> 6)]
                            : hstate[idx];
    }
    float c = c0row ? c0row[lane * 1024 + ucolh] : cstate[ucolh * 64 + lane];
    grid.sync();

    for (int t = 0; t < Tc; ++t) {
        const float* hread = (t & 1) ? hB : hA;
        float* hwrite = (t & 1) ? hA : hB;
        float pf = 0.f, pi = 0.f, pg = 0.f, po = 0.f;

        for (int cc = 0; cc < 4; ++cc) {
            __syncthreads();
#pragma unroll
            for (int p = 0; p < 4; ++p) {          // stage both halves' chunks
                const int off = p * 2048 + tid * 4;
                *reinterpret_cast<float4*>(&hS[off]) =
                    *reinterpret_cast<const float4*>(&hread[cc * 8192 + off]);
                *reinterpret_cast<float4*>(&hS[8192 + off]) =
                    *reinterpret_cast<const float4*>(
                        &hread[32768 + cc * 8192 + off]);
            }
            __syncthreads();
            const float* hc = hS + half * 8192;
            const float* wf = wfp + cc * 128;
            const float* wi = wip + cc * 128;
            const float* wg = wgp + cc * 128;
            const float* wo = wop + cc * 128;
#pragma unroll 2
            for (int kk = 0; kk < 128; kk += 4) {
                const float4 vf = *reinterpret_cast<const float4*>(&wf[kk]);
                const float4 vi = *reinterpret_cast<const float4*>(&wi[kk]);
                const float4 vg = *reinterpret_cast<const float4*>(&wg[kk]);
                const float4 vo = *reinterpret_cast<const float4*>(&wo[kk]);
                const float h0v = hc[(kk + 0) * 64 + lane];
                const float h1v = hc[(kk + 1) * 64 + lane];
                const float h2v = hc[(kk + 2) * 64 + lane];
                const float h3v = hc[(kk + 3) * 64 + lane];
                pf = fmaf(h0v, vf.x, pf); pf = fmaf(h1v, vf.y, pf);
                pf = fmaf(h2v, vf.z, pf); pf = fmaf(h3v, vf.w, pf);
                pi = fmaf(h0v, vi.x, pi); pi = fmaf(h1v, vi.y, pi);
                pi = fmaf(h2v, vi.z, pi); pi = fmaf(h3v, vi.w, pi);
                pg = fmaf(h0v, vg.x, pg); pg = fmaf(h1v, vg.y, pg);
                pg = fmaf(h2v, vg.z, pg); pg = fmaf(h3v, vg.w, pg);
                po = fmaf(h0v, vo.x, po); po = fmaf(h1v, vo.y, po);
                po = fmaf(h2v, vo.z, po); po = fmaf(h3v, vo.w, po);
            }
        }
        __syncthreads();                  // all hS consumption done
        if (half) {
            partS[(wq * 4 + 0) * 64 + lane] = pf;
            partS[(wq * 4 + 1) * 64 + lane] = pi;
            partS[(wq * 4 + 2) * 64 + lane] = pg;
            partS[(wq * 4 + 3) * 64 + lane] = po;
        }
        __syncthreads();
        if (!half) {
            pf += partS[(wq * 4 + 0) * 64 + lane];
            pi += partS[(wq * 4 + 1) * 64 + lane];
            pg += partS[(wq * 4 + 2) * 64 + lane];
            po += partS[(wq * 4 + 3) * 64 + lane];
            const size_t gb = (size_t)t * 262144 + (size_t)colh * 64 + lane;
            const float f = sigmoidf_(G[gb] + pf);
            const float i = sigmoidf_(G[gb + 65536] + pi);
            const float g = tanhf(G[gb + 131072] + pg);
            const float o = sigmoidf_(G[gb + 196608] + po);
            c = fmaf(f, c, i * g);
            const float h = o * tanhf(c);
            hwrite[colh * 64 + lane] = h;
            if (Y) Y[(size_t)t * 65536 + colh * 64 + lane] = h;
            if (t == Tc - 1) {
                hstate[colh * 64 + lane] = h;
                cstate[colh * 64 + lane] = c;
            }
        }
        grid.sync();
    }
}

// out[b][n] = hfin[:, b] . Wc[:, n] + bcls[n].  hfin is [k][b].
__global__ __launch_bounds__(256) void cls_k(
    const float* __restrict__ hfin, const float* __restrict__ Wc,
    const float* __restrict__ bcls, float* __restrict__ out)
{
    __shared__ float red[4][64];
    const int n = blockIdx.x;
    const int lane = threadIdx.x & 63, w = threadIdx.x >> 6;
    float acc = 0.f;
    for (int k = w * 256; k < w * 256 + 256; ++k)
        acc = fmaf(hfin[k * 64 + lane], Wc[k * 10 + n], acc);
    red[w][lane] = acc;
    __syncthreads();
    if (w == 0) {
        const float s = red[0][lane] + red[1][lane] + red[2][lane] +
                        red[3][lane] + bcls[n];
        out[lane * 10 + n] = s;
    }
}

extern "C" void kernel_launch(void* const* d_in, const int* in_sizes, int n_in,
                              void* d_out, int out_size, void* d_ws,
                              size_t ws_size, hipStream_t stream)
{
    const float* x    = (const float*)d_in[0];
    const float* h0   = (const float*)d_in[1];
    const float* c0   = (const float*)d_in[2];
    const float* Wenc = (const float*)d_in[3];
    const float* benc = (const float*)d_in[4];
    const float* alpha= (const float*)d_in[5];
    const float* Wx0  = (const float*)d_in[6];
    const float* bx0  = (const float*)d_in[7];
    const float* Wh0  = (const float*)d_in[8];
    const float* bh0  = (const float*)d_in[9];
    const float* Wx1  = (const float*)d_in[10];
    const float* bx1  = (const float*)d_in[11];
    const float* Wh1  = (const float*)d_in[12];
    const float* bh1  = (const float*)d_in[13];
    const float* Wcls = (const float*)d_in[14];
    const float* bcls = (const float*)d_in[15];
    float* out = (float*)d_out;

    // Adaptive chunk size so the workspace plan fits ws_size.
    const size_t ws_f = ws_size / sizeof(float);
    const size_t fixed = 8781824;                 // 2xWhT + hA/hB + 4 states
    int Tc = 256;
    while (Tc > 8 && fixed + (size_t)Tc * 360448 > ws_f) Tc >>= 1;

    float* ws   = (float*)d_ws;
    float* G    = ws;                              // Tc*262144
    float* Y0c  = G    + (size_t)Tc * 262144;      // Tc*65536
    float* Ec   = Y0c  + (size_t)Tc * 65536;       // Tc*32768
    float* WhT0 = Ec   + (size_t)Tc * 32768;       // 4,194,304
    float* WhT1 = WhT0 + 4194304;                  // 4,194,304
    float* hA   = WhT1 + 4194304;
    float* hB   = hA + 65536;
    float* hst0 = hB + 65536;
    float* hst1 = hst0 + 65536;
    float* cst0 = hst1 + 65536;
    float* cst1 = cst0 + 65536;

    transpose_k<<<dim3(128, 32), 256, 0, stream>>>(Wh0, WhT0, 1024, 4096);
    transpose_k<<<dim3(128, 32), 256, 0, stream>>>(Wh1, WhT1, 1024, 4096);

    const int nch = 256 / Tc;
    const int Mc = Tc * 64;
    for (int ch = 0; ch < nch; ++ch) {
        const float* xch = x + (size_t)ch * Tc * 256;   // s-offset in x[b][s][k]
        // encoder chunk: Ec[t*64+b][e] = PReLU(x[b][s][:] . Wenc + benc)
        gemm_k<2, 0, true><<<dim3(8, Mc / 128), 256, 0, stream>>>(
            xch, Wenc, Ec, benc, nullptr, alpha, Mc, 512, 256, 65536, 256);
        // Gx0 chunk = Ec @ Wx0 + bx0 + bh0 -> G [t][j][b]
        gemm_k<0, 1, false><<<dim3(64, Mc / 128), 256, 0, stream>>>(
            Ec, Wx0, G, bx0, bh0, nullptr, Mc, 4096, 512, 0, 0);
        // LSTM layer 0 chunk (cooperative)
        {
            const float* h0arg = (ch == 0) ? h0 : nullptr;
            const float* c0arg = (ch == 0) ? c0 : nullptr;
            float* Yarg = Y0c;
            void* args[] = {(void*)&G, (void*)&WhT0, (void*)&h0arg,
                            (void*)&c0arg, (void*)&hst0, (void*)&cst0,
                            (void*)&hA, (void*)&hB, (void*)&Yarg, (void*)&Tc};
            hipLaunchCooperativeKernel((void*)lstm_k, dim3(256), dim3(512),
                                       args, 0, stream);
        }
        // Gx1 chunk = Y0c @ Wx1 + bx1 + bh1 -> G
        gemm_k<1, 1, false><<<dim3(64, Mc / 128), 256, 0, stream>>>(
            Y0c, Wx1, G, bx1, bh1, nullptr, Mc, 4096, 1024, 0, 0);
        // LSTM layer 1 chunk (cooperative, no Y)
        {
            const float* h0arg = (ch == 0) ? h0 + 65536 : nullptr;
            const float* c0arg = (ch == 0) ? c0 + 65536 : nullptr;
            float* Yarg = nullptr;
            void* args[] = {(void*)&G, (void*)&WhT1, (void*)&h0arg,
                            (void*)&c0arg, (void*)&hst1, (void*)&cst1,
                            (void*)&hA, (void*)&hB, (void*)&Yarg, (void*)&Tc};
            hipLaunchCooperativeKernel((void*)lstm_k, dim3(256), dim3(512),
                                       args, 0, stream);
        }
    }
    // classifier from layer-1 final h state ([k][b])
    cls_k<<<dim3(10), 256, 0, stream>>>(hst1, Wcls, bcls, out);
}

// Round 4
// 23668.399 us; speedup vs baseline: 1.3059x; 1.3059x over previous
//
#include <hip/hip_runtime.h>
#include <hip/hip_bf16.h>
#include <cstddef>

// ---------------------------------------------------------------------------
// B=64, S=256, W=256, E=512, HID=1024, L=2, NCLS=10
// enc GEMM(fp32,split-out) -> Gx MFMA GEMM (bf16 hi/lo 3-pass) -> persistent
// LSTM (custom grid barrier) -> repack -> layer 2 -> classifier.
// m-index convention everywhere: m = t*64 + b.
// ---------------------------------------------------------------------------

using short8 = __attribute__((ext_vector_type(8))) short;
using f32x4  = __attribute__((ext_vector_type(4))) float;

__device__ __forceinline__ float sigmoidf_(float x) {
    return 1.f / (1.f + __expf(-x));
}
__device__ __forceinline__ unsigned short f2bf(float x) {   // RNE bf16
    union { float f; unsigned u; } v; v.f = x;
    unsigned r = v.u + 0x7fffu + ((v.u >> 16) & 1u);
    return (unsigned short)(r >> 16);
}
__device__ __forceinline__ float bf2f(unsigned short h) {
    union { unsigned u; float f; } v; v.u = ((unsigned)h) << 16;
    return v.f;
}

// ---------------- encoder GEMM (fp32 compute, bf16-split output) -----------
// A: x via [b=r&63][s=r>>6][k] (sB,sS strides). C: hi/lo bf16 planes [M][N].
__global__ __launch_bounds__(256) void enc_gemm_k(
    const float* __restrict__ A, const float* __restrict__ B,
    unsigned short* __restrict__ Chi, unsigned short* __restrict__ Clo,
    const float* __restrict__ bias1, const float* __restrict__ alphap,
    int M, int N, int K, int sB, int sS)
{
    __shared__ float As[128][17];
    __shared__ float Bs[16][64];
    const int tid = threadIdx.x;
    const int tx = tid & 15, ty = tid >> 4;
    const int rb = blockIdx.y * 128;
    const int cb = blockIdx.x * 64;

    float acc[8][4];
#pragma unroll
    for (int i = 0; i < 8; ++i)
#pragma unroll
        for (int j = 0; j < 4; ++j) acc[i][j] = 0.f;

    const int nk = K >> 4;
    for (int kt = 0; kt < nk; ++kt) {
        const int k0 = kt << 4;
        __syncthreads();
        {
            const int row = tid >> 2, k4 = tid & 3;
#pragma unroll
            for (int h = 0; h < 2; ++h) {
                const int r = rb + row + h * 64;
                const float4 v = *reinterpret_cast<const float4*>(
                    &A[(size_t)(r & 63) * sB + (size_t)(r >> 6) * sS + k0 + k4 * 4]);
                As[row + h * 64][k4 * 4 + 0] = v.x;
                As[row + h * 64][k4 * 4 + 1] = v.y;
                As[row + h * 64][k4 * 4 + 2] = v.z;
                As[row + h * 64][k4 * 4 + 3] = v.w;
            }
        }
        {
            const int bk = tid >> 4, c4 = tid & 15;
            *reinterpret_cast<float4*>(&Bs[bk][c4 * 4]) =
                *reinterpret_cast<const float4*>(
                    &B[(size_t)(k0 + bk) * N + cb + c4 * 4]);
        }
        __syncthreads();
#pragma unroll
        for (int k = 0; k < 16; ++k) {
            float a[8];
#pragma unroll
            for (int i = 0; i < 8; ++i) a[i] = As[ty * 8 + i][k];
            const float4 bv = *reinterpret_cast<const float4*>(&Bs[k][tx * 4]);
#pragma unroll
            for (int i = 0; i < 8; ++i) {
                acc[i][0] = fmaf(a[i], bv.x, acc[i][0]);
                acc[i][1] = fmaf(a[i], bv.y, acc[i][1]);
                acc[i][2] = fmaf(a[i], bv.z, acc[i][2]);
                acc[i][3] = fmaf(a[i], bv.w, acc[i][3]);
            }
        }
    }

    float bsum[4];
#pragma unroll
    for (int j = 0; j < 4; ++j) bsum[j] = bias1[cb + tx * 4 + j];
    const float alpha = alphap[0];
#pragma unroll
    for (int i = 0; i < 8; ++i) {
        const int r = rb + ty * 8 + i;
        unsigned hpack[2], lpack[2];
        unsigned short hs[4], ls[4];
#pragma unroll
        for (int j = 0; j < 4; ++j) {
            float v = acc[i][j] + bsum[j];
            v = (v >= 0.f) ? v : alpha * v;
            hs[j] = f2bf(v);
            ls[j] = f2bf(v - bf2f(hs[j]));
        }
        hpack[0] = (unsigned)hs[0] | ((unsigned)hs[1] << 16);
        hpack[1] = (unsigned)hs[2] | ((unsigned)hs[3] << 16);
        lpack[0] = (unsigned)ls[0] | ((unsigned)ls[1] << 16);
        lpack[1] = (unsigned)ls[2] | ((unsigned)ls[3] << 16);
        const size_t o = (size_t)r * N + cb + tx * 4;
        *reinterpret_cast<uint2*>(&Chi[o]) = make_uint2(hpack[0], hpack[1]);
        *reinterpret_cast<uint2*>(&Clo[o]) = make_uint2(lpack[0], lpack[1]);
    }
}

// ------------- weight split+transpose: W[K][4096] f32 -> Bt hi/lo [4096][K] -
__global__ __launch_bounds__(256) void bsplit_k(
    const float* __restrict__ W, unsigned short* __restrict__ Bhi,
    unsigned short* __restrict__ Blo, int K)
{
    __shared__ float tl[32][65];
    const int k0 = blockIdx.x * 32, n0 = blockIdx.y * 64;
    const int tid = threadIdx.x;
    {
        const int kk = tid >> 3, nq = tid & 7;
#pragma unroll
        for (int j = 0; j < 2; ++j) {
            const float4 v = *reinterpret_cast<const float4*>(
                &W[(size_t)(k0 + kk) * 4096 + n0 + nq * 8 + j * 4]);
            tl[kk][nq * 8 + j * 4 + 0] = v.x; tl[kk][nq * 8 + j * 4 + 1] = v.y;
            tl[kk][nq * 8 + j * 4 + 2] = v.z; tl[kk][nq * 8 + j * 4 + 3] = v.w;
        }
    }
    __syncthreads();
    const int n = tid >> 2, kq = tid & 3;
    short8 hv, lv;
#pragma unroll
    for (int j = 0; j < 8; ++j) {
        const float x = tl[kq * 8 + j][n];
        const unsigned short h = f2bf(x);
        hv[j] = (short)h;
        lv[j] = (short)f2bf(x - bf2f(h));
    }
    const size_t o = (size_t)(n0 + n) * K + k0 + kq * 8;
    *reinterpret_cast<short8*>(&Bhi[o]) = hv;
    *reinterpret_cast<short8*>(&Blo[o]) = lv;
}

// ------------- repack Y0 [t][k=1024][b=64] f32 -> A hi/lo [t*64+b][1024] ----
__global__ __launch_bounds__(256) void repack_k(
    const float* __restrict__ Y, unsigned short* __restrict__ Ahi,
    unsigned short* __restrict__ Alo)
{
    __shared__ float tl[64][65];
    const int t = blockIdx.y, kt = blockIdx.x;          // kt: 0..15
    const int tid = threadIdx.x;
    {
        const int kk = tid >> 2, bq = tid & 3;
#pragma unroll
        for (int j = 0; j < 4; ++j) {
            const float4 v = *reinterpret_cast<const float4*>(
                &Y[((size_t)t * 1024 + kt * 64 + kk) * 64 + bq * 16 + j * 4]);
            tl[kk][bq * 16 + j * 4 + 0] = v.x; tl[kk][bq * 16 + j * 4 + 1] = v.y;
            tl[kk][bq * 16 + j * 4 + 2] = v.z; tl[kk][bq * 16 + j * 4 + 3] = v.w;
        }
    }
    __syncthreads();
    const int b = tid >> 2, kq = tid & 3;
#pragma unroll
    for (int j = 0; j < 2; ++j) {
        short8 hv, lv;
#pragma unroll
        for (int e = 0; e < 8; ++e) {
            const float x = tl[kq * 16 + j * 8 + e][b];
            const unsigned short h = f2bf(x);
            hv[e] = (short)h;
            lv[e] = (short)f2bf(x - bf2f(h));
        }
        const size_t o = ((size_t)t * 64 + b) * 1024 + kt * 64 + kq * 16 + j * 8;
        *reinterpret_cast<short8*>(&Ahi[o]) = hv;
        *reinterpret_cast<short8*>(&Alo[o]) = lv;
    }
}

// ------------- MFMA split-bf16 GEMM: G[t][j][b] = A[M,K]@Wx[K,4096]+bx+bh ---
// A planes row-major [M][K] bf16; B planes transposed [4096][K] bf16.
// BM=128, BN=128, BK=32, 4 waves (2x2), wave tile 64x64.
__global__ __launch_bounds__(256) void gemm_mfma_k(
    const unsigned short* __restrict__ Ahi, const unsigned short* __restrict__ Alo,
    const unsigned short* __restrict__ Bhi, const unsigned short* __restrict__ Blo,
    float* __restrict__ G, const float* __restrict__ bx,
    const float* __restrict__ bh, int K)
{
    __shared__ float smemf[10240];                       // 40 KB
    unsigned short* const smemh = (unsigned short*)smemf;
    unsigned short* const As0 = smemh;                   // hi A tile
    unsigned short* const As1 = smemh + 5120;            // lo A tile
    unsigned short* const Bs0 = smemh + 10240;           // hi B tile
    unsigned short* const Bs1 = smemh + 15360;           // lo B tile

    const int tid = threadIdx.x;
    const int lane = tid & 63, wid = tid >> 6;
    const int wm = wid >> 1, wn = wid & 1;
    const int m0 = blockIdx.y * 128;
    const int n0 = blockIdx.x * 128;

    f32x4 acc[4][4] = {};

    const int sr = tid & 127;                            // staging row
    const int spl = tid >> 7;                            // staging plane
    const unsigned short* Ag = (spl ? Alo : Ahi) + (size_t)(m0 + sr) * K;
    const unsigned short* Bg = (spl ? Blo : Bhi) + (size_t)(n0 + sr) * K;
    unsigned short* Asw = (spl ? As1 : As0) + sr * 40;
    unsigned short* Bsw = (spl ? Bs1 : Bs0) + sr * 40;
    const int sw = sr & 3;

    const int kg = lane >> 4;                            // frag k-chunk
    const int fr = lane & 15;

    for (int k0 = 0; k0 < K; k0 += 32) {
        short8 av[4], bv[4];
#pragma unroll
        for (int c = 0; c < 4; ++c) {
            av[c] = *reinterpret_cast<const short8*>(Ag + k0 + c * 8);
            bv[c] = *reinterpret_cast<const short8*>(Bg + k0 + c * 8);
        }
        __syncthreads();
#pragma unroll
        for (int c = 0; c < 4; ++c) {
            *reinterpret_cast<short8*>(Asw + ((c ^ sw) * 8)) = av[c];
            *reinterpret_cast<short8*>(Bsw + ((c ^ sw) * 8)) = bv[c];
        }
        __syncthreads();

        short8 af[2][4], bf[2][4];
#pragma unroll
        for (int i = 0; i < 4; ++i) {
            const int ra = wm * 64 + i * 16 + fr;
            const int rb = wn * 64 + i * 16 + fr;
            af[0][i] = *reinterpret_cast<const short8*>(
                As0 + ra * 40 + ((kg ^ (ra & 3)) * 8));
            af[1][i] = *reinterpret_cast<const short8*>(
                As1 + ra * 40 + ((kg ^ (ra & 3)) * 8));
            bf[0][i] = *reinterpret_cast<const short8*>(
                Bs0 + rb * 40 + ((kg ^ (rb & 3)) * 8));
            bf[1][i] = *reinterpret_cast<const short8*>(
                Bs1 + rb * 40 + ((kg ^ (rb & 3)) * 8));
        }
#pragma unroll
        for (int i = 0; i < 4; ++i)
#pragma unroll
            for (int j = 0; j < 4; ++j) {
                acc[i][j] = __builtin_amdgcn_mfma_f32_16x16x32_bf16(
                    af[0][i], bf[0][j], acc[i][j], 0, 0, 0);
                acc[i][j] = __builtin_amdgcn_mfma_f32_16x16x32_bf16(
                    af[0][i], bf[1][j], acc[i][j], 0, 0, 0);
                acc[i][j] = __builtin_amdgcn_mfma_f32_16x16x32_bf16(
                    af[1][i], bf[0][j], acc[i][j], 0, 0, 0);
            }
    }
    __syncthreads();                                     // staging LDS now dead

    // Epilogue: per-wave [16 n][65] f32 slab -> coalesced G[t][j][b] stores.
    float* slab = smemf + wid * 1040;
    const int t = (m0 + wm * 64) >> 6;
    const int fq = lane >> 4;
#pragma unroll 1
    for (int j = 0; j < 4; ++j) {
        const int ncol = n0 + wn * 64 + j * 16 + fr;
        const float bias = bx[ncol] + bh[ncol];
#pragma unroll
        for (int i = 0; i < 4; ++i)
#pragma unroll
            for (int rr = 0; rr < 4; ++rr)
                slab[fr * 65 + i * 16 + fq * 4 + rr] = acc[i][j][rr] + bias;
        __syncthreads();                                 // slab write -> read
        const int nrow = lane >> 2, q = lane & 3;
        float* gp = &G[(size_t)t * 262144 +
                       (size_t)(n0 + wn * 64 + j * 16 + nrow) * 64 + q * 16];
#pragma unroll
        for (int v = 0; v < 4; ++v) {
            float4 o;
            o.x = slab[nrow * 65 + q * 16 + v * 4 + 0];
            o.y = slab[nrow * 65 + q * 16 + v * 4 + 1];
            o.z = slab[nrow * 65 + q * 16 + v * 4 + 2];
            o.w = slab[nrow * 65 + q * 16 + v * 4 + 3];
            *reinterpret_cast<float4*>(gp + v * 4) = o;
        }
        __syncthreads();                                 // before next overwrite
    }
}

// ---------------- transpose (Wh -> WhT), fp32 -------------------------------
__global__ __launch_bounds__(256) void transpose_k(
    const float* __restrict__ in, float* __restrict__ out, int R, int Cc)
{
    __shared__ float tile[32][33];
    const int tx = threadIdx.x & 31, ty = threadIdx.x >> 5;
    const int rb = blockIdx.y * 32, cb = blockIdx.x * 32;
#pragma unroll
    for (int yy = 0; yy < 32; yy += 8)
        tile[ty + yy][tx] = in[(size_t)(rb + ty + yy) * Cc + cb + tx];
    __syncthreads();
#pragma unroll
    for (int yy = 0; yy < 32; yy += 8)
        out[(size_t)(cb + ty + yy) * R + rb + tx] = tile[tx][ty + yy];
}

// ---------------- custom grid barrier (two-level, generation-based) --------
__device__ __forceinline__ void gbar(unsigned* bar, int bid, unsigned gen) {
    __syncthreads();
    if (threadIdx.x == 0) {
        __threadfence();                                  // release
        unsigned* grp  = bar + ((bid >> 5) * 16);         // 8 groups x 64B
        unsigned* root = bar + 128;
        unsigned* go   = bar + 160;
        __hip_atomic_fetch_add(grp, 1u, __ATOMIC_RELAXED,
                               __HIP_MEMORY_SCOPE_AGENT);
        if ((bid & 31) == 0) {
            while (__hip_atomic_load(grp, __ATOMIC_RELAXED,
                                     __HIP_MEMORY_SCOPE_AGENT) < 32u * gen)
                __builtin_amdgcn_s_sleep(1);
            __hip_atomic_fetch_add(root, 1u, __ATOMIC_RELAXED,
                                   __HIP_MEMORY_SCOPE_AGENT);
        }
        if (bid == 0) {
            while (__hip_atomic_load(root, __ATOMIC_RELAXED,
                                     __HIP_MEMORY_SCOPE_AGENT) < 8u * gen)
                __builtin_amdgcn_s_sleep(1);
            __hip_atomic_store(go, gen, __ATOMIC_RELEASE,
                               __HIP_MEMORY_SCOPE_AGENT);
        }
        while (__hip_atomic_load(go, __ATOMIC_RELAXED,
                                 __HIP_MEMORY_SCOPE_AGENT) < gen)
            __builtin_amdgcn_s_sleep(1);
        __threadfence();                                  // acquire
    }
    __syncthreads();
}

// ---------------- persistent LSTM layer (256 blocks x 512 threads) ---------
__global__ __launch_bounds__(512) void lstm_k(
    const float* __restrict__ G, const float* __restrict__ WhT,
    const float* __restrict__ h0row, const float* __restrict__ c0row,
    float* __restrict__ hstate, float* __restrict__ cstate,
    float* __restrict__ hA, float* __restrict__ hB, float* __restrict__ Y,
    int Tc, unsigned* bar)
{
    __shared__ float hS[2 * 8192];
    float* partS = hS;

    const int tid = threadIdx.x;
    const int lane = tid & 63;
    const int w = tid >> 6;
    const int wq = w & 3;
    const int half = w >> 2;
    const int bid = blockIdx.x;
    const int colh = bid * 4 + wq;
    const int ucolh = __builtin_amdgcn_readfirstlane(colh);
    const int uhalf = __builtin_amdgcn_readfirstlane(half);

    const float* __restrict__ wfp = WhT + (size_t)ucolh * 1024 + uhalf * 512;
    const float* __restrict__ wip = WhT + (size_t)(ucolh + 1024) * 1024 + uhalf * 512;
    const float* __restrict__ wgp = WhT + (size_t)(ucolh + 2048) * 1024 + uhalf * 512;
    const float* __restrict__ wop = WhT + (size_t)(ucolh + 3072) * 1024 + uhalf * 512;

    {
        const int idx = bid * 512 + tid;
        if (idx < 65536)
            hA[idx] = h0row ? h0row[(idx & 63) * 1024 + (idx >> 6)]
                            : hstate[idx];
    }
    float c = c0row ? c0row[lane * 1024 + ucolh] : cstate[ucolh * 64 + lane];
    unsigned gen = 1;
    gbar(bar, bid, gen++);

    for (int t = 0; t < Tc; ++t) {
        const float* hread = (t & 1) ? hB : hA;
        float* hwrite = (t & 1) ? hA : hB;
        float pf = 0.f, pi = 0.f, pg = 0.f, po = 0.f;

        float gx0 = 0.f, gx1 = 0.f, gx2 = 0.f, gx3 = 0.f;
        if (!half) {                                     // prefetch gate-x
            const size_t gb = (size_t)t * 262144 + (size_t)colh * 64 + lane;
            gx0 = G[gb]; gx1 = G[gb + 65536];
            gx2 = G[gb + 131072]; gx3 = G[gb + 196608];
        }

        for (int cc = 0; cc < 4; ++cc) {
            __syncthreads();
#pragma unroll
            for (int p = 0; p < 4; ++p) {
                const int off = p * 2048 + tid * 4;
                *reinterpret_cast<float4*>(&hS[off]) =
                    *reinterpret_cast<const float4*>(&hread[cc * 8192 + off]);
                *reinterpret_cast<float4*>(&hS[8192 + off]) =
                    *reinterpret_cast<const float4*>(
                        &hread[32768 + cc * 8192 + off]);
            }
            __syncthreads();
            const float* hc = hS + half * 8192;
            const float* wf = wfp + cc * 128;
            const float* wi = wip + cc * 128;
            const float* wg = wgp + cc * 128;
            const float* wo = wop + cc * 128;
#pragma unroll 2
            for (int kk = 0; kk < 128; kk += 4) {
                const float4 vf = *reinterpret_cast<const float4*>(&wf[kk]);
                const float4 vi = *reinterpret_cast<const float4*>(&wi[kk]);
                const float4 vg = *reinterpret_cast<const float4*>(&wg[kk]);
                const float4 vo = *reinterpret_cast<const float4*>(&wo[kk]);
                const float h0v = hc[(kk + 0) * 64 + lane];
                const float h1v = hc[(kk + 1) * 64 + lane];
                const float h2v = hc[(kk + 2) * 64 + lane];
                const float h3v = hc[(kk + 3) * 64 + lane];
                pf = fmaf(h0v, vf.x, pf); pf = fmaf(h1v, vf.y, pf);
                pf = fmaf(h2v, vf.z, pf); pf = fmaf(h3v, vf.w, pf);
                pi = fmaf(h0v, vi.x, pi); pi = fmaf(h1v, vi.y, pi);
                pi = fmaf(h2v, vi.z, pi); pi = fmaf(h3v, vi.w, pi);
                pg = fmaf(h0v, vg.x, pg); pg = fmaf(h1v, vg.y, pg);
                pg = fmaf(h2v, vg.z, pg); pg = fmaf(h3v, vg.w, pg);
                po = fmaf(h0v, vo.x, po); po = fmaf(h1v, vo.y, po);
                po = fmaf(h2v, vo.z, po); po = fmaf(h3v, vo.w, po);
            }
        }
        __syncthreads();
        if (half) {
            partS[(wq * 4 + 0) * 64 + lane] = pf;
            partS[(wq * 4 + 1) * 64 + lane] = pi;
            partS[(wq * 4 + 2) * 64 + lane] = pg;
            partS[(wq * 4 + 3) * 64 + lane] = po;
        }
        __syncthreads();
        if (!half) {
            pf += partS[(wq * 4 + 0) * 64 + lane];
            pi += partS[(wq * 4 + 1) * 64 + lane];
            pg += partS[(wq * 4 + 2) * 64 + lane];
            po += partS[(wq * 4 + 3) * 64 + lane];
            const float f = sigmoidf_(gx0 + pf);
            const float i = sigmoidf_(gx1 + pi);
            const float g = tanhf(gx2 + pg);
            const float o = sigmoidf_(gx3 + po);
            c = fmaf(f, c, i * g);
            const float h = o * tanhf(c);
            hwrite[colh * 64 + lane] = h;
            if (Y) Y[(size_t)t * 65536 + colh * 64 + lane] = h;
            if (t == Tc - 1) {
                hstate[colh * 64 + lane] = h;
                cstate[colh * 64 + lane] = c;
            }
        }
        gbar(bar, bid, gen++);
    }
}

// ---------------- classifier ------------------------------------------------
__global__ __launch_bounds__(256) void cls_k(
    const float* __restrict__ hfin, const float* __restrict__ Wc,
    const float* __restrict__ bcls, float* __restrict__ out)
{
    __shared__ float red[4][64];
    const int n = blockIdx.x;
    const int lane = threadIdx.x & 63, w = threadIdx.x >> 6;
    float acc = 0.f;
    for (int k = w * 256; k < w * 256 + 256; ++k)
        acc = fmaf(hfin[k * 64 + lane], Wc[k * 10 + n], acc);
    red[w][lane] = acc;
    __syncthreads();
    if (w == 0) {
        out[lane * 10 + n] = red[0][lane] + red[1][lane] + red[2][lane] +
                             red[3][lane] + bcls[n];
    }
}

extern "C" void kernel_launch(void* const* d_in, const int* in_sizes, int n_in,
                              void* d_out, int out_size, void* d_ws,
                              size_t ws_size, hipStream_t stream)
{
    const float* x    = (const float*)d_in[0];
    const float* h0   = (const float*)d_in[1];
    const float* c0   = (const float*)d_in[2];
    const float* Wenc = (const float*)d_in[3];
    const float* benc = (const float*)d_in[4];
    const float* alpha= (const float*)d_in[5];
    const float* Wx0  = (const float*)d_in[6];
    const float* bx0  = (const float*)d_in[7];
    const float* Wh0  = (const float*)d_in[8];
    const float* bh0  = (const float*)d_in[9];
    const float* Wx1  = (const float*)d_in[10];
    const float* bx1  = (const float*)d_in[11];
    const float* Wh1  = (const float*)d_in[12];
    const float* bh1  = (const float*)d_in[13];
    const float* Wcls = (const float*)d_in[14];
    const float* bcls = (const float*)d_in[15];
    float* out = (float*)d_out;

    // Adaptive chunking: fixed ~15.2M floats + 425,984 floats per timestep.
    const size_t ws_f = ws_size / sizeof(float);
    const size_t fixed = 15138816 + 65536;
    int Tc = 256;
    while (Tc > 2 && fixed + (size_t)Tc * 425984 > ws_f) Tc >>= 1;
    const int nch = 256 / Tc;
    const int Mc = Tc * 64;

    float* ws = (float*)d_ws;
    size_t off = 0;
    float* G    = ws + off; off += (size_t)Tc * 262144;
    float* Y0c  = ws + off; off += (size_t)Tc * 65536;
    unsigned short* Ehi  = (unsigned short*)(ws + off); off += (size_t)Tc * 16384;
    unsigned short* Elo  = (unsigned short*)(ws + off); off += (size_t)Tc * 16384;
    unsigned short* A1hi = (unsigned short*)(ws + off); off += (size_t)Tc * 32768;
    unsigned short* A1lo = (unsigned short*)(ws + off); off += (size_t)Tc * 32768;
    unsigned short* B0hi = (unsigned short*)(ws + off); off += 1048576;
    unsigned short* B0lo = (unsigned short*)(ws + off); off += 1048576;
    unsigned short* B1hi = (unsigned short*)(ws + off); off += 2097152;
    unsigned short* B1lo = (unsigned short*)(ws + off); off += 2097152;
    float* WhT0 = ws + off; off += 4194304;
    float* WhT1 = ws + off; off += 4194304;
    float* hA   = ws + off; off += 65536;
    float* hB   = ws + off; off += 65536;
    float* hst0 = ws + off; off += 65536;
    float* hst1 = ws + off; off += 65536;
    float* cst0 = ws + off; off += 65536;
    float* cst1 = ws + off; off += 65536;
    unsigned* bars = (unsigned*)(ws + off);

    (void)hipMemsetAsync(bars, 0, (size_t)2 * nch * 256 * sizeof(unsigned),
                         stream);

    transpose_k<<<dim3(128, 32), 256, 0, stream>>>(Wh0, WhT0, 1024, 4096);
    transpose_k<<<dim3(128, 32), 256, 0, stream>>>(Wh1, WhT1, 1024, 4096);
    bsplit_k<<<dim3(16, 64), 256, 0, stream>>>(Wx0, B0hi, B0lo, 512);
    bsplit_k<<<dim3(32, 64), 256, 0, stream>>>(Wx1, B1hi, B1lo, 1024);

    for (int ch = 0; ch < nch; ++ch) {
        const float* xch = x + (size_t)ch * Tc * 256;
        // encoder chunk -> bf16-split E
        enc_gemm_k<<<dim3(8, Mc / 128), 256, 0, stream>>>(
            xch, Wenc, Ehi, Elo, benc, alpha, Mc, 512, 256, 65536, 256);
        // Gx0 = E @ Wx0 + bx0 + bh0 (MFMA split)
        gemm_mfma_k<<<dim3(32, Mc / 128), 256, 0, stream>>>(
            Ehi, Elo, B0hi, B0lo, G, bx0, bh0, 512);
        // LSTM layer 0
        {
            const float* h0a = (ch == 0) ? h0 : nullptr;
            const float* c0a = (ch == 0) ? c0 : nullptr;
            lstm_k<<<256, 512, 0, stream>>>(G, WhT0, h0a, c0a, hst0, cst0,
                                            hA, hB, Y0c, Tc,
                                            bars + (size_t)(ch * 2) * 256);
        }
        // repack Y0 -> bf16-split A1
        repack_k<<<dim3(16, Tc), 256, 0, stream>>>(Y0c, A1hi, A1lo);
        // Gx1 = Y0 @ Wx1 + bx1 + bh1 (MFMA split)
        gemm_mfma_k<<<dim3(32, Mc / 128), 256, 0, stream>>>(
            A1hi, A1lo, B1hi, B1lo, G, bx1, bh1, 1024);
        // LSTM layer 1
        {
            const float* h0a = (ch == 0) ? h0 + 65536 : nullptr;
            const float* c0a = (ch == 0) ? c0 + 65536 : nullptr;
            lstm_k<<<256, 512, 0, stream>>>(G, WhT1, h0a, c0a, hst1, cst1,
                                            hA, hB, (float*)nullptr, Tc,
                                            bars + (size_t)(ch * 2 + 1) * 256);
        }
    }
    cls_k<<<dim3(10), 256, 0, stream>>>(hst1, Wcls, bcls, out);
}

// Round 6
// 5848.284 us; speedup vs baseline: 5.2852x; 4.0471x over previous
//
#include <hip/hip_runtime.h>
#include <hip/hip_bf16.h>
#include <cstddef>

// ---------------------------------------------------------------------------
// B=64, S=256, W=256, E=512, HID=1024, L=2, NCLS=10
// enc GEMM (fp32 -> bf16-split E in MFMA-fragment granule order) ->
// ONE fused dual-layer pipelined LSTM:
//   blocks 0..127  = layer 0, K=1536 ([Wh0; Wx0]), reads h0-granules + E-granules
//   blocks 128..255 = layer 1, K=2048 ([Wh1; Wx1]), reads h1-granules + y0-granules
//   257 rounds, layer 1 lags layer 0 by one step; custom grid barrier.
// -> classifier.
// Fragment layouts (HW-validated round 4, absmax 7.6e-6):
//   A/B operand: lane = (row&15) + 16*kg holds 8 values [row][k0+kg*8 .. +7]
//   D: row = mi*16 + (lane>>4)*4 + rr, col = nj*16 + (lane&15)
// Granule stores (all 16B/lane):
//   W:  Wf[lb][plane][s][mi][lane][8]
//   h:  hbuf[par][plane][s(32)][nj][lane][8]   (plane stride 65536 shorts)
//   E:  Ef[t][plane][s(16)][nj][lane][8]       (plane stride 32768 shorts)
// Row permutation: gate row j=g*1024+lb*8+c  ->  block lb, rloc=g*8+c.
// Workspace total ~94 MB (known-good budget is >=279 MB).
// ---------------------------------------------------------------------------

using short8 = __attribute__((ext_vector_type(8))) short;
using f32x4  = __attribute__((ext_vector_type(4))) float;

#define LD8(p) (*reinterpret_cast<const short8*>(p))

__device__ __forceinline__ float sigmoidf_(float x) {
    return 1.f / (1.f + __expf(-x));
}
__device__ __forceinline__ unsigned short f2bf(float x) {   // RNE bf16
    union { float f; unsigned u; } v; v.f = x;
    unsigned r = v.u + 0x7fffu + ((v.u >> 16) & 1u);
    return (unsigned short)(r >> 16);
}
__device__ __forceinline__ float bf2f(unsigned short h) {
    union { unsigned u; float f; } v; v.u = ((unsigned)h) << 16;
    return v.f;
}

// ---------------- encoder GEMM (fp32 compute, granule bf16-split output) ---
// A: x via [b=r&63][s=r>>6][k] (sB,sS strides). Output straight into Ef.
__global__ __launch_bounds__(256) void enc_gemm_k(
    const float* __restrict__ A, const float* __restrict__ B,
    unsigned short* __restrict__ Ef,
    const float* __restrict__ bias1, const float* __restrict__ alphap,
    int M, int N, int K, int sB, int sS)
{
    __shared__ float As[128][17];
    __shared__ float Bs[16][64];
    const int tid = threadIdx.x;
    const int tx = tid & 15, ty = tid >> 4;
    const int rb = blockIdx.y * 128;
    const int cb = blockIdx.x * 64;

    float acc[8][4];
#pragma unroll
    for (int i = 0; i < 8; ++i)
#pragma unroll
        for (int j = 0; j < 4; ++j) acc[i][j] = 0.f;

    const int nk = K >> 4;
    for (int kt = 0; kt < nk; ++kt) {
        const int k0 = kt << 4;
        __syncthreads();
        {
            const int row = tid >> 2, k4 = tid & 3;
#pragma unroll
            for (int h = 0; h < 2; ++h) {
                const int r = rb + row + h * 64;
                const float4 v = *reinterpret_cast<const float4*>(
                    &A[(size_t)(r & 63) * sB + (size_t)(r >> 6) * sS + k0 + k4 * 4]);
                As[row + h * 64][k4 * 4 + 0] = v.x;
                As[row + h * 64][k4 * 4 + 1] = v.y;
                As[row + h * 64][k4 * 4 + 2] = v.z;
                As[row + h * 64][k4 * 4 + 3] = v.w;
            }
        }
        {
            const int bk = tid >> 4, c4 = tid & 15;
            *reinterpret_cast<float4*>(&Bs[bk][c4 * 4]) =
                *reinterpret_cast<const float4*>(
                    &B[(size_t)(k0 + bk) * N + cb + c4 * 4]);
        }
        __syncthreads();
#pragma unroll
        for (int k = 0; k < 16; ++k) {
            float a[8];
#pragma unroll
            for (int i = 0; i < 8; ++i) a[i] = As[ty * 8 + i][k];
            const float4 bv = *reinterpret_cast<const float4*>(&Bs[k][tx * 4]);
#pragma unroll
            for (int i = 0; i < 8; ++i) {
                acc[i][0] = fmaf(a[i], bv.x, acc[i][0]);
                acc[i][1] = fmaf(a[i], bv.y, acc[i][1]);
                acc[i][2] = fmaf(a[i], bv.z, acc[i][2]);
                acc[i][3] = fmaf(a[i], bv.w, acc[i][3]);
            }
        }
    }

    float bsum[4];
#pragma unroll
    for (int j = 0; j < 4; ++j) bsum[j] = bias1[cb + tx * 4 + j];
    const float alpha = alphap[0];
    const int k0c = cb + tx * 4;
    const int s = k0c >> 5, kg = (k0c >> 3) & 3, e0 = k0c & 7;
#pragma unroll
    for (int i = 0; i < 8; ++i) {
        const int r = rb + ty * 8 + i;
        const int t = r >> 6, b = r & 63;
        const int ln = (b & 15) + 16 * kg, nj = b >> 4;
        unsigned short hs[4], ls[4];
#pragma unroll
        for (int j = 0; j < 4; ++j) {
            float v = acc[i][j] + bsum[j];
            v = (v >= 0.f) ? v : alpha * v;
            hs[j] = f2bf(v);
            ls[j] = f2bf(v - bf2f(hs[j]));
        }
        uint2 hp, lp;
        hp.x = (unsigned)hs[0] | ((unsigned)hs[1] << 16);
        hp.y = (unsigned)hs[2] | ((unsigned)hs[3] << 16);
        lp.x = (unsigned)ls[0] | ((unsigned)ls[1] << 16);
        lp.y = (unsigned)ls[2] | ((unsigned)ls[3] << 16);
        const size_t base =
            ((((size_t)t * 32 + s) * 4 + nj) * 64 + ln) * 8 + e0;
        *reinterpret_cast<uint2*>(Ef + base) = hp;            // hi plane
        *reinterpret_cast<uint2*>(Ef + base + 32768) = lp;    // lo plane
    }
}

// ------------- weight prep: frag-order split planes ------------------------
// Wf[lb][p][s][mi][lane][8]; source col j = g*1024 + lb*8 + c, row k.
// Wa covers k<1024, Wb covers k>=1024 (concat [Wh; Wx]). NS = K/32.
__global__ __launch_bounds__(256) void wprep_k(
    const float* __restrict__ Wa, const float* __restrict__ Wb,
    unsigned short* __restrict__ Wf, int NS)
{
    __shared__ float tl[32][65];
    const int k0 = blockIdx.x * 32, j0 = blockIdx.y * 64;
    const int tid = threadIdx.x;
    {
        const int kk = tid >> 3, jq = tid & 7;
        const int k = k0 + kk;
        const float* src = (k < 1024) ? &Wa[(size_t)k * 4096]
                                      : &Wb[(size_t)(k - 1024) * 4096];
#pragma unroll
        for (int h = 0; h < 2; ++h) {
            const float4 v = *reinterpret_cast<const float4*>(
                &src[j0 + jq * 8 + h * 4]);
            tl[kk][jq * 8 + h * 4 + 0] = v.x; tl[kk][jq * 8 + h * 4 + 1] = v.y;
            tl[kk][jq * 8 + h * 4 + 2] = v.z; tl[kk][jq * 8 + h * 4 + 3] = v.w;
        }
    }
    __syncthreads();
    const int j = tid >> 2, kg = tid & 3;
    const int jg = j0 + j;
    const int g = jg >> 10, cc = jg & 1023;
    const int lb = cc >> 3, c = cc & 7;
    const int rloc = g * 8 + c;
    const int mi = rloc >> 4, r16 = rloc & 15;
    const int lane = r16 + 16 * kg;
    const int s = k0 >> 5;
    short8 hv, lv;
#pragma unroll
    for (int e = 0; e < 8; ++e) {
        const float x = tl[kg * 8 + e][j];
        const unsigned short h = f2bf(x);
        hv[e] = (short)h;
        lv[e] = (short)f2bf(x - bf2f(h));
    }
    const size_t oH = ((((size_t)lb * 2 + 0) * NS + s) * 2 + mi) * 512 + (size_t)lane * 8;
    const size_t oL = ((((size_t)lb * 2 + 1) * NS + s) * 2 + mi) * 512 + (size_t)lane * 8;
    *reinterpret_cast<short8*>(Wf + oH) = hv;
    *reinterpret_cast<short8*>(Wf + oL) = lv;
}

// ------------- h split init: hrow fp32 [64][1024] -> granule planes --------
__global__ __launch_bounds__(256) void hsplit_k(
    const float* __restrict__ hrow, unsigned short* __restrict__ dst)
{
    const int idx = blockIdx.x * 256 + threadIdx.x;   // 8192 total
    const int b = idx >> 7, gc = idx & 127;
    const int k = gc * 8;
    short8 hv, lv;
#pragma unroll
    for (int e = 0; e < 8; ++e) {
        const float x = hrow[(size_t)b * 1024 + k + e];
        const unsigned short h = f2bf(x);
        hv[e] = (short)h;
        lv[e] = (short)f2bf(x - bf2f(h));
    }
    const int s = k >> 5, kg = (k >> 3) & 3, nj = b >> 4;
    const int l = (b & 15) + 16 * kg;
    const size_t oH = (((size_t)(0 * 32 + s) * 4 + nj) * 64 + l) * 8;
    const size_t oL = (((size_t)(1 * 32 + s) * 4 + nj) * 64 + l) * 8;
    *reinterpret_cast<short8*>(dst + oH) = hv;
    *reinterpret_cast<short8*>(dst + oL) = lv;
}

// ------------- permuted bias sum: out[lb*32+g*8+c] = bx[j]+bh[j] -----------
__global__ __launch_bounds__(256) void bsum_k(
    const float* __restrict__ bx, const float* __restrict__ bh,
    float* __restrict__ out)
{
    const int r = blockIdx.x * 256 + threadIdx.x;     // 4096
    const int lb = r >> 5, rl = r & 31;
    const int g = rl >> 3, c = rl & 7;
    const int j = g * 1024 + lb * 8 + c;
    out[r] = bx[j] + bh[j];
}

// ---------------- custom grid barrier (two-level, generation-based) --------
__device__ __forceinline__ void gbar(unsigned* bar, int bid, unsigned gen) {
    __syncthreads();
    if (threadIdx.x == 0) {
        __threadfence();
        unsigned* grp  = bar + ((bid >> 5) * 16);
        unsigned* root = bar + 128;
        unsigned* go   = bar + 160;
        __hip_atomic_fetch_add(grp, 1u, __ATOMIC_RELAXED,
                               __HIP_MEMORY_SCOPE_AGENT);
        if ((bid & 31) == 0) {
            while (__hip_atomic_load(grp, __ATOMIC_RELAXED,
                                     __HIP_MEMORY_SCOPE_AGENT) < 32u * gen)
                __builtin_amdgcn_s_sleep(1);
            __hip_atomic_fetch_add(root, 1u, __ATOMIC_RELAXED,
                                   __HIP_MEMORY_SCOPE_AGENT);
        }
        if (bid == 0) {
            while (__hip_atomic_load(root, __ATOMIC_RELAXED,
                                     __HIP_MEMORY_SCOPE_AGENT) < 8u * gen)
                __builtin_amdgcn_s_sleep(1);
            __hip_atomic_store(go, gen, __ATOMIC_RELEASE,
                               __HIP_MEMORY_SCOPE_AGENT);
        }
        while (__hip_atomic_load(go, __ATOMIC_RELAXED,
                                 __HIP_MEMORY_SCOPE_AGENT) < gen)
            __builtin_amdgcn_s_sleep(1);
        __threadfence();
    }
    __syncthreads();
}

// ---------------- fused dual-layer pipelined LSTM --------------------------
struct Frag {
    short8 w00, w01, w10, w11;      // Whi mi0/mi1, Wlo mi0/mi1
    short8 h0, h1, h2, h3;          // hhi nj0..3
    short8 l0, l1, l2, l3;          // hlo nj0..3
};

__device__ __forceinline__ void mma_frags(const Frag& f, f32x4 (&acc)[2][4]) {
#define MM(mi, nj, WH, WL, HH, HL)                                            \
    acc[mi][nj] = __builtin_amdgcn_mfma_f32_16x16x32_bf16(f.WH, f.HH, acc[mi][nj], 0, 0, 0); \
    acc[mi][nj] = __builtin_amdgcn_mfma_f32_16x16x32_bf16(f.WH, f.HL, acc[mi][nj], 0, 0, 0); \
    acc[mi][nj] = __builtin_amdgcn_mfma_f32_16x16x32_bf16(f.WL, f.HH, acc[mi][nj], 0, 0, 0);
    MM(0, 0, w00, w10, h0, l0)  MM(0, 1, w00, w10, h1, l1)
    MM(0, 2, w00, w10, h2, l2)  MM(0, 3, w00, w10, h3, l3)
    MM(1, 0, w01, w11, h0, l0)  MM(1, 1, w01, w11, h1, l1)
    MM(1, 2, w01, w11, h2, l2)  MM(1, 3, w01, w11, h3, l3)
#undef MM
}

__global__ __launch_bounds__(256, 1) void fused_lstm_k(
    const unsigned short* __restrict__ Ef,
    const unsigned short* __restrict__ Wf0,
    const unsigned short* __restrict__ Wf1,
    unsigned short* __restrict__ h0b, unsigned short* __restrict__ h1b,
    const float* __restrict__ c0, const float* __restrict__ bsum0p,
    const float* __restrict__ bsum1p, float* __restrict__ hst1,
    unsigned* bar)
{
    __shared__ float Pred[4][32][66];
    __shared__ unsigned short hasmH[64][8];
    __shared__ unsigned short hasmL[64][8];

    const int tid = threadIdx.x;
    const int lane = tid & 63;                 // = batch row b
    const int w = tid >> 6;                    // wave id 0..3
    const int bid = blockIdx.x;
    const int layer = bid >> 7;
    const int lb = bid & 127;

    const int NS = layer ? 64 : 48;            // K/32
    const int nsub = layer ? 16 : 12;          // subtiles per wave
    const int sub0 = w * nsub;
    const int wNS = NS * 1024;                 // plane offset in weight shorts

    const unsigned short* Wf = layer ? Wf1 : Wf0;
    const unsigned short* wB =
        Wf + (size_t)lb * 2 * NS * 1024 + (size_t)lane * 8;

    // c state: 2 h-columns per thread (cols 2w, 2w+1), b = lane
    float c_[2];
    c_[0] = c0[(size_t)layer * 65536 + (size_t)lane * 1024 + lb * 8 + 2 * w];
    c_[1] = c0[(size_t)layer * 65536 + (size_t)lane * 1024 + lb * 8 + 2 * w + 1];

    const float* bsB = layer ? bsum1p : bsum0p;
    float bs0[4], bs1[4];
#pragma unroll
    for (int g = 0; g < 4; ++g) {
        bs0[g] = bsB[lb * 32 + g * 8 + 2 * w];
        bs1[g] = bsB[lb * 32 + g * 8 + 2 * w + 1];
    }

    for (int r = 1; r <= 257; ++r) {
        const bool act = layer ? (r >= 2) : (r <= 256);
        if (act) {
            const int t = layer ? r - 2 : r - 1;
            const int rpar = (r - 1) & 1, wpar = r & 1;
            const unsigned short* h0r = h0b + (size_t)rpar * 131072;
            const unsigned short* h1r = h1b + (size_t)rpar * 131072;
            const unsigned short* Et = Ef + (size_t)t * 65536;

            // per-subtile operand source (wave-uniform branch)
            auto ldst = [&](Frag& f, int s) {
                const unsigned short* wp = wB + (size_t)s * 1024;
                const unsigned short* hp;
                int po;
                if (layer) {
                    hp = (s < 32 ? h1r + (size_t)s * 2048
                                 : h0r + (size_t)(s - 32) * 2048) +
                         (size_t)lane * 8;
                    po = 65536;
                } else if (s < 32) {
                    hp = h0r + (size_t)s * 2048 + (size_t)lane * 8;
                    po = 65536;
                } else {
                    hp = Et + (size_t)(s - 32) * 2048 + (size_t)lane * 8;
                    po = 32768;
                }
                f.w00 = LD8(wp);        f.w01 = LD8(wp + 512);
                f.w10 = LD8(wp + wNS);  f.w11 = LD8(wp + wNS + 512);
                f.h0 = LD8(hp);          f.h1 = LD8(hp + 512);
                f.h2 = LD8(hp + 1024);   f.h3 = LD8(hp + 1536);
                f.l0 = LD8(hp + po);          f.l1 = LD8(hp + po + 512);
                f.l2 = LD8(hp + po + 1024);   f.l3 = LD8(hp + po + 1536);
            };

            f32x4 acc[2][4] = {};
            Frag fA, fB;
            ldst(fA, sub0);
#pragma unroll 1
            for (int ss = 0; ss + 2 <= nsub; ss += 2) {
                ldst(fB, sub0 + ss + 1);
                mma_frags(fA, acc);
                if (ss + 2 < nsub) ldst(fA, sub0 + ss + 2);
                mma_frags(fB, acc);
            }

            // k-split partials: row = mi*16+(lane>>4)*4+rr, col = nj*16+(lane&15)
            {
                const int rq = (lane >> 4) * 4, cq = lane & 15;
#pragma unroll
                for (int mi = 0; mi < 2; ++mi)
#pragma unroll
                    for (int nj = 0; nj < 4; ++nj)
#pragma unroll
                        for (int rr = 0; rr < 4; ++rr)
                            Pred[w][mi * 16 + rq + rr][nj * 16 + cq] =
                                acc[mi][nj][rr];
            }
            __syncthreads();

            // activation: thread -> (b = lane, cols 2w+cidx)
#pragma unroll
            for (int cidx = 0; cidx < 2; ++cidx) {
                const int col = 2 * w + cidx;
                float p[4];
#pragma unroll
                for (int g = 0; g < 4; ++g) {
                    const int row = g * 8 + col;
                    p[g] = Pred[0][row][lane] + Pred[1][row][lane] +
                           Pred[2][row][lane] + Pred[3][row][lane];
                    p[g] += cidx ? bs1[g] : bs0[g];
                }
                const float fg = sigmoidf_(p[0]);
                const float ig = sigmoidf_(p[1]);
                const float gg = tanhf(p[2]);
                const float og = sigmoidf_(p[3]);
                const float cn = fmaf(fg, (cidx ? c_[1] : c_[0]), ig * gg);
                if (cidx) c_[1] = cn; else c_[0] = cn;
                const float h = og * tanhf(cn);
                const unsigned short hh = f2bf(h);
                hasmH[lane][col] = hh;
                hasmL[lane][col] = f2bf(h - bf2f(hh));
                if (layer && r == 257)
                    hst1[(size_t)(lb * 8 + col) * 64 + lane] = h;
            }
            __syncthreads();

            // granule store: one 16B store per (plane, b)
            if (tid < 128) {
                const int p = tid >> 6, b = tid & 63;
                unsigned short* hw =
                    (layer ? h1b : h0b) + (size_t)wpar * 131072;
                const size_t off =
                    (((size_t)(p * 32 + (lb >> 2)) * 4 + (b >> 4)) * 64 +
                     ((b & 15) + 16 * (lb & 3))) * 8;
                *reinterpret_cast<short8*>(hw + off) =
                    *reinterpret_cast<const short8*>(
                        p ? &hasmL[b][0] : &hasmH[b][0]);
            }
        }
        gbar(bar, bid, (unsigned)r);
    }
}

// ---------------- classifier ------------------------------------------------
__global__ __launch_bounds__(256) void cls_k(
    const float* __restrict__ hfin, const float* __restrict__ Wc,
    const float* __restrict__ bcls, float* __restrict__ out)
{
    __shared__ float red[4][64];
    const int n = blockIdx.x;
    const int lane = threadIdx.x & 63, w = threadIdx.x >> 6;
    float acc = 0.f;
    for (int k = w * 256; k < w * 256 + 256; ++k)
        acc = fmaf(hfin[k * 64 + lane], Wc[k * 10 + n], acc);
    red[w][lane] = acc;
    __syncthreads();
    if (w == 0) {
        out[lane * 10 + n] = red[0][lane] + red[1][lane] + red[2][lane] +
                             red[3][lane] + bcls[n];
    }
}

extern "C" void kernel_launch(void* const* d_in, const int* in_sizes, int n_in,
                              void* d_out, int out_size, void* d_ws,
                              size_t ws_size, hipStream_t stream)
{
    const float* x    = (const float*)d_in[0];
    const float* h0   = (const float*)d_in[1];
    const float* c0   = (const float*)d_in[2];
    const float* Wenc = (const float*)d_in[3];
    const float* benc = (const float*)d_in[4];
    const float* alpha= (const float*)d_in[5];
    const float* Wx0  = (const float*)d_in[6];
    const float* bx0  = (const float*)d_in[7];
    const float* Wh0  = (const float*)d_in[8];
    const float* bh0  = (const float*)d_in[9];
    const float* Wx1  = (const float*)d_in[10];
    const float* bx1  = (const float*)d_in[11];
    const float* Wh1  = (const float*)d_in[12];
    const float* bh1  = (const float*)d_in[13];
    const float* Wcls = (const float*)d_in[14];
    const float* bcls = (const float*)d_in[15];
    float* out = (float*)d_out;

    // Workspace plan (floats): total ~23.4M floats = 94 MB.
    float* ws = (float*)d_ws;
    size_t off = 0;
    unsigned short* Ef   = (unsigned short*)(ws + off); off += 8388608;  // 16.7M sh
    unsigned short* Wf0  = (unsigned short*)(ws + off); off += 6291456;  // 12.6M sh
    unsigned short* Wf1  = (unsigned short*)(ws + off); off += 8388608;  // 16.7M sh
    unsigned short* h0b  = (unsigned short*)(ws + off); off += 131072;   // 262K sh
    unsigned short* h1b  = (unsigned short*)(ws + off); off += 131072;
    float* bsum0p = ws + off; off += 4096;
    float* bsum1p = ws + off; off += 4096;
    float* hst1   = ws + off; off += 65536;
    unsigned* bars = (unsigned*)(ws + off); off += 256;

    (void)hipMemsetAsync(bars, 0, 1024, stream);

    // prologue (input-only deps)
    enc_gemm_k<<<dim3(8, 128), 256, 0, stream>>>(
        x, Wenc, Ef, benc, alpha, 16384, 512, 256, 65536, 256);
    wprep_k<<<dim3(48, 64), 256, 0, stream>>>(Wh0, Wx0, Wf0, 48);
    wprep_k<<<dim3(64, 64), 256, 0, stream>>>(Wh1, Wx1, Wf1, 64);
    hsplit_k<<<32, 256, 0, stream>>>(h0, h0b);                   // L0 h, parity 0
    hsplit_k<<<32, 256, 0, stream>>>(h0 + 65536, h1b + 131072);  // L1 h, parity 1
    bsum_k<<<16, 256, 0, stream>>>(bx0, bh0, bsum0p);
    bsum_k<<<16, 256, 0, stream>>>(bx1, bh1, bsum1p);

    // fused dual-layer pipelined LSTM (257 rounds)
    fused_lstm_k<<<256, 256, 0, stream>>>(Ef, Wf0, Wf1, h0b, h1b, c0,
                                          bsum0p, bsum1p, hst1, bars);

    // classifier from layer-1 final h ([k][b])
    cls_k<<<dim3(10), 256, 0, stream>>>(hst1, Wcls, bcls, out);
}

// Round 7
// 5777.686 us; speedup vs baseline: 5.3498x; 1.0122x over previous
//
#include <hip/hip_runtime.h>
#include <hip/hip_bf16.h>
#include <cstddef>

// ---------------------------------------------------------------------------
// B=64, S=256, W=256, E=512, HID=1024, L=2, NCLS=10
// enc GEMM (fp32 -> bf16-split E in MFMA-fragment granule order) ->
// ONE fused dual-layer pipelined LSTM with REGISTER-RESIDENT weights:
//   256 blocks x 512 threads (8 waves). blocks 0..127 = layer 0 (K=1536,
//   [Wh0;Wx0]); blocks 128..255 = layer 1 (K=2048, [Wh1;Wx1]).
//   Each wave holds nsub (6 or 8) k-subtiles of weights in VGPRs (128 VGPR),
//   loaded once; per-round traffic = h granules + E slice only.
//   257 rounds, layer 1 lags layer 0 by one step; custom grid barrier.
// -> classifier.
// Fragment layouts (HW-validated round 4/6, absmax 7.6e-6):
//   A/B operand: lane = (row&15) + 16*kg holds 8 values [row][k0+kg*8 .. +7]
//   D: row = mi*16 + (lane>>4)*4 + rr, col = nj*16 + (lane&15)
// Granule layouts (16B per lane):
//   W:  Wf[lb][plane][s][mi][lane][8]
//   h:  hbuf[par][plane][s(32)][nj][lane][8]   (plane stride 65536 shorts)
//   E:  Ef[t][plane][s(16)][nj][lane][8]       (plane stride 32768 shorts)
// Row permutation: gate row j = g*1024 + lb*8 + c -> block lb, rloc = g*8+c.
// Workspace ~94 MB (known-good budget >= 279 MB).
// ---------------------------------------------------------------------------

using short8 = __attribute__((ext_vector_type(8))) short;
using f32x4  = __attribute__((ext_vector_type(4))) float;

#define LD8(p) (*reinterpret_cast<const short8*>(p))

__device__ __forceinline__ float sigmoidf_(float x) {
    return 1.f / (1.f + __expf(-x));
}
__device__ __forceinline__ unsigned short f2bf(float x) {   // RNE bf16
    union { float f; unsigned u; } v; v.f = x;
    unsigned r = v.u + 0x7fffu + ((v.u >> 16) & 1u);
    return (unsigned short)(r >> 16);
}
__device__ __forceinline__ float bf2f(unsigned short h) {
    union { unsigned u; float f; } v; v.u = ((unsigned)h) << 16;
    return v.f;
}

// ---------------- encoder GEMM (fp32 compute, granule bf16-split output) ---
__global__ __launch_bounds__(256) void enc_gemm_k(
    const float* __restrict__ A, const float* __restrict__ B,
    unsigned short* __restrict__ Ef,
    const float* __restrict__ bias1, const float* __restrict__ alphap,
    int M, int N, int K, int sB, int sS)
{
    __shared__ float As[128][17];
    __shared__ float Bs[16][64];
    const int tid = threadIdx.x;
    const int tx = tid & 15, ty = tid >> 4;
    const int rb = blockIdx.y * 128;
    const int cb = blockIdx.x * 64;

    float acc[8][4];
#pragma unroll
    for (int i = 0; i < 8; ++i)
#pragma unroll
        for (int j = 0; j < 4; ++j) acc[i][j] = 0.f;

    const int nk = K >> 4;
    for (int kt = 0; kt < nk; ++kt) {
        const int k0 = kt << 4;
        __syncthreads();
        {
            const int row = tid >> 2, k4 = tid & 3;
#pragma unroll
            for (int h = 0; h < 2; ++h) {
                const int r = rb + row + h * 64;
                const float4 v = *reinterpret_cast<const float4*>(
                    &A[(size_t)(r & 63) * sB + (size_t)(r >> 6) * sS + k0 + k4 * 4]);
                As[row + h * 64][k4 * 4 + 0] = v.x;
                As[row + h * 64][k4 * 4 + 1] = v.y;
                As[row + h * 64][k4 * 4 + 2] = v.z;
                As[row + h * 64][k4 * 4 + 3] = v.w;
            }
        }
        {
            const int bk = tid >> 4, c4 = tid & 15;
            *reinterpret_cast<float4*>(&Bs[bk][c4 * 4]) =
                *reinterpret_cast<const float4*>(
                    &B[(size_t)(k0 + bk) * N + cb + c4 * 4]);
        }
        __syncthreads();
#pragma unroll
        for (int k = 0; k < 16; ++k) {
            float a[8];
#pragma unroll
            for (int i = 0; i < 8; ++i) a[i] = As[ty * 8 + i][k];
            const float4 bv = *reinterpret_cast<const float4*>(&Bs[k][tx * 4]);
#pragma unroll
            for (int i = 0; i < 8; ++i) {
                acc[i][0] = fmaf(a[i], bv.x, acc[i][0]);
                acc[i][1] = fmaf(a[i], bv.y, acc[i][1]);
                acc[i][2] = fmaf(a[i], bv.z, acc[i][2]);
                acc[i][3] = fmaf(a[i], bv.w, acc[i][3]);
            }
        }
    }

    float bsum[4];
#pragma unroll
    for (int j = 0; j < 4; ++j) bsum[j] = bias1[cb + tx * 4 + j];
    const float alpha = alphap[0];
    const int k0c = cb + tx * 4;
    const int s = k0c >> 5, kg = (k0c >> 3) & 3, e0 = k0c & 7;
#pragma unroll
    for (int i = 0; i < 8; ++i) {
        const int r = rb + ty * 8 + i;
        const int t = r >> 6, b = r & 63;
        const int ln = (b & 15) + 16 * kg, nj = b >> 4;
        unsigned short hs[4], ls[4];
#pragma unroll
        for (int j = 0; j < 4; ++j) {
            float v = acc[i][j] + bsum[j];
            v = (v >= 0.f) ? v : alpha * v;
            hs[j] = f2bf(v);
            ls[j] = f2bf(v - bf2f(hs[j]));
        }
        uint2 hp, lp;
        hp.x = (unsigned)hs[0] | ((unsigned)hs[1] << 16);
        hp.y = (unsigned)hs[2] | ((unsigned)hs[3] << 16);
        lp.x = (unsigned)ls[0] | ((unsigned)ls[1] << 16);
        lp.y = (unsigned)ls[2] | ((unsigned)ls[3] << 16);
        const size_t base =
            ((((size_t)t * 32 + s) * 4 + nj) * 64 + ln) * 8 + e0;
        *reinterpret_cast<uint2*>(Ef + base) = hp;            // hi plane
        *reinterpret_cast<uint2*>(Ef + base + 32768) = lp;    // lo plane
    }
}

// ------------- weight prep: frag-order split planes ------------------------
__global__ __launch_bounds__(256) void wprep_k(
    const float* __restrict__ Wa, const float* __restrict__ Wb,
    unsigned short* __restrict__ Wf, int NS)
{
    __shared__ float tl[32][65];
    const int k0 = blockIdx.x * 32, j0 = blockIdx.y * 64;
    const int tid = threadIdx.x;
    {
        const int kk = tid >> 3, jq = tid & 7;
        const int k = k0 + kk;
        const float* src = (k < 1024) ? &Wa[(size_t)k * 4096]
                                      : &Wb[(size_t)(k - 1024) * 4096];
#pragma unroll
        for (int h = 0; h < 2; ++h) {
            const float4 v = *reinterpret_cast<const float4*>(
                &src[j0 + jq * 8 + h * 4]);
            tl[kk][jq * 8 + h * 4 + 0] = v.x; tl[kk][jq * 8 + h * 4 + 1] = v.y;
            tl[kk][jq * 8 + h * 4 + 2] = v.z; tl[kk][jq * 8 + h * 4 + 3] = v.w;
        }
    }
    __syncthreads();
    const int j = tid >> 2, kg = tid & 3;
    const int jg = j0 + j;
    const int g = jg >> 10, cc = jg & 1023;
    const int lb = cc >> 3, c = cc & 7;
    const int rloc = g * 8 + c;
    const int mi = rloc >> 4, r16 = rloc & 15;
    const int lane = r16 + 16 * kg;
    const int s = k0 >> 5;
    short8 hv, lv;
#pragma unroll
    for (int e = 0; e < 8; ++e) {
        const float x = tl[kg * 8 + e][j];
        const unsigned short h = f2bf(x);
        hv[e] = (short)h;
        lv[e] = (short)f2bf(x - bf2f(h));
    }
    const size_t oH = ((((size_t)lb * 2 + 0) * NS + s) * 2 + mi) * 512 + (size_t)lane * 8;
    const size_t oL = ((((size_t)lb * 2 + 1) * NS + s) * 2 + mi) * 512 + (size_t)lane * 8;
    *reinterpret_cast<short8*>(Wf + oH) = hv;
    *reinterpret_cast<short8*>(Wf + oL) = lv;
}

// ------------- h split init: hrow fp32 [64][1024] -> granule planes --------
__global__ __launch_bounds__(256) void hsplit_k(
    const float* __restrict__ hrow, unsigned short* __restrict__ dst)
{
    const int idx = blockIdx.x * 256 + threadIdx.x;   // 8192 total
    const int b = idx >> 7, gc = idx & 127;
    const int k = gc * 8;
    short8 hv, lv;
#pragma unroll
    for (int e = 0; e < 8; ++e) {
        const float x = hrow[(size_t)b * 1024 + k + e];
        const unsigned short h = f2bf(x);
        hv[e] = (short)h;
        lv[e] = (short)f2bf(x - bf2f(h));
    }
    const int s = k >> 5, kg = (k >> 3) & 3, nj = b >> 4;
    const int l = (b & 15) + 16 * kg;
    const size_t oH = (((size_t)(0 * 32 + s) * 4 + nj) * 64 + l) * 8;
    const size_t oL = (((size_t)(1 * 32 + s) * 4 + nj) * 64 + l) * 8;
    *reinterpret_cast<short8*>(dst + oH) = hv;
    *reinterpret_cast<short8*>(dst + oL) = lv;
}

// ------------- permuted bias sum: out[lb*32+g*8+c] = bx[j]+bh[j] -----------
__global__ __launch_bounds__(256) void bsum_k(
    const float* __restrict__ bx, const float* __restrict__ bh,
    float* __restrict__ out)
{
    const int r = blockIdx.x * 256 + threadIdx.x;     // 4096
    const int lb = r >> 5, rl = r & 31;
    const int g = rl >> 3, c = rl & 7;
    const int j = g * 1024 + lb * 8 + c;
    out[r] = bx[j] + bh[j];
}

// ---------------- custom grid barrier (two-level, per-group go flags) ------
__device__ __forceinline__ void gbar(unsigned* bar, int bid, unsigned gen) {
    __syncthreads();
    if (threadIdx.x == 0) {
        __threadfence();
        const int grp = bid >> 5;
        unsigned* grpc = bar + grp * 16;
        unsigned* root = bar + 128;
        unsigned* go   = bar + 160 + grp * 16;
        __hip_atomic_fetch_add(grpc, 1u, __ATOMIC_RELAXED,
                               __HIP_MEMORY_SCOPE_AGENT);
        if ((bid & 31) == 0) {
            while (__hip_atomic_load(grpc, __ATOMIC_RELAXED,
                                     __HIP_MEMORY_SCOPE_AGENT) < 32u * gen)
                __builtin_amdgcn_s_sleep(1);
            __hip_atomic_fetch_add(root, 1u, __ATOMIC_RELAXED,
                                   __HIP_MEMORY_SCOPE_AGENT);
        }
        if (bid == 0) {
            while (__hip_atomic_load(root, __ATOMIC_RELAXED,
                                     __HIP_MEMORY_SCOPE_AGENT) < 8u * gen)
                __builtin_amdgcn_s_sleep(1);
#pragma unroll
            for (int g = 0; g < 8; ++g)
                __hip_atomic_store(bar + 160 + g * 16, gen, __ATOMIC_RELEASE,
                                   __HIP_MEMORY_SCOPE_AGENT);
        }
        while (__hip_atomic_load(go, __ATOMIC_RELAXED,
                                 __HIP_MEMORY_SCOPE_AGENT) < gen)
            __builtin_amdgcn_s_sleep(1);
        __threadfence();
    }
    __syncthreads();
}

// ---------------- fused dual-layer LSTM, register-resident weights ---------
__global__ __launch_bounds__(512, 2) void fused_lstm_k(
    const unsigned short* __restrict__ Ef,
    const unsigned short* __restrict__ Wf0,
    const unsigned short* __restrict__ Wf1,
    unsigned short* __restrict__ h0b, unsigned short* __restrict__ h1b,
    const float* __restrict__ c0, const float* __restrict__ bsum0p,
    const float* __restrict__ bsum1p, float* __restrict__ hst1,
    unsigned* bar)
{
    __shared__ float Pred[8][32][66];
    __shared__ unsigned short hasmH[64][8];
    __shared__ unsigned short hasmL[64][8];

    const int tid = threadIdx.x;
    const int lane = tid & 63;                 // batch row for MFMA frags
    const int w = tid >> 6;                    // wave id 0..7
    const int bid = blockIdx.x;
    const int layer = bid >> 7;
    const int lb = bid & 127;

    const int NS = layer ? 64 : 48;            // K/32
    const int nsub = layer ? 8 : 6;            // subtiles per wave
    const int sub0 = w * nsub;
    const int wNS = NS * 1024;                 // plane offset in weight shorts

    const unsigned short* Wf = layer ? Wf1 : Wf0;
    const unsigned short* wB =
        Wf + (size_t)lb * 2 * NS * 1024 + (size_t)lane * 8;

    // ---- load this wave's weight fragments into registers (once) ----
    short8 w00r[8], w01r[8], w10r[8], w11r[8];
#pragma unroll
    for (int s = 0; s < 8; ++s)
        if (s < nsub) {
            const unsigned short* wp = wB + (size_t)(sub0 + s) * 1024;
            w00r[s] = LD8(wp);        w01r[s] = LD8(wp + 512);
            w10r[s] = LD8(wp + wNS);  w11r[s] = LD8(wp + wNS + 512);
        }

    // activation mapping: thread -> (b = lane, h-col = w)
    const int col = w;
    float c_ = c0[(size_t)layer * 65536 + (size_t)lane * 1024 + lb * 8 + col];
    const float* bsB = layer ? bsum1p : bsum0p;
    float bs[4];
#pragma unroll
    for (int g = 0; g < 4; ++g) bs[g] = bsB[lb * 32 + g * 8 + col];

    for (int r = 1; r <= 257; ++r) {
        const bool act = layer ? (r >= 2) : (r <= 256);
        if (act) {
            const int t = layer ? r - 2 : r - 1;
            const int rpar = (r - 1) & 1, wpar = r & 1;
            const unsigned short* h0r = h0b + (size_t)rpar * 131072;
            const unsigned short* h1r = h1b + (size_t)rpar * 131072;
            const unsigned short* Et = Ef + (size_t)t * 65536;

            f32x4 acc[2][4] = {};
#pragma unroll
            for (int s = 0; s < 8; ++s)
                if (s < nsub) {
                    const int sg = sub0 + s;
                    const unsigned short* hp;
                    int po;
                    if (layer) {
                        hp = (sg < 32 ? h1r + (size_t)sg * 2048
                                      : h0r + (size_t)(sg - 32) * 2048) +
                             (size_t)lane * 8;
                        po = 65536;
                    } else if (sg < 32) {
                        hp = h0r + (size_t)sg * 2048 + (size_t)lane * 8;
                        po = 65536;
                    } else {
                        hp = Et + (size_t)(sg - 32) * 2048 + (size_t)lane * 8;
                        po = 32768;
                    }
                    const short8 h0v = LD8(hp),        h1v = LD8(hp + 512);
                    const short8 h2v = LD8(hp + 1024), h3v = LD8(hp + 1536);
                    const short8 l0v = LD8(hp + po),        l1v = LD8(hp + po + 512);
                    const short8 l2v = LD8(hp + po + 1024), l3v = LD8(hp + po + 1536);
#define MM(mi, nj, HH, HL)                                                     \
    acc[mi][nj] = __builtin_amdgcn_mfma_f32_16x16x32_bf16(                     \
        (mi) ? w01r[s] : w00r[s], HH, acc[mi][nj], 0, 0, 0);                   \
    acc[mi][nj] = __builtin_amdgcn_mfma_f32_16x16x32_bf16(                     \
        (mi) ? w01r[s] : w00r[s], HL, acc[mi][nj], 0, 0, 0);                   \
    acc[mi][nj] = __builtin_amdgcn_mfma_f32_16x16x32_bf16(                     \
        (mi) ? w11r[s] : w10r[s], HH, acc[mi][nj], 0, 0, 0);
                    MM(0, 0, h0v, l0v)  MM(0, 1, h1v, l1v)
                    MM(0, 2, h2v, l2v)  MM(0, 3, h3v, l3v)
                    MM(1, 0, h0v, l0v)  MM(1, 1, h1v, l1v)
                    MM(1, 2, h2v, l2v)  MM(1, 3, h3v, l3v)
#undef MM
                }

            // k-split partials: row = mi*16+(lane>>4)*4+rr, col = nj*16+(lane&15)
            {
                const int rq = (lane >> 4) * 4, cq = lane & 15;
#pragma unroll
                for (int mi = 0; mi < 2; ++mi)
#pragma unroll
                    for (int nj = 0; nj < 4; ++nj)
#pragma unroll
                        for (int rr = 0; rr < 4; ++rr)
                            Pred[w][mi * 16 + rq + rr][nj * 16 + cq] =
                                acc[mi][nj][rr];
            }
            __syncthreads();

            // activation: thread (b = lane, col = w)
            {
                float p[4];
#pragma unroll
                for (int g = 0; g < 4; ++g) {
                    const int row = g * 8 + col;
                    float s0 = 0.f;
#pragma unroll
                    for (int ww = 0; ww < 8; ++ww)
                        s0 += Pred[ww][row][lane];
                    p[g] = s0 + bs[g];
                }
                const float fg = sigmoidf_(p[0]);
                const float ig = sigmoidf_(p[1]);
                const float gg = tanhf(p[2]);
                const float og = sigmoidf_(p[3]);
                c_ = fmaf(fg, c_, ig * gg);
                const float h = og * tanhf(c_);
                const unsigned short hh = f2bf(h);
                hasmH[lane][col] = hh;
                hasmL[lane][col] = f2bf(h - bf2f(hh));
                if (layer && r == 257)
                    hst1[(size_t)(lb * 8 + col) * 64 + lane] = h;
            }
            __syncthreads();

            // granule store: one 16B store per (plane, b)
            if (tid < 128) {
                const int p = tid >> 6, b = tid & 63;
                unsigned short* hw =
                    (layer ? h1b : h0b) + (size_t)wpar * 131072;
                const size_t off =
                    (((size_t)(p * 32 + (lb >> 2)) * 4 + (b >> 4)) * 64 +
                     ((b & 15) + 16 * (lb & 3))) * 8;
                *reinterpret_cast<short8*>(hw + off) =
                    *reinterpret_cast<const short8*>(
                        p ? &hasmL[b][0] : &hasmH[b][0]);
            }
        }
        gbar(bar, bid, (unsigned)r);
    }
}

// ---------------- classifier ------------------------------------------------
__global__ __launch_bounds__(256) void cls_k(
    const float* __restrict__ hfin, const float* __restrict__ Wc,
    const float* __restrict__ bcls, float* __restrict__ out)
{
    __shared__ float red[4][64];
    const int n = blockIdx.x;
    const int lane = threadIdx.x & 63, w = threadIdx.x >> 6;
    float acc = 0.f;
    for (int k = w * 256; k < w * 256 + 256; ++k)
        acc = fmaf(hfin[k * 64 + lane], Wc[k * 10 + n], acc);
    red[w][lane] = acc;
    __syncthreads();
    if (w == 0) {
        out[lane * 10 + n] = red[0][lane] + red[1][lane] + red[2][lane] +
                             red[3][lane] + bcls[n];
    }
}

extern "C" void kernel_launch(void* const* d_in, const int* in_sizes, int n_in,
                              void* d_out, int out_size, void* d_ws,
                              size_t ws_size, hipStream_t stream)
{
    const float* x    = (const float*)d_in[0];
    const float* h0   = (const float*)d_in[1];
    const float* c0   = (const float*)d_in[2];
    const float* Wenc = (const float*)d_in[3];
    const float* benc = (const float*)d_in[4];
    const float* alpha= (const float*)d_in[5];
    const float* Wx0  = (const float*)d_in[6];
    const float* bx0  = (const float*)d_in[7];
    const float* Wh0  = (const float*)d_in[8];
    const float* bh0  = (const float*)d_in[9];
    const float* Wx1  = (const float*)d_in[10];
    const float* bx1  = (const float*)d_in[11];
    const float* Wh1  = (const float*)d_in[12];
    const float* bh1  = (const float*)d_in[13];
    const float* Wcls = (const float*)d_in[14];
    const float* bcls = (const float*)d_in[15];
    float* out = (float*)d_out;

    // Workspace plan (floats): total ~23.4M floats = 94 MB.
    float* ws = (float*)d_ws;
    size_t off = 0;
    unsigned short* Ef   = (unsigned short*)(ws + off); off += 8388608;  // 16.7M sh
    unsigned short* Wf0  = (unsigned short*)(ws + off); off += 6291456;  // 12.6M sh
    unsigned short* Wf1  = (unsigned short*)(ws + off); off += 8388608;  // 16.7M sh
    unsigned short* h0b  = (unsigned short*)(ws + off); off += 131072;   // 262K sh
    unsigned short* h1b  = (unsigned short*)(ws + off); off += 131072;
    float* bsum0p = ws + off; off += 4096;
    float* bsum1p = ws + off; off += 4096;
    float* hst1   = ws + off; off += 65536;
    unsigned* bars = (unsigned*)(ws + off); off += 512;

    (void)hipMemsetAsync(bars, 0, 2048, stream);

    // prologue (input-only deps)
    enc_gemm_k<<<dim3(8, 128), 256, 0, stream>>>(
        x, Wenc, Ef, benc, alpha, 16384, 512, 256, 65536, 256);
    wprep_k<<<dim3(48, 64), 256, 0, stream>>>(Wh0, Wx0, Wf0, 48);
    wprep_k<<<dim3(64, 64), 256, 0, stream>>>(Wh1, Wx1, Wf1, 64);
    hsplit_k<<<32, 256, 0, stream>>>(h0, h0b);                   // L0 h, parity 0
    hsplit_k<<<32, 256, 0, stream>>>(h0 + 65536, h1b + 131072);  // L1 h, parity 1
    bsum_k<<<16, 256, 0, stream>>>(bx0, bh0, bsum0p);
    bsum_k<<<16, 256, 0, stream>>>(bx1, bh1, bsum1p);

    // fused dual-layer LSTM, register-resident weights (257 rounds)
    fused_lstm_k<<<256, 512, 0, stream>>>(Ef, Wf0, Wf1, h0b, h1b, c0,
                                          bsum0p, bsum1p, hst1, bars);

    // classifier from layer-1 final h ([k][b])
    cls_k<<<dim3(10), 256, 0, stream>>>(hst1, Wcls, bcls, out);
}

// Round 8
// 5588.622 us; speedup vs baseline: 5.5307x; 1.0338x over previous
//
#include <hip/hip_runtime.h>
#include <hip/hip_bf16.h>
#include <cstddef>

// ---------------------------------------------------------------------------
// B=64, S=256, W=256, E=512, HID=1024, L=2, NCLS=10
// enc GEMM (fp32 -> bf16-split E in MFMA-fragment granule order) ->
// ONE fused dual-layer pipelined LSTM with REGISTER-RESIDENT weights and a
// FLAT 2-hop counter barrier:
//   256 blocks x 512 threads (8 waves). blocks 0..127 = layer 0 (K=1536,
//   [Wh0;Wx0]); blocks 128..255 = layer 1 (K=2048, [Wh1;Wx1]).
//   Each wave holds nsub (6 or 8) k-subtiles of weights in VGPRs, loaded once.
//   257 rounds, layer 1 lags layer 0 by one step. End-of-round barrier:
//   release fence; fetch_add own layer counter; spin until BOTH counters
//   >= 128*r; acquire fence. Last round skips the barrier (kernel boundary).
// -> classifier.
// Fragment layouts (HW-validated rounds 4/6/7, absmax 7.6e-6):
//   A/B operand: lane = (row&15) + 16*kg holds 8 values [row][k0+kg*8 .. +7]
//   D: row = mi*16 + (lane>>4)*4 + rr, col = nj*16 + (lane&15)
// Granule layouts (16B per lane):
//   W:  Wf[lb][plane][s][mi][lane][8]
//   h:  hbuf[par][plane][s(32)][nj][lane][8]   (plane stride 65536 shorts)
//   E:  Ef[t][plane][s(16)][nj][lane][8]       (plane stride 32768 shorts)
// Row permutation: gate row j = g*1024 + lb*8 + c -> block lb, rloc = g*8+c.
// Workspace ~94 MB (known-good budget >= 279 MB).
// ---------------------------------------------------------------------------

using short8 = __attribute__((ext_vector_type(8))) short;
using f32x4  = __attribute__((ext_vector_type(4))) float;

#define LD8(p) (*reinterpret_cast<const short8*>(p))

__device__ __forceinline__ float sigmoidf_(float x) {
    return 1.f / (1.f + __expf(-x));
}
__device__ __forceinline__ unsigned short f2bf(float x) {   // RNE bf16
    union { float f; unsigned u; } v; v.f = x;
    unsigned r = v.u + 0x7fffu + ((v.u >> 16) & 1u);
    return (unsigned short)(r >> 16);
}
__device__ __forceinline__ float bf2f(unsigned short h) {
    union { unsigned u; float f; } v; v.u = ((unsigned)h) << 16;
    return v.f;
}

// ---------------- encoder GEMM (fp32 compute, granule bf16-split output) ---
__global__ __launch_bounds__(256) void enc_gemm_k(
    const float* __restrict__ A, const float* __restrict__ B,
    unsigned short* __restrict__ Ef,
    const float* __restrict__ bias1, const float* __restrict__ alphap,
    int M, int N, int K, int sB, int sS)
{
    __shared__ float As[128][17];
    __shared__ float Bs[16][64];
    const int tid = threadIdx.x;
    const int tx = tid & 15, ty = tid >> 4;
    const int rb = blockIdx.y * 128;
    const int cb = blockIdx.x * 64;

    float acc[8][4];
#pragma unroll
    for (int i = 0; i < 8; ++i)
#pragma unroll
        for (int j = 0; j < 4; ++j) acc[i][j] = 0.f;

    const int nk = K >> 4;
    for (int kt = 0; kt < nk; ++kt) {
        const int k0 = kt << 4;
        __syncthreads();
        {
            const int row = tid >> 2, k4 = tid & 3;
#pragma unroll
            for (int h = 0; h < 2; ++h) {
                const int r = rb + row + h * 64;
                const float4 v = *reinterpret_cast<const float4*>(
                    &A[(size_t)(r & 63) * sB + (size_t)(r >> 6) * sS + k0 + k4 * 4]);
                As[row + h * 64][k4 * 4 + 0] = v.x;
                As[row + h * 64][k4 * 4 + 1] = v.y;
                As[row + h * 64][k4 * 4 + 2] = v.z;
                As[row + h * 64][k4 * 4 + 3] = v.w;
            }
        }
        {
            const int bk = tid >> 4, c4 = tid & 15;
            *reinterpret_cast<float4*>(&Bs[bk][c4 * 4]) =
                *reinterpret_cast<const float4*>(
                    &B[(size_t)(k0 + bk) * N + cb + c4 * 4]);
        }
        __syncthreads();
#pragma unroll
        for (int k = 0; k < 16; ++k) {
            float a[8];
#pragma unroll
            for (int i = 0; i < 8; ++i) a[i] = As[ty * 8 + i][k];
            const float4 bv = *reinterpret_cast<const float4*>(&Bs[k][tx * 4]);
#pragma unroll
            for (int i = 0; i < 8; ++i) {
                acc[i][0] = fmaf(a[i], bv.x, acc[i][0]);
                acc[i][1] = fmaf(a[i], bv.y, acc[i][1]);
                acc[i][2] = fmaf(a[i], bv.z, acc[i][2]);
                acc[i][3] = fmaf(a[i], bv.w, acc[i][3]);
            }
        }
    }

    float bsum[4];
#pragma unroll
    for (int j = 0; j < 4; ++j) bsum[j] = bias1[cb + tx * 4 + j];
    const float alpha = alphap[0];
    const int k0c = cb + tx * 4;
    const int s = k0c >> 5, kg = (k0c >> 3) & 3, e0 = k0c & 7;
#pragma unroll
    for (int i = 0; i < 8; ++i) {
        const int r = rb + ty * 8 + i;
        const int t = r >> 6, b = r & 63;
        const int ln = (b & 15) + 16 * kg, nj = b >> 4;
        unsigned short hs[4], ls[4];
#pragma unroll
        for (int j = 0; j < 4; ++j) {
            float v = acc[i][j] + bsum[j];
            v = (v >= 0.f) ? v : alpha * v;
            hs[j] = f2bf(v);
            ls[j] = f2bf(v - bf2f(hs[j]));
        }
        uint2 hp, lp;
        hp.x = (unsigned)hs[0] | ((unsigned)hs[1] << 16);
        hp.y = (unsigned)hs[2] | ((unsigned)hs[3] << 16);
        lp.x = (unsigned)ls[0] | ((unsigned)ls[1] << 16);
        lp.y = (unsigned)ls[2] | ((unsigned)ls[3] << 16);
        const size_t base =
            ((((size_t)t * 32 + s) * 4 + nj) * 64 + ln) * 8 + e0;
        *reinterpret_cast<uint2*>(Ef + base) = hp;            // hi plane
        *reinterpret_cast<uint2*>(Ef + base + 32768) = lp;    // lo plane
    }
}

// ------------- weight prep: frag-order split planes ------------------------
__global__ __launch_bounds__(256) void wprep_k(
    const float* __restrict__ Wa, const float* __restrict__ Wb,
    unsigned short* __restrict__ Wf, int NS)
{
    __shared__ float tl[32][65];
    const int k0 = blockIdx.x * 32, j0 = blockIdx.y * 64;
    const int tid = threadIdx.x;
    {
        const int kk = tid >> 3, jq = tid & 7;
        const int k = k0 + kk;
        const float* src = (k < 1024) ? &Wa[(size_t)k * 4096]
                                      : &Wb[(size_t)(k - 1024) * 4096];
#pragma unroll
        for (int h = 0; h < 2; ++h) {
            const float4 v = *reinterpret_cast<const float4*>(
                &src[j0 + jq * 8 + h * 4]);
            tl[kk][jq * 8 + h * 4 + 0] = v.x; tl[kk][jq * 8 + h * 4 + 1] = v.y;
            tl[kk][jq * 8 + h * 4 + 2] = v.z; tl[kk][jq * 8 + h * 4 + 3] = v.w;
        }
    }
    __syncthreads();
    const int j = tid >> 2, kg = tid & 3;
    const int jg = j0 + j;
    const int g = jg >> 10, cc = jg & 1023;
    const int lb = cc >> 3, c = cc & 7;
    const int rloc = g * 8 + c;
    const int mi = rloc >> 4, r16 = rloc & 15;
    const int lane = r16 + 16 * kg;
    const int s = k0 >> 5;
    short8 hv, lv;
#pragma unroll
    for (int e = 0; e < 8; ++e) {
        const float x = tl[kg * 8 + e][j];
        const unsigned short h = f2bf(x);
        hv[e] = (short)h;
        lv[e] = (short)f2bf(x - bf2f(h));
    }
    const size_t oH = ((((size_t)lb * 2 + 0) * NS + s) * 2 + mi) * 512 + (size_t)lane * 8;
    const size_t oL = ((((size_t)lb * 2 + 1) * NS + s) * 2 + mi) * 512 + (size_t)lane * 8;
    *reinterpret_cast<short8*>(Wf + oH) = hv;
    *reinterpret_cast<short8*>(Wf + oL) = lv;
}

// ------------- h split init: hrow fp32 [64][1024] -> granule planes --------
__global__ __launch_bounds__(256) void hsplit_k(
    const float* __restrict__ hrow, unsigned short* __restrict__ dst)
{
    const int idx = blockIdx.x * 256 + threadIdx.x;   // 8192 total
    const int b = idx >> 7, gc = idx & 127;
    const int k = gc * 8;
    short8 hv, lv;
#pragma unroll
    for (int e = 0; e < 8; ++e) {
        const float x = hrow[(size_t)b * 1024 + k + e];
        const unsigned short h = f2bf(x);
        hv[e] = (short)h;
        lv[e] = (short)f2bf(x - bf2f(h));
    }
    const int s = k >> 5, kg = (k >> 3) & 3, nj = b >> 4;
    const int l = (b & 15) + 16 * kg;
    const size_t oH = (((size_t)(0 * 32 + s) * 4 + nj) * 64 + l) * 8;
    const size_t oL = (((size_t)(1 * 32 + s) * 4 + nj) * 64 + l) * 8;
    *reinterpret_cast<short8*>(dst + oH) = hv;
    *reinterpret_cast<short8*>(dst + oL) = lv;
}

// ------------- permuted bias sum: out[lb*32+g*8+c] = bx[j]+bh[j] -----------
__global__ __launch_bounds__(256) void bsum_k(
    const float* __restrict__ bx, const float* __restrict__ bh,
    float* __restrict__ out)
{
    const int r = blockIdx.x * 256 + threadIdx.x;     // 4096
    const int lb = r >> 5, rl = r & 31;
    const int g = rl >> 3, c = rl & 7;
    const int j = g * 1024 + lb * 8 + c;
    out[r] = bx[j] + bh[j];
}

// ---------------- fused dual-layer LSTM, register-resident weights ---------
__global__ __launch_bounds__(512, 2) void fused_lstm_k(
    const unsigned short* __restrict__ Ef,
    const unsigned short* __restrict__ Wf0,
    const unsigned short* __restrict__ Wf1,
    unsigned short* __restrict__ h0b, unsigned short* __restrict__ h1b,
    const float* __restrict__ c0, const float* __restrict__ bsum0p,
    const float* __restrict__ bsum1p, float* __restrict__ hst1,
    unsigned* bar)
{
    __shared__ float Pred[8][32][66];
    __shared__ unsigned short hasmH[64][8];
    __shared__ unsigned short hasmL[64][8];

    const int tid = threadIdx.x;
    const int lane = tid & 63;                 // batch row for MFMA frags
    const int w = tid >> 6;                    // wave id 0..7
    const int bid = blockIdx.x;
    const int layer = bid >> 7;
    const int lb = bid & 127;

    const int NS = layer ? 64 : 48;            // K/32
    const int nsub = layer ? 8 : 6;            // subtiles per wave
    const int sub0 = w * nsub;
    const int wNS = NS * 1024;                 // plane offset in weight shorts

    unsigned* cnt0 = bar;                      // layer-0 arrivals (own line)
    unsigned* cnt1 = bar + 32;                 // layer-1 arrivals (own line)

    const unsigned short* Wf = layer ? Wf1 : Wf0;
    const unsigned short* wB =
        Wf + (size_t)lb * 2 * NS * 1024 + (size_t)lane * 8;

    // ---- load this wave's weight fragments into registers (once) ----
    short8 w00r[8], w01r[8], w10r[8], w11r[8];
#pragma unroll
    for (int s = 0; s < 8; ++s)
        if (s < nsub) {
            const unsigned short* wp = wB + (size_t)(sub0 + s) * 1024;
            w00r[s] = LD8(wp);        w01r[s] = LD8(wp + 512);
            w10r[s] = LD8(wp + wNS);  w11r[s] = LD8(wp + wNS + 512);
        }

    // activation mapping: thread -> (b = lane, h-col = w)
    const int col = w;
    float c_ = c0[(size_t)layer * 65536 + (size_t)lane * 1024 + lb * 8 + col];
    const float* bsB = layer ? bsum1p : bsum0p;
    float bs[4];
#pragma unroll
    for (int g = 0; g < 4; ++g) bs[g] = bsB[lb * 32 + g * 8 + col];

    for (int r = 1; r <= 257; ++r) {
        const bool act = layer ? (r >= 2) : (r <= 256);
        if (act) {
            const int t = layer ? r - 2 : r - 1;
            const int rpar = (r - 1) & 1, wpar = r & 1;
            const unsigned short* h0r = h0b + (size_t)rpar * 131072;
            const unsigned short* h1r = h1b + (size_t)rpar * 131072;
            const unsigned short* Et = Ef + (size_t)t * 65536;

            f32x4 acc[2][4] = {};
#pragma unroll
            for (int s = 0; s < 8; ++s)
                if (s < nsub) {
                    const int sg = sub0 + s;
                    const unsigned short* hp;
                    int po;
                    if (layer) {
                        hp = (sg < 32 ? h1r + (size_t)sg * 2048
                                      : h0r + (size_t)(sg - 32) * 2048) +
                             (size_t)lane * 8;
                        po = 65536;
                    } else if (sg < 32) {
                        hp = h0r + (size_t)sg * 2048 + (size_t)lane * 8;
                        po = 65536;
                    } else {
                        hp = Et + (size_t)(sg - 32) * 2048 + (size_t)lane * 8;
                        po = 32768;
                    }
                    const short8 h0v = LD8(hp),        h1v = LD8(hp + 512);
                    const short8 h2v = LD8(hp + 1024), h3v = LD8(hp + 1536);
                    const short8 l0v = LD8(hp + po),        l1v = LD8(hp + po + 512);
                    const short8 l2v = LD8(hp + po + 1024), l3v = LD8(hp + po + 1536);
#define MM(mi, nj, HH, HL)                                                     \
    acc[mi][nj] = __builtin_amdgcn_mfma_f32_16x16x32_bf16(                     \
        (mi) ? w01r[s] : w00r[s], HH, acc[mi][nj], 0, 0, 0);                   \
    acc[mi][nj] = __builtin_amdgcn_mfma_f32_16x16x32_bf16(                     \
        (mi) ? w01r[s] : w00r[s], HL, acc[mi][nj], 0, 0, 0);                   \
    acc[mi][nj] = __builtin_amdgcn_mfma_f32_16x16x32_bf16(                     \
        (mi) ? w11r[s] : w10r[s], HH, acc[mi][nj], 0, 0, 0);
                    MM(0, 0, h0v, l0v)  MM(0, 1, h1v, l1v)
                    MM(0, 2, h2v, l2v)  MM(0, 3, h3v, l3v)
                    MM(1, 0, h0v, l0v)  MM(1, 1, h1v, l1v)
                    MM(1, 2, h2v, l2v)  MM(1, 3, h3v, l3v)
#undef MM
                }

            // k-split partials: row = mi*16+(lane>>4)*4+rr, col = nj*16+(lane&15)
            {
                const int rq = (lane >> 4) * 4, cq = lane & 15;
#pragma unroll
                for (int mi = 0; mi < 2; ++mi)
#pragma unroll
                    for (int nj = 0; nj < 4; ++nj)
#pragma unroll
                        for (int rr = 0; rr < 4; ++rr)
                            Pred[w][mi * 16 + rq + rr][nj * 16 + cq] =
                                acc[mi][nj][rr];
            }
            __syncthreads();

            // activation: thread (b = lane, col = w)
            {
                float p[4];
#pragma unroll
                for (int g = 0; g < 4; ++g) {
                    const int row = g * 8 + col;
                    float s0 = 0.f;
#pragma unroll
                    for (int ww = 0; ww < 8; ++ww)
                        s0 += Pred[ww][row][lane];
                    p[g] = s0 + bs[g];
                }
                const float fg = sigmoidf_(p[0]);
                const float ig = sigmoidf_(p[1]);
                const float gg = tanhf(p[2]);
                const float og = sigmoidf_(p[3]);
                c_ = fmaf(fg, c_, ig * gg);
                const float h = og * tanhf(c_);
                const unsigned short hh = f2bf(h);
                hasmH[lane][col] = hh;
                hasmL[lane][col] = f2bf(h - bf2f(hh));
                if (layer && r == 257)
                    hst1[(size_t)(lb * 8 + col) * 64 + lane] = h;
            }
            __syncthreads();

            // granule store: one 16B store per (plane, b)
            if (tid < 128) {
                const int p = tid >> 6, b = tid & 63;
                unsigned short* hw =
                    (layer ? h1b : h0b) + (size_t)wpar * 131072;
                const size_t off =
                    (((size_t)(p * 32 + (lb >> 2)) * 4 + (b >> 4)) * 64 +
                     ((b & 15) + 16 * (lb & 3))) * 8;
                *reinterpret_cast<short8*>(hw + off) =
                    *reinterpret_cast<const short8*>(
                        p ? &hasmL[b][0] : &hasmH[b][0]);
            }
        }

        // ---- flat 2-hop barrier (skip after final round) ----
        if (r < 257) {
            __syncthreads();                 // all stores issued; vmcnt drained
            if (tid == 0) {
                __builtin_amdgcn_fence(__ATOMIC_RELEASE, "agent");
                __hip_atomic_fetch_add(layer ? cnt1 : cnt0, 1u,
                                       __ATOMIC_RELAXED,
                                       __HIP_MEMORY_SCOPE_AGENT);
                const unsigned need = 128u * (unsigned)r;
                for (;;) {
                    const unsigned a = __hip_atomic_load(
                        cnt0, __ATOMIC_RELAXED, __HIP_MEMORY_SCOPE_AGENT);
                    const unsigned b = __hip_atomic_load(
                        cnt1, __ATOMIC_RELAXED, __HIP_MEMORY_SCOPE_AGENT);
                    if (a >= need && b >= need) break;
                    __builtin_amdgcn_s_sleep(1);
                }
                __builtin_amdgcn_fence(__ATOMIC_ACQUIRE, "agent");
            }
            __syncthreads();
        }
    }
}

// ---------------- classifier ------------------------------------------------
__global__ __launch_bounds__(256) void cls_k(
    const float* __restrict__ hfin, const float* __restrict__ Wc,
    const float* __restrict__ bcls, float* __restrict__ out)
{
    __shared__ float red[4][64];
    const int n = blockIdx.x;
    const int lane = threadIdx.x & 63, w = threadIdx.x >> 6;
    float acc = 0.f;
    for (int k = w * 256; k < w * 256 + 256; ++k)
        acc = fmaf(hfin[k * 64 + lane], Wc[k * 10 + n], acc);
    red[w][lane] = acc;
    __syncthreads();
    if (w == 0) {
        out[lane * 10 + n] = red[0][lane] + red[1][lane] + red[2][lane] +
                             red[3][lane] + bcls[n];
    }
}

extern "C" void kernel_launch(void* const* d_in, const int* in_sizes, int n_in,
                              void* d_out, int out_size, void* d_ws,
                              size_t ws_size, hipStream_t stream)
{
    const float* x    = (const float*)d_in[0];
    const float* h0   = (const float*)d_in[1];
    const float* c0   = (const float*)d_in[2];
    const float* Wenc = (const float*)d_in[3];
    const float* benc = (const float*)d_in[4];
    const float* alpha= (const float*)d_in[5];
    const float* Wx0  = (const float*)d_in[6];
    const float* bx0  = (const float*)d_in[7];
    const float* Wh0  = (const float*)d_in[8];
    const float* bh0  = (const float*)d_in[9];
    const float* Wx1  = (const float*)d_in[10];
    const float* bx1  = (const float*)d_in[11];
    const float* Wh1  = (const float*)d_in[12];
    const float* bh1  = (const float*)d_in[13];
    const float* Wcls = (const float*)d_in[14];
    const float* bcls = (const float*)d_in[15];
    float* out = (float*)d_out;

    // Workspace plan (floats): total ~23.4M floats = 94 MB.
    float* ws = (float*)d_ws;
    size_t off = 0;
    unsigned short* Ef   = (unsigned short*)(ws + off); off += 8388608;  // 16.7M sh
    unsigned short* Wf0  = (unsigned short*)(ws + off); off += 6291456;  // 12.6M sh
    unsigned short* Wf1  = (unsigned short*)(ws + off); off += 8388608;  // 16.7M sh
    unsigned short* h0b  = (unsigned short*)(ws + off); off += 131072;   // 262K sh
    unsigned short* h1b  = (unsigned short*)(ws + off); off += 131072;
    float* bsum0p = ws + off; off += 4096;
    float* bsum1p = ws + off; off += 4096;
    float* hst1   = ws + off; off += 65536;
    unsigned* bars = (unsigned*)(ws + off); off += 64;

    (void)hipMemsetAsync(bars, 0, 256, stream);

    // prologue (input-only deps)
    enc_gemm_k<<<dim3(8, 128), 256, 0, stream>>>(
        x, Wenc, Ef, benc, alpha, 16384, 512, 256, 65536, 256);
    wprep_k<<<dim3(48, 64), 256, 0, stream>>>(Wh0, Wx0, Wf0, 48);
    wprep_k<<<dim3(64, 64), 256, 0, stream>>>(Wh1, Wx1, Wf1, 64);
    hsplit_k<<<32, 256, 0, stream>>>(h0, h0b);                   // L0 h, parity 0
    hsplit_k<<<32, 256, 0, stream>>>(h0 + 65536, h1b + 131072);  // L1 h, parity 1
    bsum_k<<<16, 256, 0, stream>>>(bx0, bh0, bsum0p);
    bsum_k<<<16, 256, 0, stream>>>(bx1, bh1, bsum1p);

    // fused dual-layer LSTM, register-resident weights (257 rounds)
    fused_lstm_k<<<256, 512, 0, stream>>>(Ef, Wf0, Wf1, h0b, h1b, c0,
                                          bsum0p, bsum1p, hst1, bars);

    // classifier from layer-1 final h ([k][b])
    cls_k<<<dim3(10), 256, 0, stream>>>(hst1, Wcls, bcls, out);
}

// Round 9
// 2511.950 us; speedup vs baseline: 12.3049x; 2.2248x over previous
//
#include <hip/hip_runtime.h>
#include <hip/hip_bf16.h>
#include <cstddef>

// ---------------------------------------------------------------------------
// B=64, S=256, W=256, E=512, HID=1024, L=2, NCLS=10
// enc GEMM (fp32 -> bf16-split E in MFMA-fragment granule order) ->
// ONE fused dual-layer pipelined LSTM, register-resident weights, fence-thin
// barrier:
//   256 blocks x 512 threads. blocks 0..127 = layer 0 (K=1536, [Wh0;Wx0]);
//   blocks 128..255 = layer 1 (K=2048, [Wh1;Wx1]). 257 rounds, layer 1 lags
//   layer 0 by one step.
//   Per round: h granules stored WRITE-THROUGH (8B agent atomics) -> no
//   release fence needed; arrival via 8 spread counter lines (32 adders
//   each); block 0 aggregates and writes 8 go lines (32 pollers each);
//   single agent acquire fence (L1/L2 inv) before next round's cached reads.
// -> classifier.
// Fragment layouts (HW-validated rounds 4/6/7/8, absmax 7.6e-6):
//   A/B operand: lane = (row&15) + 16*kg holds 8 values [row][k0+kg*8 .. +7]
//   D: row = mi*16 + (lane>>4)*4 + rr, col = nj*16 + (lane&15)
// Granule layouts (16B per lane):
//   W:  Wf[lb][plane][s][mi][lane][8]
//   h:  hbuf[par][plane][s(32)][nj][lane][8]   (plane stride 65536 shorts)
//   E:  Ef[t][plane][s(16)][nj][lane][8]       (plane stride 32768 shorts)
// Row permutation: gate row j = g*1024 + lb*8 + c -> block lb, rloc = g*8+c.
// Workspace ~94 MB (known-good budget >= 279 MB).
// ---------------------------------------------------------------------------

using short8 = __attribute__((ext_vector_type(8))) short;
using f32x4  = __attribute__((ext_vector_type(4))) float;

#define LD8(p) (*reinterpret_cast<const short8*>(p))

__device__ __forceinline__ float sigmoidf_(float x) {
    return 1.f / (1.f + __expf(-x));
}
__device__ __forceinline__ unsigned short f2bf(float x) {   // RNE bf16
    union { float f; unsigned u; } v; v.f = x;
    unsigned r = v.u + 0x7fffu + ((v.u >> 16) & 1u);
    return (unsigned short)(r >> 16);
}
__device__ __forceinline__ float bf2f(unsigned short h) {
    union { unsigned u; float f; } v; v.u = ((unsigned)h) << 16;
    return v.f;
}

// ---------------- encoder GEMM (fp32 compute, granule bf16-split output) ---
__global__ __launch_bounds__(256) void enc_gemm_k(
    const float* __restrict__ A, const float* __restrict__ B,
    unsigned short* __restrict__ Ef,
    const float* __restrict__ bias1, const float* __restrict__ alphap,
    int M, int N, int K, int sB, int sS)
{
    __shared__ float As[128][17];
    __shared__ float Bs[16][64];
    const int tid = threadIdx.x;
    const int tx = tid & 15, ty = tid >> 4;
    const int rb = blockIdx.y * 128;
    const int cb = blockIdx.x * 64;

    float acc[8][4];
#pragma unroll
    for (int i = 0; i < 8; ++i)
#pragma unroll
        for (int j = 0; j < 4; ++j) acc[i][j] = 0.f;

    const int nk = K >> 4;
    for (int kt = 0; kt < nk; ++kt) {
        const int k0 = kt << 4;
        __syncthreads();
        {
            const int row = tid >> 2, k4 = tid & 3;
#pragma unroll
            for (int h = 0; h < 2; ++h) {
                const int r = rb + row + h * 64;
                const float4 v = *reinterpret_cast<const float4*>(
                    &A[(size_t)(r & 63) * sB + (size_t)(r >> 6) * sS + k0 + k4 * 4]);
                As[row + h * 64][k4 * 4 + 0] = v.x;
                As[row + h * 64][k4 * 4 + 1] = v.y;
                As[row + h * 64][k4 * 4 + 2] = v.z;
                As[row + h * 64][k4 * 4 + 3] = v.w;
            }
        }
        {
            const int bk = tid >> 4, c4 = tid & 15;
            *reinterpret_cast<float4*>(&Bs[bk][c4 * 4]) =
                *reinterpret_cast<const float4*>(
                    &B[(size_t)(k0 + bk) * N + cb + c4 * 4]);
        }
        __syncthreads();
#pragma unroll
        for (int k = 0; k < 16; ++k) {
            float a[8];
#pragma unroll
            for (int i = 0; i < 8; ++i) a[i] = As[ty * 8 + i][k];
            const float4 bv = *reinterpret_cast<const float4*>(&Bs[k][tx * 4]);
#pragma unroll
            for (int i = 0; i < 8; ++i) {
                acc[i][0] = fmaf(a[i], bv.x, acc[i][0]);
                acc[i][1] = fmaf(a[i], bv.y, acc[i][1]);
                acc[i][2] = fmaf(a[i], bv.z, acc[i][2]);
                acc[i][3] = fmaf(a[i], bv.w, acc[i][3]);
            }
        }
    }

    float bsum[4];
#pragma unroll
    for (int j = 0; j < 4; ++j) bsum[j] = bias1[cb + tx * 4 + j];
    const float alpha = alphap[0];
    const int k0c = cb + tx * 4;
    const int s = k0c >> 5, kg = (k0c >> 3) & 3, e0 = k0c & 7;
#pragma unroll
    for (int i = 0; i < 8; ++i) {
        const int r = rb + ty * 8 + i;
        const int t = r >> 6, b = r & 63;
        const int ln = (b & 15) + 16 * kg, nj = b >> 4;
        unsigned short hs[4], ls[4];
#pragma unroll
        for (int j = 0; j < 4; ++j) {
            float v = acc[i][j] + bsum[j];
            v = (v >= 0.f) ? v : alpha * v;
            hs[j] = f2bf(v);
            ls[j] = f2bf(v - bf2f(hs[j]));
        }
        uint2 hp, lp;
        hp.x = (unsigned)hs[0] | ((unsigned)hs[1] << 16);
        hp.y = (unsigned)hs[2] | ((unsigned)hs[3] << 16);
        lp.x = (unsigned)ls[0] | ((unsigned)ls[1] << 16);
        lp.y = (unsigned)ls[2] | ((unsigned)ls[3] << 16);
        const size_t base =
            ((((size_t)t * 32 + s) * 4 + nj) * 64 + ln) * 8 + e0;
        *reinterpret_cast<uint2*>(Ef + base) = hp;            // hi plane
        *reinterpret_cast<uint2*>(Ef + base + 32768) = lp;    // lo plane
    }
}

// ------------- weight prep: frag-order split planes ------------------------
__global__ __launch_bounds__(256) void wprep_k(
    const float* __restrict__ Wa, const float* __restrict__ Wb,
    unsigned short* __restrict__ Wf, int NS)
{
    __shared__ float tl[32][65];
    const int k0 = blockIdx.x * 32, j0 = blockIdx.y * 64;
    const int tid = threadIdx.x;
    {
        const int kk = tid >> 3, jq = tid & 7;
        const int k = k0 + kk;
        const float* src = (k < 1024) ? &Wa[(size_t)k * 4096]
                                      : &Wb[(size_t)(k - 1024) * 4096];
#pragma unroll
        for (int h = 0; h < 2; ++h) {
            const float4 v = *reinterpret_cast<const float4*>(
                &src[j0 + jq * 8 + h * 4]);
            tl[kk][jq * 8 + h * 4 + 0] = v.x; tl[kk][jq * 8 + h * 4 + 1] = v.y;
            tl[kk][jq * 8 + h * 4 + 2] = v.z; tl[kk][jq * 8 + h * 4 + 3] = v.w;
        }
    }
    __syncthreads();
    const int j = tid >> 2, kg = tid & 3;
    const int jg = j0 + j;
    const int g = jg >> 10, cc = jg & 1023;
    const int lb = cc >> 3, c = cc & 7;
    const int rloc = g * 8 + c;
    const int mi = rloc >> 4, r16 = rloc & 15;
    const int lane = r16 + 16 * kg;
    const int s = k0 >> 5;
    short8 hv, lv;
#pragma unroll
    for (int e = 0; e < 8; ++e) {
        const float x = tl[kg * 8 + e][j];
        const unsigned short h = f2bf(x);
        hv[e] = (short)h;
        lv[e] = (short)f2bf(x - bf2f(h));
    }
    const size_t oH = ((((size_t)lb * 2 + 0) * NS + s) * 2 + mi) * 512 + (size_t)lane * 8;
    const size_t oL = ((((size_t)lb * 2 + 1) * NS + s) * 2 + mi) * 512 + (size_t)lane * 8;
    *reinterpret_cast<short8*>(Wf + oH) = hv;
    *reinterpret_cast<short8*>(Wf + oL) = lv;
}

// ------------- h split init: hrow fp32 [64][1024] -> granule planes --------
__global__ __launch_bounds__(256) void hsplit_k(
    const float* __restrict__ hrow, unsigned short* __restrict__ dst)
{
    const int idx = blockIdx.x * 256 + threadIdx.x;   // 8192 total
    const int b = idx >> 7, gc = idx & 127;
    const int k = gc * 8;
    short8 hv, lv;
#pragma unroll
    for (int e = 0; e < 8; ++e) {
        const float x = hrow[(size_t)b * 1024 + k + e];
        const unsigned short h = f2bf(x);
        hv[e] = (short)h;
        lv[e] = (short)f2bf(x - bf2f(h));
    }
    const int s = k >> 5, kg = (k >> 3) & 3, nj = b >> 4;
    const int l = (b & 15) + 16 * kg;
    const size_t oH = (((size_t)(0 * 32 + s) * 4 + nj) * 64 + l) * 8;
    const size_t oL = (((size_t)(1 * 32 + s) * 4 + nj) * 64 + l) * 8;
    *reinterpret_cast<short8*>(dst + oH) = hv;
    *reinterpret_cast<short8*>(dst + oL) = lv;
}

// ------------- permuted bias sum: out[lb*32+g*8+c] = bx[j]+bh[j] -----------
__global__ __launch_bounds__(256) void bsum_k(
    const float* __restrict__ bx, const float* __restrict__ bh,
    float* __restrict__ out)
{
    const int r = blockIdx.x * 256 + threadIdx.x;     // 4096
    const int lb = r >> 5, rl = r & 31;
    const int g = rl >> 3, c = rl & 7;
    const int j = g * 1024 + lb * 8 + c;
    out[r] = bx[j] + bh[j];
}

// ---------------- fused dual-layer LSTM, register-resident weights ---------
// Barrier lines: arrivals bar[grp*256] (grp = bid>>5, 8 lines 1KB apart,
// 32 adders each); go flags bar[4096 + grp*256] (32 pollers each); block 0
// aggregates. h stores are write-through atomics -> no release fence; one
// agent acquire fence per round before cached h reads.
__global__ __launch_bounds__(512, 2) void fused_lstm_k(
    const unsigned short* __restrict__ Ef,
    const unsigned short* __restrict__ Wf0,
    const unsigned short* __restrict__ Wf1,
    unsigned short* __restrict__ h0b, unsigned short* __restrict__ h1b,
    const float* __restrict__ c0, const float* __restrict__ bsum0p,
    const float* __restrict__ bsum1p, float* __restrict__ hst1,
    unsigned* bar)
{
    __shared__ float Pred[8][32][66];
    __shared__ unsigned short hasmH[64][8];
    __shared__ unsigned short hasmL[64][8];

    const int tid = threadIdx.x;
    const int lane = tid & 63;                 // batch row for MFMA frags
    const int w = tid >> 6;                    // wave id 0..7
    const int bid = blockIdx.x;
    const int layer = bid >> 7;
    const int lb = bid & 127;

    const int NS = layer ? 64 : 48;            // K/32
    const int nsub = layer ? 8 : 6;            // subtiles per wave
    const int sub0 = w * nsub;
    const int wNS = NS * 1024;                 // plane offset in weight shorts

    const int grp = bid >> 5;
    unsigned* acnt = bar + grp * 256;          // arrival line (1KB spread)
    unsigned* ago  = bar + 4096 + grp * 256;   // go line

    const unsigned short* Wf = layer ? Wf1 : Wf0;
    const unsigned short* wB =
        Wf + (size_t)lb * 2 * NS * 1024 + (size_t)lane * 8;

    // ---- load this wave's weight fragments into registers (once) ----
    short8 w00r[8], w01r[8], w10r[8], w11r[8];
#pragma unroll
    for (int s = 0; s < 8; ++s)
        if (s < nsub) {
            const unsigned short* wp = wB + (size_t)(sub0 + s) * 1024;
            w00r[s] = LD8(wp);        w01r[s] = LD8(wp + 512);
            w10r[s] = LD8(wp + wNS);  w11r[s] = LD8(wp + wNS + 512);
        }

    // activation mapping: thread -> (b = lane, h-col = w)
    const int col = w;
    float c_ = c0[(size_t)layer * 65536 + (size_t)lane * 1024 + lb * 8 + col];
    const float* bsB = layer ? bsum1p : bsum0p;
    float bs[4];
#pragma unroll
    for (int g = 0; g < 4; ++g) bs[g] = bsB[lb * 32 + g * 8 + col];

    for (int r = 1; r <= 257; ++r) {
        const bool act = layer ? (r >= 2) : (r <= 256);
        if (act) {
            const int t = layer ? r - 2 : r - 1;
            const int rpar = (r - 1) & 1, wpar = r & 1;
            const unsigned short* h0r = h0b + (size_t)rpar * 131072;
            const unsigned short* h1r = h1b + (size_t)rpar * 131072;
            const unsigned short* Et = Ef + (size_t)t * 65536;

            f32x4 acc[2][4] = {};
#pragma unroll
            for (int s = 0; s < 8; ++s)
                if (s < nsub) {
                    const int sg = sub0 + s;
                    const unsigned short* hp;
                    int po;
                    if (layer) {
                        hp = (sg < 32 ? h1r + (size_t)sg * 2048
                                      : h0r + (size_t)(sg - 32) * 2048) +
                             (size_t)lane * 8;
                        po = 65536;
                    } else if (sg < 32) {
                        hp = h0r + (size_t)sg * 2048 + (size_t)lane * 8;
                        po = 65536;
                    } else {
                        hp = Et + (size_t)(sg - 32) * 2048 + (size_t)lane * 8;
                        po = 32768;
                    }
                    const short8 h0v = LD8(hp),        h1v = LD8(hp + 512);
                    const short8 h2v = LD8(hp + 1024), h3v = LD8(hp + 1536);
                    const short8 l0v = LD8(hp + po),        l1v = LD8(hp + po + 512);
                    const short8 l2v = LD8(hp + po + 1024), l3v = LD8(hp + po + 1536);
#define MM(mi, nj, HH, HL)                                                     \
    acc[mi][nj] = __builtin_amdgcn_mfma_f32_16x16x32_bf16(                     \
        (mi) ? w01r[s] : w00r[s], HH, acc[mi][nj], 0, 0, 0);                   \
    acc[mi][nj] = __builtin_amdgcn_mfma_f32_16x16x32_bf16(                     \
        (mi) ? w01r[s] : w00r[s], HL, acc[mi][nj], 0, 0, 0);                   \
    acc[mi][nj] = __builtin_amdgcn_mfma_f32_16x16x32_bf16(                     \
        (mi) ? w11r[s] : w10r[s], HH, acc[mi][nj], 0, 0, 0);
                    MM(0, 0, h0v, l0v)  MM(0, 1, h1v, l1v)
                    MM(0, 2, h2v, l2v)  MM(0, 3, h3v, l3v)
                    MM(1, 0, h0v, l0v)  MM(1, 1, h1v, l1v)
                    MM(1, 2, h2v, l2v)  MM(1, 3, h3v, l3v)
#undef MM
                }

            // k-split partials: row = mi*16+(lane>>4)*4+rr, col = nj*16+(lane&15)
            {
                const int rq = (lane >> 4) * 4, cq = lane & 15;
#pragma unroll
                for (int mi = 0; mi < 2; ++mi)
#pragma unroll
                    for (int nj = 0; nj < 4; ++nj)
#pragma unroll
                        for (int rr = 0; rr < 4; ++rr)
                            Pred[w][mi * 16 + rq + rr][nj * 16 + cq] =
                                acc[mi][nj][rr];
            }
            __syncthreads();

            // activation: thread (b = lane, col = w)
            {
                float p[4];
#pragma unroll
                for (int g = 0; g < 4; ++g) {
                    const int row = g * 8 + col;
                    float s0 = 0.f;
#pragma unroll
                    for (int ww = 0; ww < 8; ++ww)
                        s0 += Pred[ww][row][lane];
                    p[g] = s0 + bs[g];
                }
                const float fg = sigmoidf_(p[0]);
                const float ig = sigmoidf_(p[1]);
                const float gg = tanhf(p[2]);
                const float og = sigmoidf_(p[3]);
                c_ = fmaf(fg, c_, ig * gg);
                const float h = og * tanhf(c_);
                const unsigned short hh = f2bf(h);
                hasmH[lane][col] = hh;
                hasmL[lane][col] = f2bf(h - bf2f(hh));
                if (layer && r == 257)
                    hst1[(size_t)(lb * 8 + col) * 64 + lane] = h;
            }
            __syncthreads();

            // granule store: write-through agent atomics (2 x 8B per thread)
            if (tid < 128) {
                const int p = tid >> 6, b = tid & 63;
                unsigned short* hw =
                    (layer ? h1b : h0b) + (size_t)wpar * 131072;
                const size_t off =
                    (((size_t)(p * 32 + (lb >> 2)) * 4 + (b >> 4)) * 64 +
                     ((b & 15) + 16 * (lb & 3))) * 8;
                const unsigned long long* src =
                    reinterpret_cast<const unsigned long long*>(
                        p ? &hasmL[b][0] : &hasmH[b][0]);
                unsigned long long* dst =
                    reinterpret_cast<unsigned long long*>(hw + off);
                __hip_atomic_store(dst, src[0], __ATOMIC_RELAXED,
                                   __HIP_MEMORY_SCOPE_AGENT);
                __hip_atomic_store(dst + 1, src[1], __ATOMIC_RELAXED,
                                   __HIP_MEMORY_SCOPE_AGENT);
            }
        }

        // ---- fence-thin barrier (skip after final round) ----
        if (r < 257) {
            __syncthreads();          // drains each wave's vmem (stores done)
            if (tid == 0) {
                __hip_atomic_fetch_add(acnt, 1u, __ATOMIC_RELAXED,
                                       __HIP_MEMORY_SCOPE_AGENT);
                if (bid == 0) {
                    const unsigned need = 32u * (unsigned)r;
#pragma unroll 1
                    for (int g = 0; g < 8; ++g) {
                        while (__hip_atomic_load(bar + g * 256,
                                                 __ATOMIC_RELAXED,
                                                 __HIP_MEMORY_SCOPE_AGENT) < need)
                            __builtin_amdgcn_s_sleep(2);
                    }
                    asm volatile("" ::: "memory");
#pragma unroll 1
                    for (int g = 0; g < 8; ++g)
                        __hip_atomic_store(bar + 4096 + g * 256, (unsigned)r,
                                           __ATOMIC_RELAXED,
                                           __HIP_MEMORY_SCOPE_AGENT);
                }
                while (__hip_atomic_load(ago, __ATOMIC_RELAXED,
                                         __HIP_MEMORY_SCOPE_AGENT) < (unsigned)r)
                    __builtin_amdgcn_s_sleep(2);
                __builtin_amdgcn_fence(__ATOMIC_ACQUIRE, "agent");
            }
            __syncthreads();
        }
    }
}

// ---------------- classifier ------------------------------------------------
__global__ __launch_bounds__(256) void cls_k(
    const float* __restrict__ hfin, const float* __restrict__ Wc,
    const float* __restrict__ bcls, float* __restrict__ out)
{
    __shared__ float red[4][64];
    const int n = blockIdx.x;
    const int lane = threadIdx.x & 63, w = threadIdx.x >> 6;
    float acc = 0.f;
    for (int k = w * 256; k < w * 256 + 256; ++k)
        acc = fmaf(hfin[k * 64 + lane], Wc[k * 10 + n], acc);
    red[w][lane] = acc;
    __syncthreads();
    if (w == 0) {
        out[lane * 10 + n] = red[0][lane] + red[1][lane] + red[2][lane] +
                             red[3][lane] + bcls[n];
    }
}

extern "C" void kernel_launch(void* const* d_in, const int* in_sizes, int n_in,
                              void* d_out, int out_size, void* d_ws,
                              size_t ws_size, hipStream_t stream)
{
    const float* x    = (const float*)d_in[0];
    const float* h0   = (const float*)d_in[1];
    const float* c0   = (const float*)d_in[2];
    const float* Wenc = (const float*)d_in[3];
    const float* benc = (const float*)d_in[4];
    const float* alpha= (const float*)d_in[5];
    const float* Wx0  = (const float*)d_in[6];
    const float* bx0  = (const float*)d_in[7];
    const float* Wh0  = (const float*)d_in[8];
    const float* bh0  = (const float*)d_in[9];
    const float* Wx1  = (const float*)d_in[10];
    const float* bx1  = (const float*)d_in[11];
    const float* Wh1  = (const float*)d_in[12];
    const float* bh1  = (const float*)d_in[13];
    const float* Wcls = (const float*)d_in[14];
    const float* bcls = (const float*)d_in[15];
    float* out = (float*)d_out;

    // Workspace plan (floats): total ~23.4M floats = 94 MB.
    float* ws = (float*)d_ws;
    size_t off = 0;
    unsigned short* Ef   = (unsigned short*)(ws + off); off += 8388608;  // 16.7M sh
    unsigned short* Wf0  = (unsigned short*)(ws + off); off += 6291456;  // 12.6M sh
    unsigned short* Wf1  = (unsigned short*)(ws + off); off += 8388608;  // 16.7M sh
    unsigned short* h0b  = (unsigned short*)(ws + off); off += 131072;   // 262K sh
    unsigned short* h1b  = (unsigned short*)(ws + off); off += 131072;
    float* bsum0p = ws + off; off += 4096;
    float* bsum1p = ws + off; off += 4096;
    float* hst1   = ws + off; off += 65536;
    unsigned* bars = (unsigned*)(ws + off); off += 8192;   // 32 KB barrier area

    (void)hipMemsetAsync(bars, 0, 32768, stream);

    // prologue (input-only deps)
    enc_gemm_k<<<dim3(8, 128), 256, 0, stream>>>(
        x, Wenc, Ef, benc, alpha, 16384, 512, 256, 65536, 256);
    wprep_k<<<dim3(48, 64), 256, 0, stream>>>(Wh0, Wx0, Wf0, 48);
    wprep_k<<<dim3(64, 64), 256, 0, stream>>>(Wh1, Wx1, Wf1, 64);
    hsplit_k<<<32, 256, 0, stream>>>(h0, h0b);                   // L0 h, parity 0
    hsplit_k<<<32, 256, 0, stream>>>(h0 + 65536, h1b + 131072);  // L1 h, parity 1
    bsum_k<<<16, 256, 0, stream>>>(bx0, bh0, bsum0p);
    bsum_k<<<16, 256, 0, stream>>>(bx1, bh1, bsum1p);

    // fused dual-layer LSTM, register-resident weights (257 rounds)
    fused_lstm_k<<<256, 512, 0, stream>>>(Ef, Wf0, Wf1, h0b, h1b, c0,
                                          bsum0p, bsum1p, hst1, bars);

    // classifier from layer-1 final h ([k][b])
    cls_k<<<dim3(10), 256, 0, stream>>>(hst1, Wcls, bcls, out);
}

// Round 10
// 2336.578 us; speedup vs baseline: 13.2284x; 1.0751x over previous
//
#include <hip/hip_runtime.h>
#include <hip/hip_bf16.h>
#include <cstddef>

// ---------------------------------------------------------------------------
// B=64, S=256, W=256, E=512, HID=1024, L=2, NCLS=10
// enc GEMM (fp32 -> bf16-split E in MFMA-fragment granule order) ->
// ONE fused dual-layer LSTM, register-resident weights, DECOUPLED per-layer
// barrier domains + write-once state slots:
//   256 blocks x 512 threads. blocks 0..127 = layer 0 (K=1536, [Wh0;Wx0]);
//   blocks 128..255 = layer 1 (K=2048, [Wh1;Wx1]). 257 rounds, layer 1 lags
//   layer 0 by one step.
//   State: Y0[0..256] / H1[0..256] slot arrays (slot 0 = initial h, slot t+1
//   = h after step t; write-once, write-through 8B agent atomics).
//   Sync: per-block slot stores (no RMW); aggregator block per layer
//   (bid 0 / bid 128) polls its 128 slots with 128 parallel threads, then
//   publishes 8 mirrored go lines. Layer-0 waits only on go0. Layer-1 waits
//   on go1 AND go0 (forward-only cross dependency). Acquire fence after.
// -> classifier.
// Fragment layouts (HW-validated rounds 4/6/7/8/9, absmax 7.6e-6):
//   A/B operand: lane = (row&15) + 16*kg holds 8 values [row][k0+kg*8 .. +7]
//   D: row = mi*16 + (lane>>4)*4 + rr, col = nj*16 + (lane&15)
// Granule layouts (16B per lane):
//   W:  Wf[lb][plane][s][mi][lane][8]
//   h slot:  [plane][s(32)][nj][lane][8]  (plane stride 65536 shorts,
//            slot stride 131072 shorts = 256KB)
//   E:  Ef[t][plane][s(16)][nj][lane][8]  (plane stride 32768 shorts)
// Row permutation: gate row j = g*1024 + lb*8 + c -> block lb, rloc = g*8+c.
// Workspace ~227 MB (known-good budget >= 279 MB).
// ---------------------------------------------------------------------------

using short8 = __attribute__((ext_vector_type(8))) short;
using f32x4  = __attribute__((ext_vector_type(4))) float;

#define LD8(p) (*reinterpret_cast<const short8*>(p))

__device__ __forceinline__ float sigmoidf_(float x) {
    return 1.f / (1.f + __expf(-x));
}
__device__ __forceinline__ unsigned short f2bf(float x) {   // RNE bf16
    union { float f; unsigned u; } v; v.f = x;
    unsigned r = v.u + 0x7fffu + ((v.u >> 16) & 1u);
    return (unsigned short)(r >> 16);
}
__device__ __forceinline__ float bf2f(unsigned short h) {
    union { unsigned u; float f; } v; v.u = ((unsigned)h) << 16;
    return v.f;
}

// ---------------- encoder GEMM (fp32 compute, granule bf16-split output) ---
__global__ __launch_bounds__(256) void enc_gemm_k(
    const float* __restrict__ A, const float* __restrict__ B,
    unsigned short* __restrict__ Ef,
    const float* __restrict__ bias1, const float* __restrict__ alphap,
    int M, int N, int K, int sB, int sS)
{
    __shared__ float As[128][17];
    __shared__ float Bs[16][64];
    const int tid = threadIdx.x;
    const int tx = tid & 15, ty = tid >> 4;
    const int rb = blockIdx.y * 128;
    const int cb = blockIdx.x * 64;

    float acc[8][4];
#pragma unroll
    for (int i = 0; i < 8; ++i)
#pragma unroll
        for (int j = 0; j < 4; ++j) acc[i][j] = 0.f;

    const int nk = K >> 4;
    for (int kt = 0; kt < nk; ++kt) {
        const int k0 = kt << 4;
        __syncthreads();
        {
            const int row = tid >> 2, k4 = tid & 3;
#pragma unroll
            for (int h = 0; h < 2; ++h) {
                const int r = rb + row + h * 64;
                const float4 v = *reinterpret_cast<const float4*>(
                    &A[(size_t)(r & 63) * sB + (size_t)(r >> 6) * sS + k0 + k4 * 4]);
                As[row + h * 64][k4 * 4 + 0] = v.x;
                As[row + h * 64][k4 * 4 + 1] = v.y;
                As[row + h * 64][k4 * 4 + 2] = v.z;
                As[row + h * 64][k4 * 4 + 3] = v.w;
            }
        }
        {
            const int bk = tid >> 4, c4 = tid & 15;
            *reinterpret_cast<float4*>(&Bs[bk][c4 * 4]) =
                *reinterpret_cast<const float4*>(
                    &B[(size_t)(k0 + bk) * N + cb + c4 * 4]);
        }
        __syncthreads();
#pragma unroll
        for (int k = 0; k < 16; ++k) {
            float a[8];
#pragma unroll
            for (int i = 0; i < 8; ++i) a[i] = As[ty * 8 + i][k];
            const float4 bv = *reinterpret_cast<const float4*>(&Bs[k][tx * 4]);
#pragma unroll
            for (int i = 0; i < 8; ++i) {
                acc[i][0] = fmaf(a[i], bv.x, acc[i][0]);
                acc[i][1] = fmaf(a[i], bv.y, acc[i][1]);
                acc[i][2] = fmaf(a[i], bv.z, acc[i][2]);
                acc[i][3] = fmaf(a[i], bv.w, acc[i][3]);
            }
        }
    }

    float bsum[4];
#pragma unroll
    for (int j = 0; j < 4; ++j) bsum[j] = bias1[cb + tx * 4 + j];
    const float alpha = alphap[0];
    const int k0c = cb + tx * 4;
    const int s = k0c >> 5, kg = (k0c >> 3) & 3, e0 = k0c & 7;
#pragma unroll
    for (int i = 0; i < 8; ++i) {
        const int r = rb + ty * 8 + i;
        const int t = r >> 6, b = r & 63;
        const int ln = (b & 15) + 16 * kg, nj = b >> 4;
        unsigned short hs[4], ls[4];
#pragma unroll
        for (int j = 0; j < 4; ++j) {
            float v = acc[i][j] + bsum[j];
            v = (v >= 0.f) ? v : alpha * v;
            hs[j] = f2bf(v);
            ls[j] = f2bf(v - bf2f(hs[j]));
        }
        uint2 hp, lp;
        hp.x = (unsigned)hs[0] | ((unsigned)hs[1] << 16);
        hp.y = (unsigned)hs[2] | ((unsigned)hs[3] << 16);
        lp.x = (unsigned)ls[0] | ((unsigned)ls[1] << 16);
        lp.y = (unsigned)ls[2] | ((unsigned)ls[3] << 16);
        const size_t base =
            ((((size_t)t * 32 + s) * 4 + nj) * 64 + ln) * 8 + e0;
        *reinterpret_cast<uint2*>(Ef + base) = hp;            // hi plane
        *reinterpret_cast<uint2*>(Ef + base + 32768) = lp;    // lo plane
    }
}

// ------------- weight prep: frag-order split planes ------------------------
__global__ __launch_bounds__(256) void wprep_k(
    const float* __restrict__ Wa, const float* __restrict__ Wb,
    unsigned short* __restrict__ Wf, int NS)
{
    __shared__ float tl[32][65];
    const int k0 = blockIdx.x * 32, j0 = blockIdx.y * 64;
    const int tid = threadIdx.x;
    {
        const int kk = tid >> 3, jq = tid & 7;
        const int k = k0 + kk;
        const float* src = (k < 1024) ? &Wa[(size_t)k * 4096]
                                      : &Wb[(size_t)(k - 1024) * 4096];
#pragma unroll
        for (int h = 0; h < 2; ++h) {
            const float4 v = *reinterpret_cast<const float4*>(
                &src[j0 + jq * 8 + h * 4]);
            tl[kk][jq * 8 + h * 4 + 0] = v.x; tl[kk][jq * 8 + h * 4 + 1] = v.y;
            tl[kk][jq * 8 + h * 4 + 2] = v.z; tl[kk][jq * 8 + h * 4 + 3] = v.w;
        }
    }
    __syncthreads();
    const int j = tid >> 2, kg = tid & 3;
    const int jg = j0 + j;
    const int g = jg >> 10, cc = jg & 1023;
    const int lb = cc >> 3, c = cc & 7;
    const int rloc = g * 8 + c;
    const int mi = rloc >> 4, r16 = rloc & 15;
    const int lane = r16 + 16 * kg;
    const int s = k0 >> 5;
    short8 hv, lv;
#pragma unroll
    for (int e = 0; e < 8; ++e) {
        const float x = tl[kg * 8 + e][j];
        const unsigned short h = f2bf(x);
        hv[e] = (short)h;
        lv[e] = (short)f2bf(x - bf2f(h));
    }
    const size_t oH = ((((size_t)lb * 2 + 0) * NS + s) * 2 + mi) * 512 + (size_t)lane * 8;
    const size_t oL = ((((size_t)lb * 2 + 1) * NS + s) * 2 + mi) * 512 + (size_t)lane * 8;
    *reinterpret_cast<short8*>(Wf + oH) = hv;
    *reinterpret_cast<short8*>(Wf + oL) = lv;
}

// ------------- h split init: hrow fp32 [64][1024] -> granule slot ----------
__global__ __launch_bounds__(256) void hsplit_k(
    const float* __restrict__ hrow, unsigned short* __restrict__ dst)
{
    const int idx = blockIdx.x * 256 + threadIdx.x;   // 8192 total
    const int b = idx >> 7, gc = idx & 127;
    const int k = gc * 8;
    short8 hv, lv;
#pragma unroll
    for (int e = 0; e < 8; ++e) {
        const float x = hrow[(size_t)b * 1024 + k + e];
        const unsigned short h = f2bf(x);
        hv[e] = (short)h;
        lv[e] = (short)f2bf(x - bf2f(h));
    }
    const int s = k >> 5, kg = (k >> 3) & 3, nj = b >> 4;
    const int l = (b & 15) + 16 * kg;
    const size_t oH = (((size_t)(0 * 32 + s) * 4 + nj) * 64 + l) * 8;
    const size_t oL = (((size_t)(1 * 32 + s) * 4 + nj) * 64 + l) * 8;
    *reinterpret_cast<short8*>(dst + oH) = hv;
    *reinterpret_cast<short8*>(dst + oL) = lv;
}

// ------------- permuted bias sum: out[lb*32+g*8+c] = bx[j]+bh[j] -----------
__global__ __launch_bounds__(256) void bsum_k(
    const float* __restrict__ bx, const float* __restrict__ bh,
    float* __restrict__ out)
{
    const int r = blockIdx.x * 256 + threadIdx.x;     // 4096
    const int lb = r >> 5, rl = r & 31;
    const int g = rl >> 3, c = rl & 7;
    const int j = g * 1024 + lb * 8 + c;
    out[r] = bx[j] + bh[j];
}

// ---------------- fused dual-layer LSTM, decoupled barrier domains ---------
// bar layout (uints): block slots at bid*32 (256 x 128B); go0 mirrors at
// 8192+g*32 (g<8); go1 mirrors at 8704+g*32.
__global__ __launch_bounds__(512, 2) void fused_lstm_k(
    const unsigned short* __restrict__ Ef,
    const unsigned short* __restrict__ Wf0,
    const unsigned short* __restrict__ Wf1,
    unsigned short* __restrict__ Y0, unsigned short* __restrict__ H1,
    const float* __restrict__ c0, const float* __restrict__ bsum0p,
    const float* __restrict__ bsum1p, float* __restrict__ hst1,
    unsigned* bar)
{
    __shared__ float Pred[8][32][66];
    __shared__ unsigned short hasmH[64][8];
    __shared__ unsigned short hasmL[64][8];

    const int tid = threadIdx.x;
    const int lane = tid & 63;                 // batch row for MFMA frags
    const int w = tid >> 6;                    // wave id 0..7
    const int bid = blockIdx.x;
    const int layer = bid >> 7;
    const int lb = bid & 127;

    const int NS = layer ? 64 : 48;            // K/32
    const int nsub = layer ? 8 : 6;            // subtiles per wave
    const int sub0 = w * nsub;
    const int wNS = NS * 1024;                 // plane offset in weight shorts

    const unsigned short* Wf = layer ? Wf1 : Wf0;
    const unsigned short* wB =
        Wf + (size_t)lb * 2 * NS * 1024 + (size_t)lane * 8;

    // ---- load this wave's weight fragments into registers (once) ----
    short8 w00r[8], w01r[8], w10r[8], w11r[8];
#pragma unroll
    for (int s = 0; s < 8; ++s)
        if (s < nsub) {
            const unsigned short* wp = wB + (size_t)(sub0 + s) * 1024;
            w00r[s] = LD8(wp);        w01r[s] = LD8(wp + 512);
            w10r[s] = LD8(wp + wNS);  w11r[s] = LD8(wp + wNS + 512);
        }

    // activation mapping: thread -> (b = lane, h-col = w)
    const int col = w;
    float c_ = c0[(size_t)layer * 65536 + (size_t)lane * 1024 + lb * 8 + col];
    const float* bsB = layer ? bsum1p : bsum0p;
    float bs[4];
#pragma unroll
    for (int g = 0; g < 4; ++g) bs[g] = bsB[lb * 32 + g * 8 + col];

    for (int r = 1; r <= 257; ++r) {
        const bool act = layer ? (r >= 2) : (r <= 256);
        if (act) {
            const int t = layer ? r - 2 : r - 1;
            // own-layer h state (slot t), cross input (y0 slot t+1 / E[t])
            const unsigned short* hOwn =
                (layer ? H1 : Y0) + (size_t)t * 131072 + (size_t)lane * 8;
            const unsigned short* hCross = layer
                ? Y0 + (size_t)(t + 1) * 131072 + (size_t)lane * 8
                : Ef + (size_t)t * 65536 + (size_t)lane * 8;
            const int poCross = layer ? 65536 : 32768;

            f32x4 acc[2][4] = {};
#pragma unroll
            for (int s = 0; s < 8; ++s)
                if (s < nsub) {
                    const int sg = sub0 + s;
                    const unsigned short* hp;
                    int po;
                    if (sg < 32) {
                        hp = hOwn + (size_t)sg * 2048;
                        po = 65536;
                    } else {
                        hp = hCross + (size_t)(sg - 32) * 2048;
                        po = poCross;
                    }
                    const short8 h0v = LD8(hp),        h1v = LD8(hp + 512);
                    const short8 h2v = LD8(hp + 1024), h3v = LD8(hp + 1536);
                    const short8 l0v = LD8(hp + po),        l1v = LD8(hp + po + 512);
                    const short8 l2v = LD8(hp + po + 1024), l3v = LD8(hp + po + 1536);
#define MM(mi, nj, HH, HL)                                                     \
    acc[mi][nj] = __builtin_amdgcn_mfma_f32_16x16x32_bf16(                     \
        (mi) ? w01r[s] : w00r[s], HH, acc[mi][nj], 0, 0, 0);                   \
    acc[mi][nj] = __builtin_amdgcn_mfma_f32_16x16x32_bf16(                     \
        (mi) ? w01r[s] : w00r[s], HL, acc[mi][nj], 0, 0, 0);                   \
    acc[mi][nj] = __builtin_amdgcn_mfma_f32_16x16x32_bf16(                     \
        (mi) ? w11r[s] : w10r[s], HH, acc[mi][nj], 0, 0, 0);
                    MM(0, 0, h0v, l0v)  MM(0, 1, h1v, l1v)
                    MM(0, 2, h2v, l2v)  MM(0, 3, h3v, l3v)
                    MM(1, 0, h0v, l0v)  MM(1, 1, h1v, l1v)
                    MM(1, 2, h2v, l2v)  MM(1, 3, h3v, l3v)
#undef MM
                }

            // k-split partials: row = mi*16+(lane>>4)*4+rr, col = nj*16+(lane&15)
            {
                const int rq = (lane >> 4) * 4, cq = lane & 15;
#pragma unroll
                for (int mi = 0; mi < 2; ++mi)
#pragma unroll
                    for (int nj = 0; nj < 4; ++nj)
#pragma unroll
                        for (int rr = 0; rr < 4; ++rr)
                            Pred[w][mi * 16 + rq + rr][nj * 16 + cq] =
                                acc[mi][nj][rr];
            }
            __syncthreads();

            // activation: thread (b = lane, col = w)
            {
                float p[4];
#pragma unroll
                for (int g = 0; g < 4; ++g) {
                    const int row = g * 8 + col;
                    float s0 = 0.f;
#pragma unroll
                    for (int ww = 0; ww < 8; ++ww)
                        s0 += Pred[ww][row][lane];
                    p[g] = s0 + bs[g];
                }
                const float fg = sigmoidf_(p[0]);
                const float ig = sigmoidf_(p[1]);
                const float gg = tanhf(p[2]);
                const float og = sigmoidf_(p[3]);
                c_ = fmaf(fg, c_, ig * gg);
                const float h = og * tanhf(c_);
                const unsigned short hh = f2bf(h);
                hasmH[lane][col] = hh;
                hasmL[lane][col] = f2bf(h - bf2f(hh));
                if (layer && r == 257)
                    hst1[(size_t)(lb * 8 + col) * 64 + lane] = h;
            }
            __syncthreads();

            // granule store -> write-once slot t+1 (write-through atomics)
            if (tid < 128) {
                const int p = tid >> 6, b = tid & 63;
                unsigned short* hw =
                    (layer ? H1 : Y0) + (size_t)(t + 1) * 131072;
                const size_t off =
                    (((size_t)(p * 32 + (lb >> 2)) * 4 + (b >> 4)) * 64 +
                     ((b & 15) + 16 * (lb & 3))) * 8;
                const unsigned long long* src =
                    reinterpret_cast<const unsigned long long*>(
                        p ? &hasmL[b][0] : &hasmH[b][0]);
                unsigned long long* dst =
                    reinterpret_cast<unsigned long long*>(hw + off);
                __hip_atomic_store(dst, src[0], __ATOMIC_RELAXED,
                                   __HIP_MEMORY_SCOPE_AGENT);
                __hip_atomic_store(dst + 1, src[1], __ATOMIC_RELAXED,
                                   __HIP_MEMORY_SCOPE_AGENT);
            }
        }

        // ---- decoupled per-layer barrier (skip after final round) ----
        if (r < 257) {
            __syncthreads();          // drains each wave's vmem (stores at CP)
            const unsigned rr = (unsigned)r;
            if (tid == 0)
                __hip_atomic_store(bar + (size_t)bid * 32, rr,
                                   __ATOMIC_RELAXED, __HIP_MEMORY_SCOPE_AGENT);
            if (bid == 0) {                       // layer-0 aggregator
                if (tid < 128) {
                    while (__hip_atomic_load(bar + (size_t)tid * 32,
                                             __ATOMIC_RELAXED,
                                             __HIP_MEMORY_SCOPE_AGENT) < rr)
                        __builtin_amdgcn_s_sleep(1);
                }
                __syncthreads();
                if (tid == 0)
#pragma unroll
                    for (int g = 0; g < 8; ++g)
                        __hip_atomic_store(bar + 8192 + g * 32, rr,
                                           __ATOMIC_RELAXED,
                                           __HIP_MEMORY_SCOPE_AGENT);
            } else if (bid == 128) {              // layer-1 aggregator
                if (tid < 128) {
                    while (__hip_atomic_load(bar + (size_t)(128 + tid) * 32,
                                             __ATOMIC_RELAXED,
                                             __HIP_MEMORY_SCOPE_AGENT) < rr)
                        __builtin_amdgcn_s_sleep(1);
                }
                __syncthreads();
                if (tid == 0)
#pragma unroll
                    for (int g = 0; g < 8; ++g)
                        __hip_atomic_store(bar + 8704 + g * 32, rr,
                                           __ATOMIC_RELAXED,
                                           __HIP_MEMORY_SCOPE_AGENT);
            }
            if (tid == 0) {
                unsigned* g0 = bar + 8192 + (bid & 7) * 32;
                if (layer == 0) {
                    while (__hip_atomic_load(g0, __ATOMIC_RELAXED,
                                             __HIP_MEMORY_SCOPE_AGENT) < rr)
                        __builtin_amdgcn_s_sleep(1);
                } else {
                    unsigned* g1 = bar + 8704 + (bid & 7) * 32;
                    for (;;) {
                        const unsigned a = __hip_atomic_load(
                            g1, __ATOMIC_RELAXED, __HIP_MEMORY_SCOPE_AGENT);
                        const unsigned b = __hip_atomic_load(
                            g0, __ATOMIC_RELAXED, __HIP_MEMORY_SCOPE_AGENT);
                        if (a >= rr && b >= rr) break;
                        __builtin_amdgcn_s_sleep(1);
                    }
                }
                __builtin_amdgcn_fence(__ATOMIC_ACQUIRE, "agent");
            }
            __syncthreads();
        }
    }
}

// ---------------- classifier ------------------------------------------------
__global__ __launch_bounds__(256) void cls_k(
    const float* __restrict__ hfin, const float* __restrict__ Wc,
    const float* __restrict__ bcls, float* __restrict__ out)
{
    __shared__ float red[4][64];
    const int n = blockIdx.x;
    const int lane = threadIdx.x & 63, w = threadIdx.x >> 6;
    float acc = 0.f;
    for (int k = w * 256; k < w * 256 + 256; ++k)
        acc = fmaf(hfin[k * 64 + lane], Wc[k * 10 + n], acc);
    red[w][lane] = acc;
    __syncthreads();
    if (w == 0) {
        out[lane * 10 + n] = red[0][lane] + red[1][lane] + red[2][lane] +
                             red[3][lane] + bcls[n];
    }
}

extern "C" void kernel_launch(void* const* d_in, const int* in_sizes, int n_in,
                              void* d_out, int out_size, void* d_ws,
                              size_t ws_size, hipStream_t stream)
{
    const float* x    = (const float*)d_in[0];
    const float* h0   = (const float*)d_in[1];
    const float* c0   = (const float*)d_in[2];
    const float* Wenc = (const float*)d_in[3];
    const float* benc = (const float*)d_in[4];
    const float* alpha= (const float*)d_in[5];
    const float* Wx0  = (const float*)d_in[6];
    const float* bx0  = (const float*)d_in[7];
    const float* Wh0  = (const float*)d_in[8];
    const float* bh0  = (const float*)d_in[9];
    const float* Wx1  = (const float*)d_in[10];
    const float* bx1  = (const float*)d_in[11];
    const float* Wh1  = (const float*)d_in[12];
    const float* bh1  = (const float*)d_in[13];
    const float* Wcls = (const float*)d_in[14];
    const float* bcls = (const float*)d_in[15];
    float* out = (float*)d_out;

    // Workspace plan (floats): ~56.9M floats = 227 MB (budget >= 279 MB).
    float* ws = (float*)d_ws;
    size_t off = 0;
    unsigned short* Ef   = (unsigned short*)(ws + off); off += 8388608;   // 16.7M sh
    unsigned short* Wf0  = (unsigned short*)(ws + off); off += 6291456;   // 12.6M sh
    unsigned short* Wf1  = (unsigned short*)(ws + off); off += 8388608;   // 16.7M sh
    unsigned short* Y0   = (unsigned short*)(ws + off); off += 16842752;  // 257 slots
    unsigned short* H1   = (unsigned short*)(ws + off); off += 16842752;  // 257 slots
    float* bsum0p = ws + off; off += 4096;
    float* bsum1p = ws + off; off += 4096;
    float* hst1   = ws + off; off += 65536;
    unsigned* bars = (unsigned*)(ws + off); off += 16384;   // 64 KB barrier area

    (void)hipMemsetAsync(bars, 0, 65536, stream);

    // prologue (input-only deps)
    enc_gemm_k<<<dim3(8, 128), 256, 0, stream>>>(
        x, Wenc, Ef, benc, alpha, 16384, 512, 256, 65536, 256);
    wprep_k<<<dim3(48, 64), 256, 0, stream>>>(Wh0, Wx0, Wf0, 48);
    wprep_k<<<dim3(64, 64), 256, 0, stream>>>(Wh1, Wx1, Wf1, 64);
    hsplit_k<<<32, 256, 0, stream>>>(h0, Y0);                // h0_init -> slot 0
    hsplit_k<<<32, 256, 0, stream>>>(h0 + 65536, H1);        // h1_init -> slot 0
    bsum_k<<<16, 256, 0, stream>>>(bx0, bh0, bsum0p);
    bsum_k<<<16, 256, 0, stream>>>(bx1, bh1, bsum1p);

    // fused dual-layer LSTM, decoupled barrier domains (257 rounds)
    fused_lstm_k<<<256, 512, 0, stream>>>(Ef, Wf0, Wf1, Y0, H1, c0,
                                          bsum0p, bsum1p, hst1, bars);

    // classifier from layer-1 final h ([k][b])
    cls_k<<<dim3(10), 256, 0, stream>>>(hst1, Wcls, bcls, out);
}

// Round 11
// 1913.295 us; speedup vs baseline: 16.1550x; 1.2212x over previous
//
#include <hip/hip_runtime.h>
#include <hip/hip_bf16.h>
#include <cstddef>

// ---------------------------------------------------------------------------
// B=64, S=256, W=256, E=512, HID=1024, L=2, NCLS=10
// enc GEMM (fp32 -> bf16-split E in MFMA-fragment granule order) ->
// ONE fused dual-layer LSTM, register-resident weights, PEER-TO-PEER flag
// sync (no aggregator, no go-lines, no per-round fences):
//   256 blocks x 512 threads. blocks 0..127 = layer 0 (K=1536, [Wh0;Wx0]);
//   blocks 128..255 = layer 1 (K=2048, [Wh1;Wx1]).
//   State: Y0[0..256] / H1[0..256] write-once slot arrays (slot 0 = initial
//   h, slot t+1 = h after step t), stored write-through (8B agent atomics).
//   Sync: each block stores flag[bid] = r (after vmcnt drain via
//   __syncthreads). Consumers poll the 128 flags they need with 128 parallel
//   threads. Fence-free: every consumed h line is read exactly once, only
//   after its producer's write-through store reached the coherence point
//   (flag protocol), and was never cached locally before -> no stale copies.
//   Dependency-ordered compute: independent subtiles (E / y0-cross) run
//   BEFORE the own-layer poll to hide flag propagation.
//   Layer 0 never waits on layer 1 (write-once => no back-pressure); it
//   free-runs; layer 1's L0 poll is satisfied ~always instantly.
// -> classifier.
// Fragment layouts (HW-validated rounds 4/6/7/8/9/10, absmax 7.6e-6):
//   A/B operand: lane = (row&15) + 16*kg holds 8 values [row][k0+kg*8 .. +7]
//   D: row = mi*16 + (lane>>4)*4 + rr, col = nj*16 + (lane&15)
// Granule layouts (16B per lane):
//   W:  Wf[lb][plane][s][mi][lane][8]
//   h slot:  [plane][s(32)][nj][lane][8]  (plane stride 65536 shorts,
//            slot stride 131072 shorts = 256KB)
//   E:  Ef[t][plane][s(16)][nj][lane][8]  (plane stride 32768 shorts)
// Row permutation: gate row j = g*1024 + lb*8 + c -> block lb, rloc = g*8+c.
// Per-wave subtile map (register idx i): i<4 -> own sg = w*4+i;
//   i>=4 -> cross: layer0 sg = 32+w*2+(i-4) (E, 2), layer1 sg = 32+w*4+(i-4)
//   (y0, 4).
// Workspace ~227 MB (known-good budget >= 279 MB).
// ---------------------------------------------------------------------------

using short8 = __attribute__((ext_vector_type(8))) short;
using f32x4  = __attribute__((ext_vector_type(4))) float;

#define LD8(p) (*reinterpret_cast<const short8*>(p))

__device__ __forceinline__ float sigmoidf_(float x) {
    return 1.f / (1.f + __expf(-x));
}
__device__ __forceinline__ unsigned short f2bf(float x) {   // RNE bf16
    union { float f; unsigned u; } v; v.f = x;
    unsigned r = v.u + 0x7fffu + ((v.u >> 16) & 1u);
    return (unsigned short)(r >> 16);
}
__device__ __forceinline__ float bf2f(unsigned short h) {
    union { unsigned u; float f; } v; v.u = ((unsigned)h) << 16;
    return v.f;
}

// ---------------- encoder GEMM (fp32 compute, granule bf16-split output) ---
__global__ __launch_bounds__(256) void enc_gemm_k(
    const float* __restrict__ A, const float* __restrict__ B,
    unsigned short* __restrict__ Ef,
    const float* __restrict__ bias1, const float* __restrict__ alphap,
    int M, int N, int K, int sB, int sS)
{
    __shared__ float As[128][17];
    __shared__ float Bs[16][64];
    const int tid = threadIdx.x;
    const int tx = tid & 15, ty = tid >> 4;
    const int rb = blockIdx.y * 128;
    const int cb = blockIdx.x * 64;

    float acc[8][4];
#pragma unroll
    for (int i = 0; i < 8; ++i)
#pragma unroll
        for (int j = 0; j < 4; ++j) acc[i][j] = 0.f;

    const int nk = K >> 4;
    for (int kt = 0; kt < nk; ++kt) {
        const int k0 = kt << 4;
        __syncthreads();
        {
            const int row = tid >> 2, k4 = tid & 3;
#pragma unroll
            for (int h = 0; h < 2; ++h) {
                const int r = rb + row + h * 64;
                const float4 v = *reinterpret_cast<const float4*>(
                    &A[(size_t)(r & 63) * sB + (size_t)(r >> 6) * sS + k0 + k4 * 4]);
                As[row + h * 64][k4 * 4 + 0] = v.x;
                As[row + h * 64][k4 * 4 + 1] = v.y;
                As[row + h * 64][k4 * 4 + 2] = v.z;
                As[row + h * 64][k4 * 4 + 3] = v.w;
            }
        }
        {
            const int bk = tid >> 4, c4 = tid & 15;
            *reinterpret_cast<float4*>(&Bs[bk][c4 * 4]) =
                *reinterpret_cast<const float4*>(
                    &B[(size_t)(k0 + bk) * N + cb + c4 * 4]);
        }
        __syncthreads();
#pragma unroll
        for (int k = 0; k < 16; ++k) {
            float a[8];
#pragma unroll
            for (int i = 0; i < 8; ++i) a[i] = As[ty * 8 + i][k];
            const float4 bv = *reinterpret_cast<const float4*>(&Bs[k][tx * 4]);
#pragma unroll
            for (int i = 0; i < 8; ++i) {
                acc[i][0] = fmaf(a[i], bv.x, acc[i][0]);
                acc[i][1] = fmaf(a[i], bv.y, acc[i][1]);
                acc[i][2] = fmaf(a[i], bv.z, acc[i][2]);
                acc[i][3] = fmaf(a[i], bv.w, acc[i][3]);
            }
        }
    }

    float bsum[4];
#pragma unroll
    for (int j = 0; j < 4; ++j) bsum[j] = bias1[cb + tx * 4 + j];
    const float alpha = alphap[0];
    const int k0c = cb + tx * 4;
    const int s = k0c >> 5, kg = (k0c >> 3) & 3, e0 = k0c & 7;
#pragma unroll
    for (int i = 0; i < 8; ++i) {
        const int r = rb + ty * 8 + i;
        const int t = r >> 6, b = r & 63;
        const int ln = (b & 15) + 16 * kg, nj = b >> 4;
        unsigned short hs[4], ls[4];
#pragma unroll
        for (int j = 0; j < 4; ++j) {
            float v = acc[i][j] + bsum[j];
            v = (v >= 0.f) ? v : alpha * v;
            hs[j] = f2bf(v);
            ls[j] = f2bf(v - bf2f(hs[j]));
        }
        uint2 hp, lp;
        hp.x = (unsigned)hs[0] | ((unsigned)hs[1] << 16);
        hp.y = (unsigned)hs[2] | ((unsigned)hs[3] << 16);
        lp.x = (unsigned)ls[0] | ((unsigned)ls[1] << 16);
        lp.y = (unsigned)ls[2] | ((unsigned)ls[3] << 16);
        const size_t base =
            ((((size_t)t * 32 + s) * 4 + nj) * 64 + ln) * 8 + e0;
        *reinterpret_cast<uint2*>(Ef + base) = hp;            // hi plane
        *reinterpret_cast<uint2*>(Ef + base + 32768) = lp;    // lo plane
    }
}

// ------------- weight prep: frag-order split planes ------------------------
__global__ __launch_bounds__(256) void wprep_k(
    const float* __restrict__ Wa, const float* __restrict__ Wb,
    unsigned short* __restrict__ Wf, int NS)
{
    __shared__ float tl[32][65];
    const int k0 = blockIdx.x * 32, j0 = blockIdx.y * 64;
    const int tid = threadIdx.x;
    {
        const int kk = tid >> 3, jq = tid & 7;
        const int k = k0 + kk;
        const float* src = (k < 1024) ? &Wa[(size_t)k * 4096]
                                      : &Wb[(size_t)(k - 1024) * 4096];
#pragma unroll
        for (int h = 0; h < 2; ++h) {
            const float4 v = *reinterpret_cast<const float4*>(
                &src[j0 + jq * 8 + h * 4]);
            tl[kk][jq * 8 + h * 4 + 0] = v.x; tl[kk][jq * 8 + h * 4 + 1] = v.y;
            tl[kk][jq * 8 + h * 4 + 2] = v.z; tl[kk][jq * 8 + h * 4 + 3] = v.w;
        }
    }
    __syncthreads();
    const int j = tid >> 2, kg = tid & 3;
    const int jg = j0 + j;
    const int g = jg >> 10, cc = jg & 1023;
    const int lb = cc >> 3, c = cc & 7;
    const int rloc = g * 8 + c;
    const int mi = rloc >> 4, r16 = rloc & 15;
    const int lane = r16 + 16 * kg;
    const int s = k0 >> 5;
    short8 hv, lv;
#pragma unroll
    for (int e = 0; e < 8; ++e) {
        const float x = tl[kg * 8 + e][j];
        const unsigned short h = f2bf(x);
        hv[e] = (short)h;
        lv[e] = (short)f2bf(x - bf2f(h));
    }
    const size_t oH = ((((size_t)lb * 2 + 0) * NS + s) * 2 + mi) * 512 + (size_t)lane * 8;
    const size_t oL = ((((size_t)lb * 2 + 1) * NS + s) * 2 + mi) * 512 + (size_t)lane * 8;
    *reinterpret_cast<short8*>(Wf + oH) = hv;
    *reinterpret_cast<short8*>(Wf + oL) = lv;
}

// ------------- h split init: hrow fp32 [64][1024] -> granule slot ----------
__global__ __launch_bounds__(256) void hsplit_k(
    const float* __restrict__ hrow, unsigned short* __restrict__ dst)
{
    const int idx = blockIdx.x * 256 + threadIdx.x;   // 8192 total
    const int b = idx >> 7, gc = idx & 127;
    const int k = gc * 8;
    short8 hv, lv;
#pragma unroll
    for (int e = 0; e < 8; ++e) {
        const float x = hrow[(size_t)b * 1024 + k + e];
        const unsigned short h = f2bf(x);
        hv[e] = (short)h;
        lv[e] = (short)f2bf(x - bf2f(h));
    }
    const int s = k >> 5, kg = (k >> 3) & 3, nj = b >> 4;
    const int l = (b & 15) + 16 * kg;
    const size_t oH = (((size_t)(0 * 32 + s) * 4 + nj) * 64 + l) * 8;
    const size_t oL = (((size_t)(1 * 32 + s) * 4 + nj) * 64 + l) * 8;
    *reinterpret_cast<short8*>(dst + oH) = hv;
    *reinterpret_cast<short8*>(dst + oL) = lv;
}

// ------------- permuted bias sum: out[lb*32+g*8+c] = bx[j]+bh[j] -----------
__global__ __launch_bounds__(256) void bsum_k(
    const float* __restrict__ bx, const float* __restrict__ bh,
    float* __restrict__ out)
{
    const int r = blockIdx.x * 256 + threadIdx.x;     // 4096
    const int lb = r >> 5, rl = r & 31;
    const int g = rl >> 3, c = rl & 7;
    const int j = g * 1024 + lb * 8 + c;
    out[r] = bx[j] + bh[j];
}

// ---------------- fused dual-layer LSTM, peer-to-peer flag sync ------------
// bar: per-block flags at bid*32 uints (256 x 128B). flag[bid] = last round
// whose stores are visible at the coherence point.
__device__ __forceinline__ void poll_flags(unsigned* bar, int base,
                                           unsigned need, int tid) {
    if (tid < 128) {
        unsigned* p = bar + (size_t)(base + tid) * 32;
        while (__hip_atomic_load(p, __ATOMIC_RELAXED,
                                 __HIP_MEMORY_SCOPE_AGENT) < need)
            __builtin_amdgcn_s_sleep(1);
    }
    __syncthreads();   // joins + orders subsequent loads after the poll
}

__global__ __launch_bounds__(512, 2) void fused_lstm_k(
    const unsigned short* __restrict__ Ef,
    const unsigned short* __restrict__ Wf0,
    const unsigned short* __restrict__ Wf1,
    unsigned short* __restrict__ Y0, unsigned short* __restrict__ H1,
    const float* __restrict__ c0, const float* __restrict__ bsum0p,
    const float* __restrict__ bsum1p, float* __restrict__ hst1,
    unsigned* bar)
{
    __shared__ float Pred[8][32][66];
    __shared__ unsigned short hasmH[64][8];
    __shared__ unsigned short hasmL[64][8];

    const int tid = threadIdx.x;
    const int lane = tid & 63;                 // batch row for MFMA frags
    const int w = tid >> 6;                    // wave id 0..7
    const int bid = blockIdx.x;
    const int layer = bid >> 7;
    const int lb = bid & 127;

    const int NS = layer ? 64 : 48;            // K/32
    const int nEx = layer ? 4 : 2;             // cross subtiles per wave
    const int wNS = NS * 1024;                 // plane offset in weight shorts

    const unsigned short* Wf = layer ? Wf1 : Wf0;
    const unsigned short* wB =
        Wf + (size_t)lb * 2 * NS * 1024 + (size_t)lane * 8;

    // ---- load this wave's weight fragments into registers (once) ----
    // regidx i<4: own sg = w*4+i; i>=4: cross sg (E or y0), see header.
    short8 w00r[8], w01r[8], w10r[8], w11r[8];
#pragma unroll
    for (int i = 0; i < 8; ++i)
        if (i < 4 + nEx) {
            const int sg = (i < 4)
                ? (w * 4 + i)
                : (layer ? (32 + w * 4 + (i - 4)) : (32 + w * 2 + (i - 4)));
            const unsigned short* wp = wB + (size_t)sg * 1024;
            w00r[i] = LD8(wp);        w01r[i] = LD8(wp + 512);
            w10r[i] = LD8(wp + wNS);  w11r[i] = LD8(wp + wNS + 512);
        }

    // activation mapping: thread -> (b = lane, h-col = w)
    const int col = w;
    float c_ = c0[(size_t)layer * 65536 + (size_t)lane * 1024 + lb * 8 + col];
    const float* bsB = layer ? bsum1p : bsum0p;
    float bs[4];
#pragma unroll
    for (int g = 0; g < 4; ++g) bs[g] = bsB[lb * 32 + g * 8 + col];

#define MM(mi, nj, HH, HL)                                                     \
    acc[mi][nj] = __builtin_amdgcn_mfma_f32_16x16x32_bf16(                     \
        (mi) ? w01r[i] : w00r[i], HH, acc[mi][nj], 0, 0, 0);                   \
    acc[mi][nj] = __builtin_amdgcn_mfma_f32_16x16x32_bf16(                     \
        (mi) ? w01r[i] : w00r[i], HL, acc[mi][nj], 0, 0, 0);                   \
    acc[mi][nj] = __builtin_amdgcn_mfma_f32_16x16x32_bf16(                     \
        (mi) ? w11r[i] : w10r[i], HH, acc[mi][nj], 0, 0, 0);
#define SUBTILE(hp, po)                                                        \
    {                                                                          \
        const short8 h0v = LD8(hp),        h1v = LD8(hp + 512);                \
        const short8 h2v = LD8(hp + 1024), h3v = LD8(hp + 1536);               \
        const short8 l0v = LD8(hp + po),        l1v = LD8(hp + po + 512);      \
        const short8 l2v = LD8(hp + po + 1024), l3v = LD8(hp + po + 1536);     \
        MM(0, 0, h0v, l0v)  MM(0, 1, h1v, l1v)                                 \
        MM(0, 2, h2v, l2v)  MM(0, 3, h3v, l3v)                                 \
        MM(1, 0, h0v, l0v)  MM(1, 1, h1v, l1v)                                 \
        MM(1, 2, h2v, l2v)  MM(1, 3, h3v, l3v)                                 \
    }

    for (int r = 1; r <= 257; ++r) {
        const bool act = layer ? (r >= 2) : (r <= 256);
        if (act) {
            const int t = layer ? r - 2 : r - 1;
            const unsigned short* hOwn =
                (layer ? H1 : Y0) + (size_t)t * 131072 + (size_t)lane * 8;
            const unsigned short* hCross = layer
                ? Y0 + (size_t)(t + 1) * 131072 + (size_t)lane * 8
                : Ef + (size_t)t * 65536 + (size_t)lane * 8;
            const int poCross = layer ? 65536 : 32768;

            f32x4 acc[2][4] = {};

            // cross part: layer0 E (no dep); layer1 y0 (needs L0 >= r-1,
            // L0 free-runs ahead -> poll returns ~instantly)
            if (layer) poll_flags(bar, 0, (unsigned)(r - 1), tid);
#pragma unroll
            for (int i = 4; i < 8; ++i)
                if (i < 4 + nEx) {
                    const int cs = layer ? (w * 4 + (i - 4)) : (w * 2 + (i - 4));
                    const unsigned short* hp = hCross + (size_t)cs * 2048;
                    SUBTILE(hp, poCross)
                }

            // own part: needs own-layer peers >= r-1
            if (r >= 2) poll_flags(bar, layer ? 128 : 0, (unsigned)(r - 1), tid);
#pragma unroll
            for (int i = 0; i < 4; ++i) {
                const unsigned short* hp = hOwn + (size_t)(w * 4 + i) * 2048;
                SUBTILE(hp, 65536)
            }

            // k-split partials: row = mi*16+(lane>>4)*4+rr, col = nj*16+(lane&15)
            {
                const int rq = (lane >> 4) * 4, cq = lane & 15;
#pragma unroll
                for (int mi = 0; mi < 2; ++mi)
#pragma unroll
                    for (int nj = 0; nj < 4; ++nj)
#pragma unroll
                        for (int rr = 0; rr < 4; ++rr)
                            Pred[w][mi * 16 + rq + rr][nj * 16 + cq] =
                                acc[mi][nj][rr];
            }
            __syncthreads();

            // activation: thread (b = lane, col = w)
            {
                float p[4];
#pragma unroll
                for (int g = 0; g < 4; ++g) {
                    const int row = g * 8 + col;
                    float s0 = 0.f;
#pragma unroll
                    for (int ww = 0; ww < 8; ++ww)
                        s0 += Pred[ww][row][lane];
                    p[g] = s0 + bs[g];
                }
                const float fg = sigmoidf_(p[0]);
                const float ig = sigmoidf_(p[1]);
                const float gg = tanhf(p[2]);
                const float og = sigmoidf_(p[3]);
                c_ = fmaf(fg, c_, ig * gg);
                const float h = og * tanhf(c_);
                const unsigned short hh = f2bf(h);
                hasmH[lane][col] = hh;
                hasmL[lane][col] = f2bf(h - bf2f(hh));
                if (layer && r == 257)
                    hst1[(size_t)(lb * 8 + col) * 64 + lane] = h;
            }
            __syncthreads();

            // granule store -> write-once slot t+1 (write-through atomics)
            if (tid < 128) {
                const int p = tid >> 6, b = tid & 63;
                unsigned short* hw =
                    (layer ? H1 : Y0) + (size_t)(t + 1) * 131072;
                const size_t off =
                    (((size_t)(p * 32 + (lb >> 2)) * 4 + (b >> 4)) * 64 +
                     ((b & 15) + 16 * (lb & 3))) * 8;
                const unsigned long long* src =
                    reinterpret_cast<const unsigned long long*>(
                        p ? &hasmL[b][0] : &hasmH[b][0]);
                unsigned long long* dst =
                    reinterpret_cast<unsigned long long*>(hw + off);
                __hip_atomic_store(dst, src[0], __ATOMIC_RELAXED,
                                   __HIP_MEMORY_SCOPE_AGENT);
                __hip_atomic_store(dst + 1, src[1], __ATOMIC_RELAXED,
                                   __HIP_MEMORY_SCOPE_AGENT);
            }
        }

        // ---- publish flag (stores drained by the barrier's vmcnt wait) ----
        if (r <= 256) {
            __syncthreads();
            if (tid == 0)
                __hip_atomic_store(bar + (size_t)bid * 32, (unsigned)r,
                                   __ATOMIC_RELAXED, __HIP_MEMORY_SCOPE_AGENT);
        }
    }
#undef SUBTILE
#undef MM
}

// ---------------- classifier ------------------------------------------------
__global__ __launch_bounds__(256) void cls_k(
    const float* __restrict__ hfin, const float* __restrict__ Wc,
    const float* __restrict__ bcls, float* __restrict__ out)
{
    __shared__ float red[4][64];
    const int n = blockIdx.x;
    const int lane = threadIdx.x & 63, w = threadIdx.x >> 6;
    float acc = 0.f;
    for (int k = w * 256; k < w * 256 + 256; ++k)
        acc = fmaf(hfin[k * 64 + lane], Wc[k * 10 + n], acc);
    red[w][lane] = acc;
    __syncthreads();
    if (w == 0) {
        out[lane * 10 + n] = red[0][lane] + red[1][lane] + red[2][lane] +
                             red[3][lane] + bcls[n];
    }
}

extern "C" void kernel_launch(void* const* d_in, const int* in_sizes, int n_in,
                              void* d_out, int out_size, void* d_ws,
                              size_t ws_size, hipStream_t stream)
{
    const float* x    = (const float*)d_in[0];
    const float* h0   = (const float*)d_in[1];
    const float* c0   = (const float*)d_in[2];
    const float* Wenc = (const float*)d_in[3];
    const float* benc = (const float*)d_in[4];
    const float* alpha= (const float*)d_in[5];
    const float* Wx0  = (const float*)d_in[6];
    const float* bx0  = (const float*)d_in[7];
    const float* Wh0  = (const float*)d_in[8];
    const float* bh0  = (const float*)d_in[9];
    const float* Wx1  = (const float*)d_in[10];
    const float* bx1  = (const float*)d_in[11];
    const float* Wh1  = (const float*)d_in[12];
    const float* bh1  = (const float*)d_in[13];
    const float* Wcls = (const float*)d_in[14];
    const float* bcls = (const float*)d_in[15];
    float* out = (float*)d_out;

    // Workspace plan (floats): ~56.9M floats = 227 MB (budget >= 279 MB).
    float* ws = (float*)d_ws;
    size_t off = 0;
    unsigned short* Ef   = (unsigned short*)(ws + off); off += 8388608;   // 16.7M sh
    unsigned short* Wf0  = (unsigned short*)(ws + off); off += 6291456;   // 12.6M sh
    unsigned short* Wf1  = (unsigned short*)(ws + off); off += 8388608;   // 16.7M sh
    unsigned short* Y0   = (unsigned short*)(ws + off); off += 16842752;  // 257 slots
    unsigned short* H1   = (unsigned short*)(ws + off); off += 16842752;  // 257 slots
    float* bsum0p = ws + off; off += 4096;
    float* bsum1p = ws + off; off += 4096;
    float* hst1   = ws + off; off += 65536;
    unsigned* bars = (unsigned*)(ws + off); off += 8192;   // 32 KB flag area

    (void)hipMemsetAsync(bars, 0, 32768, stream);

    // prologue (input-only deps)
    enc_gemm_k<<<dim3(8, 128), 256, 0, stream>>>(
        x, Wenc, Ef, benc, alpha, 16384, 512, 256, 65536, 256);
    wprep_k<<<dim3(48, 64), 256, 0, stream>>>(Wh0, Wx0, Wf0, 48);
    wprep_k<<<dim3(64, 64), 256, 0, stream>>>(Wh1, Wx1, Wf1, 64);
    hsplit_k<<<32, 256, 0, stream>>>(h0, Y0);                // h0_init -> slot 0
    hsplit_k<<<32, 256, 0, stream>>>(h0 + 65536, H1);        // h1_init -> slot 0
    bsum_k<<<16, 256, 0, stream>>>(bx0, bh0, bsum0p);
    bsum_k<<<16, 256, 0, stream>>>(bx1, bh1, bsum1p);

    // fused dual-layer LSTM, peer-to-peer flag sync (257 rounds)
    fused_lstm_k<<<256, 512, 0, stream>>>(Ef, Wf0, Wf1, Y0, H1, c0,
                                          bsum0p, bsum1p, hst1, bars);

    // classifier from layer-1 final h ([k][b])
    cls_k<<<dim3(10), 256, 0, stream>>>(hst1, Wcls, bcls, out);
}

// Round 12
// 1911.291 us; speedup vs baseline: 16.1719x; 1.0010x over previous
//
#include <hip/hip_runtime.h>
#include <hip/hip_bf16.h>
#include <cstddef>

// ---------------------------------------------------------------------------
// B=64, S=256, W=256, E=512, HID=1024, L=2, NCLS=10
// xsplit + WencT split -> enc MFMA GEMM (3-pass split-bf16, granule epilogue)
// -> ONE fused dual-layer LSTM, register-resident weights, PER-WAVE p2p flag
// sync (wave w polls only its 16 producers; no block-wide poll joins):
//   256 blocks x 512 threads. blocks 0..127 = layer 0 (K=1536, [Wh0;Wx0]);
//   blocks 128..255 = layer 1 (K=2048, [Wh1;Wx1]).
//   State: Y0[0..256] / H1[0..256] write-once slot arrays, write-through 8B
//   agent atomics. Flags: flag[bid] = r after block-wide store drain.
//   Wave w own-h k-range = [w*128,(w+1)*128) -> producers w*16..w*16+15.
//   Fence-free: consumed lines are write-once, read only after producer's
//   flag (which follows its vmcnt drain), never locally cached earlier.
// -> classifier.
// Fragment layouts (HW-validated rounds 4/6..11, absmax 7.6e-6):
//   A/B operand: lane = (row&15) + 16*kg holds 8 values [row][k0+kg*8 .. +7]
//   D: row = mi*16 + (lane>>4)*4 + rr, col = nj*16 + (lane&15)
// Granule layouts (16B per lane):
//   W:  Wf[lb][plane][s][mi][lane][8]
//   h slot: [plane][s(32)][nj][lane][8] (plane stride 65536 sh, slot 131072)
//   E:  Ef[t][plane][s(16)][nj][lane][8] (plane stride 32768 sh)
// Row permutation: gate row j = g*1024 + lb*8 + c -> block lb, rloc = g*8+c.
// Workspace ~245 MB (known-good budget >= 279 MB).
// ---------------------------------------------------------------------------

using short8 = __attribute__((ext_vector_type(8))) short;
using f32x4  = __attribute__((ext_vector_type(4))) float;

#define LD8(p) (*reinterpret_cast<const short8*>(p))

__device__ __forceinline__ float sigmoidf_(float x) {
    return 1.f / (1.f + __expf(-x));
}
__device__ __forceinline__ unsigned short f2bf(float x) {   // RNE bf16
    union { float f; unsigned u; } v; v.f = x;
    unsigned r = v.u + 0x7fffu + ((v.u >> 16) & 1u);
    return (unsigned short)(r >> 16);
}
__device__ __forceinline__ float bf2f(unsigned short h) {
    union { unsigned u; float f; } v; v.u = ((unsigned)h) << 16;
    return v.f;
}

// ------------- x split: x[b][t][k] f32 -> Xhi/Xlo [m=t*64+b][256] bf16 -----
__global__ __launch_bounds__(256) void xsplit_k(
    const float* __restrict__ x, unsigned short* __restrict__ Xhi,
    unsigned short* __restrict__ Xlo)
{
    const int idx = blockIdx.x * 256 + threadIdx.x;   // 524288 total
    const int m = idx >> 5, kq = idx & 31;
    const int b = m & 63, t = m >> 6;
    const float* src = x + (size_t)b * 65536 + (size_t)t * 256 + kq * 8;
    short8 hv, lv;
#pragma unroll
    for (int e = 0; e < 8; ++e) {
        const float f = src[e];
        const unsigned short h = f2bf(f);
        hv[e] = (short)h;
        lv[e] = (short)f2bf(f - bf2f(h));
    }
    const size_t o = (size_t)m * 256 + kq * 8;
    *reinterpret_cast<short8*>(Xhi + o) = hv;
    *reinterpret_cast<short8*>(Xlo + o) = lv;
}

// ------------- W split+transpose: W[K][N] f32 -> Bt hi/lo [N][K] bf16 ------
__global__ __launch_bounds__(256) void bsplitN_k(
    const float* __restrict__ W, unsigned short* __restrict__ Bhi,
    unsigned short* __restrict__ Blo, int K, int N)
{
    __shared__ float tl[32][65];
    const int k0 = blockIdx.x * 32, n0 = blockIdx.y * 64;
    const int tid = threadIdx.x;
    {
        const int kk = tid >> 3, nq = tid & 7;
#pragma unroll
        for (int j = 0; j < 2; ++j) {
            const float4 v = *reinterpret_cast<const float4*>(
                &W[(size_t)(k0 + kk) * N + n0 + nq * 8 + j * 4]);
            tl[kk][nq * 8 + j * 4 + 0] = v.x; tl[kk][nq * 8 + j * 4 + 1] = v.y;
            tl[kk][nq * 8 + j * 4 + 2] = v.z; tl[kk][nq * 8 + j * 4 + 3] = v.w;
        }
    }
    __syncthreads();
    const int n = tid >> 2, kq = tid & 3;
    short8 hv, lv;
#pragma unroll
    for (int j = 0; j < 8; ++j) {
        const float xv = tl[kq * 8 + j][n];
        const unsigned short h = f2bf(xv);
        hv[j] = (short)h;
        lv[j] = (short)f2bf(xv - bf2f(h));
    }
    const size_t o = (size_t)(n0 + n) * K + k0 + kq * 8;
    *reinterpret_cast<short8*>(&Bhi[o]) = hv;
    *reinterpret_cast<short8*>(&Blo[o]) = lv;
}

// ------------- enc MFMA GEMM: Ef = PReLU(X @ Wenc + benc), granule out -----
// A planes [16384][256]; B planes transposed [512][256]. BM=128, BN=128,
// BK=32, 4 waves (2m x 2n), wave tile 64x64. K=256. Grid (4, 128).
__global__ __launch_bounds__(256) void enc_mfma_k(
    const unsigned short* __restrict__ Ahi, const unsigned short* __restrict__ Alo,
    const unsigned short* __restrict__ Bhi, const unsigned short* __restrict__ Blo,
    unsigned short* __restrict__ Ef, const float* __restrict__ benc,
    const float* __restrict__ alphap)
{
    __shared__ float smemf[10240];                       // 40 KB
    unsigned short* const smemh = (unsigned short*)smemf;
    unsigned short* const As0 = smemh;
    unsigned short* const As1 = smemh + 5120;
    unsigned short* const Bs0 = smemh + 10240;
    unsigned short* const Bs1 = smemh + 15360;

    const int tid = threadIdx.x;
    const int lane = tid & 63, wid = tid >> 6;
    const int wm = wid >> 1, wn = wid & 1;
    const int m0 = blockIdx.y * 128;
    const int n0 = blockIdx.x * 128;
    const int K = 256;

    f32x4 acc[4][4] = {};

    const int sr = tid & 127;
    const int spl = tid >> 7;
    const unsigned short* Ag = (spl ? Alo : Ahi) + (size_t)(m0 + sr) * K;
    const unsigned short* Bg = (spl ? Blo : Bhi) + (size_t)(n0 + sr) * K;
    unsigned short* Asw = (spl ? As1 : As0) + sr * 40;
    unsigned short* Bsw = (spl ? Bs1 : Bs0) + sr * 40;
    const int sw = sr & 3;

    const int kg = lane >> 4;
    const int fr = lane & 15;

    for (int k0 = 0; k0 < K; k0 += 32) {
        short8 av[4], bv[4];
#pragma unroll
        for (int c = 0; c < 4; ++c) {
            av[c] = LD8(Ag + k0 + c * 8);
            bv[c] = LD8(Bg + k0 + c * 8);
        }
        __syncthreads();
#pragma unroll
        for (int c = 0; c < 4; ++c) {
            *reinterpret_cast<short8*>(Asw + ((c ^ sw) * 8)) = av[c];
            *reinterpret_cast<short8*>(Bsw + ((c ^ sw) * 8)) = bv[c];
        }
        __syncthreads();

        short8 af[2][4], bf[2][4];
#pragma unroll
        for (int i = 0; i < 4; ++i) {
            const int ra = wm * 64 + i * 16 + fr;
            const int rb = wn * 64 + i * 16 + fr;
            af[0][i] = LD8(As0 + ra * 40 + ((kg ^ (ra & 3)) * 8));
            af[1][i] = LD8(As1 + ra * 40 + ((kg ^ (ra & 3)) * 8));
            bf[0][i] = LD8(Bs0 + rb * 40 + ((kg ^ (rb & 3)) * 8));
            bf[1][i] = LD8(Bs1 + rb * 40 + ((kg ^ (rb & 3)) * 8));
        }
#pragma unroll
        for (int i = 0; i < 4; ++i)
#pragma unroll
            for (int j = 0; j < 4; ++j) {
                acc[i][j] = __builtin_amdgcn_mfma_f32_16x16x32_bf16(
                    af[0][i], bf[0][j], acc[i][j], 0, 0, 0);
                acc[i][j] = __builtin_amdgcn_mfma_f32_16x16x32_bf16(
                    af[0][i], bf[1][j], acc[i][j], 0, 0, 0);
                acc[i][j] = __builtin_amdgcn_mfma_f32_16x16x32_bf16(
                    af[1][i], bf[0][j], acc[i][j], 0, 0, 0);
            }
    }
    __syncthreads();                                     // staging LDS dead

    // Epilogue: per-wave slab [16 n][65 m] -> PReLU+split -> Ef granules.
    float* slab = smemf + wid * 1040;
    const int t = (m0 >> 6) + wm;                        // this wave's t
    const int fq = lane >> 4;
    const float alpha = alphap[0];
#pragma unroll 1
    for (int j = 0; j < 4; ++j) {
#pragma unroll
        for (int i = 0; i < 4; ++i)
#pragma unroll
            for (int rr = 0; rr < 4; ++rr)
                slab[fr * 65 + i * 16 + fq * 4 + rr] = acc[i][j][rr];
        __syncthreads();
        const int b = lane;                              // m_local = batch
        const int nj = b >> 4;
#pragma unroll
        for (int ng = 0; ng < 4; ++ng) {
            const int n = n0 + wn * 64 + j * 16 + ng * 4;
            unsigned short hs[4], ls[4];
#pragma unroll
            for (int v = 0; v < 4; ++v) {
                float f = slab[(ng * 4 + v) * 65 + b] + benc[n + v];
                f = (f >= 0.f) ? f : alpha * f;
                hs[v] = f2bf(f);
                ls[v] = f2bf(f - bf2f(hs[v]));
            }
            uint2 hp, lp;
            hp.x = (unsigned)hs[0] | ((unsigned)hs[1] << 16);
            hp.y = (unsigned)hs[2] | ((unsigned)hs[3] << 16);
            lp.x = (unsigned)ls[0] | ((unsigned)ls[1] << 16);
            lp.y = (unsigned)ls[2] | ((unsigned)ls[3] << 16);
            const int s = n >> 5, kgn = (n >> 3) & 3, e0 = n & 7;
            const int ln = (b & 15) + 16 * kgn;
            const size_t base =
                ((((size_t)t * 32 + s) * 4 + nj) * 64 + ln) * 8 + e0;
            *reinterpret_cast<uint2*>(Ef + base) = hp;
            *reinterpret_cast<uint2*>(Ef + base + 32768) = lp;
        }
        __syncthreads();
    }
}

// ------------- weight prep: frag-order split planes ------------------------
__global__ __launch_bounds__(256) void wprep_k(
    const float* __restrict__ Wa, const float* __restrict__ Wb,
    unsigned short* __restrict__ Wf, int NS)
{
    __shared__ float tl[32][65];
    const int k0 = blockIdx.x * 32, j0 = blockIdx.y * 64;
    const int tid = threadIdx.x;
    {
        const int kk = tid >> 3, jq = tid & 7;
        const int k = k0 + kk;
        const float* src = (k < 1024) ? &Wa[(size_t)k * 4096]
                                      : &Wb[(size_t)(k - 1024) * 4096];
#pragma unroll
        for (int h = 0; h < 2; ++h) {
            const float4 v = *reinterpret_cast<const float4*>(
                &src[j0 + jq * 8 + h * 4]);
            tl[kk][jq * 8 + h * 4 + 0] = v.x; tl[kk][jq * 8 + h * 4 + 1] = v.y;
            tl[kk][jq * 8 + h * 4 + 2] = v.z; tl[kk][jq * 8 + h * 4 + 3] = v.w;
        }
    }
    __syncthreads();
    const int j = tid >> 2, kg = tid & 3;
    const int jg = j0 + j;
    const int g = jg >> 10, cc = jg & 1023;
    const int lb = cc >> 3, c = cc & 7;
    const int rloc = g * 8 + c;
    const int mi = rloc >> 4, r16 = rloc & 15;
    const int lane = r16 + 16 * kg;
    const int s = k0 >> 5;
    short8 hv, lv;
#pragma unroll
    for (int e = 0; e < 8; ++e) {
        const float x = tl[kg * 8 + e][j];
        const unsigned short h = f2bf(x);
        hv[e] = (short)h;
        lv[e] = (short)f2bf(x - bf2f(h));
    }
    const size_t oH = ((((size_t)lb * 2 + 0) * NS + s) * 2 + mi) * 512 + (size_t)lane * 8;
    const size_t oL = ((((size_t)lb * 2 + 1) * NS + s) * 2 + mi) * 512 + (size_t)lane * 8;
    *reinterpret_cast<short8*>(Wf + oH) = hv;
    *reinterpret_cast<short8*>(Wf + oL) = lv;
}

// ------------- h split init: hrow fp32 [64][1024] -> granule slot ----------
__global__ __launch_bounds__(256) void hsplit_k(
    const float* __restrict__ hrow, unsigned short* __restrict__ dst)
{
    const int idx = blockIdx.x * 256 + threadIdx.x;   // 8192 total
    const int b = idx >> 7, gc = idx & 127;
    const int k = gc * 8;
    short8 hv, lv;
#pragma unroll
    for (int e = 0; e < 8; ++e) {
        const float x = hrow[(size_t)b * 1024 + k + e];
        const unsigned short h = f2bf(x);
        hv[e] = (short)h;
        lv[e] = (short)f2bf(x - bf2f(h));
    }
    const int s = k >> 5, kg = (k >> 3) & 3, nj = b >> 4;
    const int l = (b & 15) + 16 * kg;
    const size_t oH = (((size_t)(0 * 32 + s) * 4 + nj) * 64 + l) * 8;
    const size_t oL = (((size_t)(1 * 32 + s) * 4 + nj) * 64 + l) * 8;
    *reinterpret_cast<short8*>(dst + oH) = hv;
    *reinterpret_cast<short8*>(dst + oL) = lv;
}

// ------------- permuted bias sum: out[lb*32+g*8+c] = bx[j]+bh[j] -----------
__global__ __launch_bounds__(256) void bsum_k(
    const float* __restrict__ bx, const float* __restrict__ bh,
    float* __restrict__ out)
{
    const int r = blockIdx.x * 256 + threadIdx.x;     // 4096
    const int lb = r >> 5, rl = r & 31;
    const int g = rl >> 3, c = rl & 7;
    const int j = g * 1024 + lb * 8 + c;
    out[r] = bx[j] + bh[j];
}

// ---------------- fused dual-layer LSTM, per-wave p2p flag sync ------------
// bar: per-block flags at bid*32 uints (256 x 128B).
__global__ __launch_bounds__(512, 2) void fused_lstm_k(
    const unsigned short* __restrict__ Ef,
    const unsigned short* __restrict__ Wf0,
    const unsigned short* __restrict__ Wf1,
    unsigned short* __restrict__ Y0, unsigned short* __restrict__ H1,
    const float* __restrict__ c0, const float* __restrict__ bsum0p,
    const float* __restrict__ bsum1p, float* __restrict__ hst1,
    unsigned* bar)
{
    __shared__ float Pred[8][32][66];
    __shared__ unsigned short hasmH[64][8];
    __shared__ unsigned short hasmL[64][8];

    const int tid = threadIdx.x;
    const int lane = tid & 63;                 // batch row for MFMA frags
    const int w = tid >> 6;                    // wave id 0..7
    const int bid = blockIdx.x;
    const int layer = bid >> 7;
    const int lb = bid & 127;

    const int NS = layer ? 64 : 48;            // K/32
    const int nEx = layer ? 4 : 2;             // cross subtiles per wave
    const int wNS = NS * 1024;                 // plane offset in weight shorts

    const unsigned short* Wf = layer ? Wf1 : Wf0;
    const unsigned short* wB =
        Wf + (size_t)lb * 2 * NS * 1024 + (size_t)lane * 8;

    // ---- load this wave's weight fragments into registers (once) ----
    short8 w00r[8], w01r[8], w10r[8], w11r[8];
#pragma unroll
    for (int i = 0; i < 8; ++i)
        if (i < 4 + nEx) {
            const int sg = (i < 4)
                ? (w * 4 + i)
                : (layer ? (32 + w * 4 + (i - 4)) : (32 + w * 2 + (i - 4)));
            const unsigned short* wp = wB + (size_t)sg * 1024;
            w00r[i] = LD8(wp);        w01r[i] = LD8(wp + 512);
            w10r[i] = LD8(wp + wNS);  w11r[i] = LD8(wp + wNS + 512);
        }

    // activation mapping: thread -> (b = lane, h-col = w)
    const int col = w;
    float c_ = c0[(size_t)layer * 65536 + (size_t)lane * 1024 + lb * 8 + col];
    const float* bsB = layer ? bsum1p : bsum0p;
    float bs[4];
#pragma unroll
    for (int g = 0; g < 4; ++g) bs[g] = bsB[lb * 32 + g * 8 + col];

#define MM(mi, nj, HH, HL)                                                     \
    acc[mi][nj] = __builtin_amdgcn_mfma_f32_16x16x32_bf16(                     \
        (mi) ? w01r[i] : w00r[i], HH, acc[mi][nj], 0, 0, 0);                   \
    acc[mi][nj] = __builtin_amdgcn_mfma_f32_16x16x32_bf16(                     \
        (mi) ? w01r[i] : w00r[i], HL, acc[mi][nj], 0, 0, 0);                   \
    acc[mi][nj] = __builtin_amdgcn_mfma_f32_16x16x32_bf16(                     \
        (mi) ? w11r[i] : w10r[i], HH, acc[mi][nj], 0, 0, 0);
#define SUBTILE(hp, po)                                                        \
    {                                                                          \
        const short8 h0v = LD8(hp),        h1v = LD8(hp + 512);                \
        const short8 h2v = LD8(hp + 1024), h3v = LD8(hp + 1536);               \
        const short8 l0v = LD8(hp + po),        l1v = LD8(hp + po + 512);      \
        const short8 l2v = LD8(hp + po + 1024), l3v = LD8(hp + po + 1536);     \
        MM(0, 0, h0v, l0v)  MM(0, 1, h1v, l1v)                                 \
        MM(0, 2, h2v, l2v)  MM(0, 3, h3v, l3v)                                 \
        MM(1, 0, h0v, l0v)  MM(1, 1, h1v, l1v)                                 \
        MM(1, 2, h2v, l2v)  MM(1, 3, h3v, l3v)                                 \
    }
    // wave-local poll of 16 producer flags (lanes 0..15), then compiler
    // barrier so the h loads below cannot be hoisted above the spin.
#define WPOLL(baseIdx, need)                                                   \
    {                                                                          \
        if (lane < 16) {                                                       \
            unsigned* p = bar + (size_t)((baseIdx) + lane) * 32;               \
            while (__hip_atomic_load(p, __ATOMIC_RELAXED,                      \
                                     __HIP_MEMORY_SCOPE_AGENT) < (need))       \
                __builtin_amdgcn_s_sleep(1);                                   \
        }                                                                      \
        __builtin_amdgcn_wave_barrier();                                       \
        asm volatile("" ::: "memory");                                         \
    }

    for (int r = 1; r <= 257; ++r) {
        const bool act = layer ? (r >= 2) : (r <= 256);
        if (act) {
            const int t = layer ? r - 2 : r - 1;
            const unsigned short* hOwn =
                (layer ? H1 : Y0) + (size_t)t * 131072 + (size_t)lane * 8;
            const unsigned short* hCross = layer
                ? Y0 + (size_t)(t + 1) * 131072 + (size_t)lane * 8
                : Ef + (size_t)t * 65536 + (size_t)lane * 8;
            const int poCross = layer ? 65536 : 32768;

            f32x4 acc[2][4] = {};

            // cross part: layer0 E (no dep); layer1 y0 slot t+1 (its 16
            // producers are L0 blocks w*16..w*16+15, flag >= r-1)
            if (layer) WPOLL(w * 16, (unsigned)(r - 1))
#pragma unroll
            for (int i = 4; i < 8; ++i)
                if (i < 4 + nEx) {
                    const int cs = layer ? (w * 4 + (i - 4)) : (w * 2 + (i - 4));
                    const unsigned short* hp = hCross + (size_t)cs * 2048;
                    SUBTILE(hp, poCross)
                }

            // own part: 16 own-layer producers (w*16..w*16+15), flag >= r-1
            if (r >= 2) WPOLL((layer ? 128 : 0) + w * 16, (unsigned)(r - 1))
#pragma unroll
            for (int i = 0; i < 4; ++i) {
                const unsigned short* hp = hOwn + (size_t)(w * 4 + i) * 2048;
                SUBTILE(hp, 65536)
            }

            // k-split partials: row = mi*16+(lane>>4)*4+rr, col = nj*16+(lane&15)
            {
                const int rq = (lane >> 4) * 4, cq = lane & 15;
#pragma unroll
                for (int mi = 0; mi < 2; ++mi)
#pragma unroll
                    for (int nj = 0; nj < 4; ++nj)
#pragma unroll
                        for (int rr = 0; rr < 4; ++rr)
                            Pred[w][mi * 16 + rq + rr][nj * 16 + cq] =
                                acc[mi][nj][rr];
            }
            __syncthreads();

            // activation: thread (b = lane, col = w)
            {
                float p[4];
#pragma unroll
                for (int g = 0; g < 4; ++g) {
                    const int row = g * 8 + col;
                    float s0 = 0.f;
#pragma unroll
                    for (int ww = 0; ww < 8; ++ww)
                        s0 += Pred[ww][row][lane];
                    p[g] = s0 + bs[g];
                }
                const float fg = sigmoidf_(p[0]);
                const float ig = sigmoidf_(p[1]);
                const float gg = tanhf(p[2]);
                const float og = sigmoidf_(p[3]);
                c_ = fmaf(fg, c_, ig * gg);
                const float h = og * tanhf(c_);
                const unsigned short hh = f2bf(h);
                hasmH[lane][col] = hh;
                hasmL[lane][col] = f2bf(h - bf2f(hh));
                if (layer && r == 257)
                    hst1[(size_t)(lb * 8 + col) * 64 + lane] = h;
            }
            __syncthreads();

            // granule store -> write-once slot t+1 (write-through atomics)
            if (tid < 128) {
                const int p = tid >> 6, b = tid & 63;
                unsigned short* hw =
                    (layer ? H1 : Y0) + (size_t)(t + 1) * 131072;
                const size_t off =
                    (((size_t)(p * 32 + (lb >> 2)) * 4 + (b >> 4)) * 64 +
                     ((b & 15) + 16 * (lb & 3))) * 8;
                const unsigned long long* src =
                    reinterpret_cast<const unsigned long long*>(
                        p ? &hasmL[b][0] : &hasmH[b][0]);
                unsigned long long* dst =
                    reinterpret_cast<unsigned long long*>(hw + off);
                __hip_atomic_store(dst, src[0], __ATOMIC_RELAXED,
                                   __HIP_MEMORY_SCOPE_AGENT);
                __hip_atomic_store(dst + 1, src[1], __ATOMIC_RELAXED,
                                   __HIP_MEMORY_SCOPE_AGENT);
            }
        }

        // ---- publish flag (stores drained by the barrier's vmcnt wait) ----
        if (r <= 256) {
            __syncthreads();
            if (tid == 0)
                __hip_atomic_store(bar + (size_t)bid * 32, (unsigned)r,
                                   __ATOMIC_RELAXED, __HIP_MEMORY_SCOPE_AGENT);
        }
    }
#undef WPOLL
#undef SUBTILE
#undef MM
}

// ---------------- classifier ------------------------------------------------
__global__ __launch_bounds__(256) void cls_k(
    const float* __restrict__ hfin, const float* __restrict__ Wc,
    const float* __restrict__ bcls, float* __restrict__ out)
{
    __shared__ float red[4][64];
    const int n = blockIdx.x;
    const int lane = threadIdx.x & 63, w = threadIdx.x >> 6;
    float acc = 0.f;
    for (int k = w * 256; k < w * 256 + 256; ++k)
        acc = fmaf(hfin[k * 64 + lane], Wc[k * 10 + n], acc);
    red[w][lane] = acc;
    __syncthreads();
    if (w == 0) {
        out[lane * 10 + n] = red[0][lane] + red[1][lane] + red[2][lane] +
                             red[3][lane] + bcls[n];
    }
}

extern "C" void kernel_launch(void* const* d_in, const int* in_sizes, int n_in,
                              void* d_out, int out_size, void* d_ws,
                              size_t ws_size, hipStream_t stream)
{
    const float* x    = (const float*)d_in[0];
    const float* h0   = (const float*)d_in[1];
    const float* c0   = (const float*)d_in[2];
    const float* Wenc = (const float*)d_in[3];
    const float* benc = (const float*)d_in[4];
    const float* alpha= (const float*)d_in[5];
    const float* Wx0  = (const float*)d_in[6];
    const float* bx0  = (const float*)d_in[7];
    const float* Wh0  = (const float*)d_in[8];
    const float* bh0  = (const float*)d_in[9];
    const float* Wx1  = (const float*)d_in[10];
    const float* bx1  = (const float*)d_in[11];
    const float* Wh1  = (const float*)d_in[12];
    const float* bh1  = (const float*)d_in[13];
    const float* Wcls = (const float*)d_in[14];
    const float* bcls = (const float*)d_in[15];
    float* out = (float*)d_out;

    // Workspace plan (floats): ~61.2M floats = 245 MB (budget >= 279 MB).
    float* ws = (float*)d_ws;
    size_t off = 0;
    unsigned short* Ef   = (unsigned short*)(ws + off); off += 8388608;   // 16.7M sh
    unsigned short* Wf0  = (unsigned short*)(ws + off); off += 6291456;   // 12.6M sh
    unsigned short* Wf1  = (unsigned short*)(ws + off); off += 8388608;   // 16.7M sh
    unsigned short* Y0   = (unsigned short*)(ws + off); off += 16842752;  // 257 slots
    unsigned short* H1   = (unsigned short*)(ws + off); off += 16842752;  // 257 slots
    unsigned short* Xhi  = (unsigned short*)(ws + off); off += 2097152;   // 4.2M sh
    unsigned short* Xlo  = (unsigned short*)(ws + off); off += 2097152;
    unsigned short* WeThi= (unsigned short*)(ws + off); off += 65536;     // 131K sh
    unsigned short* WeTlo= (unsigned short*)(ws + off); off += 65536;
    float* bsum0p = ws + off; off += 4096;
    float* bsum1p = ws + off; off += 4096;
    float* hst1   = ws + off; off += 65536;
    unsigned* bars = (unsigned*)(ws + off); off += 8192;   // 32 KB flag area

    (void)hipMemsetAsync(bars, 0, 32768, stream);

    // prologue (input-only deps)
    xsplit_k<<<2048, 256, 0, stream>>>(x, Xhi, Xlo);
    bsplitN_k<<<dim3(8, 8), 256, 0, stream>>>(Wenc, WeThi, WeTlo, 256, 512);
    enc_mfma_k<<<dim3(4, 128), 256, 0, stream>>>(
        Xhi, Xlo, WeThi, WeTlo, Ef, benc, alpha);
    wprep_k<<<dim3(48, 64), 256, 0, stream>>>(Wh0, Wx0, Wf0, 48);
    wprep_k<<<dim3(64, 64), 256, 0, stream>>>(Wh1, Wx1, Wf1, 64);
    hsplit_k<<<32, 256, 0, stream>>>(h0, Y0);                // h0_init -> slot 0
    hsplit_k<<<32, 256, 0, stream>>>(h0 + 65536, H1);        // h1_init -> slot 0
    bsum_k<<<16, 256, 0, stream>>>(bx0, bh0, bsum0p);
    bsum_k<<<16, 256, 0, stream>>>(bx1, bh1, bsum1p);

    // fused dual-layer LSTM, per-wave p2p flag sync (257 rounds)
    fused_lstm_k<<<256, 512, 0, stream>>>(Ef, Wf0, Wf1, Y0, H1, c0,
                                          bsum0p, bsum1p, hst1, bars);

    // classifier from layer-1 final h ([k][b])
    cls_k<<<dim3(10), 256, 0, stream>>>(hst1, Wcls, bcls, out);
}